// Round 5
// baseline (41861.884 us; speedup 1.0000x reference)
//
#include <hip/hip_runtime.h>
#include <math.h>

#define Hn 512
#define En 256
#define Sn 32
#define Bn 1024
#define Tn 32
#define Vn 256
#define G3 1536
#define EHn 768

// fma4 as a FUNCTION, not a macro (R6 lesson: macro param `w` collides with `.w`).
__device__ __forceinline__ void fma4(float& acc, const float4 w, const float4 x) {
  acc = fmaf(w.x, x.x, acc);
  acc = fmaf(w.y, x.y, acc);
  acc = fmaf(w.z, x.z, acc);
  acc = fmaf(w.w, x.w, acc);
}

// ============ one-time weight transpose: W[gate][K] -> WT4[k4*G + g] ============
__global__ __launch_bounds__(256) void transpose_pack(const float* __restrict__ W,
                                                      float4* __restrict__ WT4,
                                                      int G, int K) {
  const int idx = blockIdx.x * blockDim.x + threadIdx.x;
  const int n = G * (K >> 2);
  if (idx >= n) return;
  const int k4 = idx / G, g = idx - k4 * G;
  WT4[idx] = *(const float4*)(W + (size_t)g * K + (k4 << 2));
}

// ============ kproj GEMM: C(M,N) = A(M,K) @ W(N,K)^T + bias ============
__global__ __launch_bounds__(256) void gemm_bias(const float* __restrict__ A,
                                                 const float* __restrict__ Wt,
                                                 const float* __restrict__ bias,
                                                 float* __restrict__ C,
                                                 int M, int N, int K) {
  __shared__ float As[16][68];
  __shared__ float Ws[16][68];
  const int bm = blockIdx.y * 64;
  const int bn = blockIdx.x * 64;
  const int tid = threadIdx.x;
  const int tx = tid & 15;
  const int ty = tid >> 4;
  const int kk = tid & 15;
  const int r0 = tid >> 4;
  float acc[4][4] = {};
  for (int k0 = 0; k0 < K; k0 += 16) {
#pragma unroll
    for (int i = 0; i < 4; ++i) {
      const int m = r0 + (i << 4);
      As[kk][m] = A[(size_t)(bm + m) * K + (k0 + kk)];
      Ws[kk][m] = Wt[(size_t)(bn + m) * K + (k0 + kk)];
    }
    __syncthreads();
#pragma unroll
    for (int k = 0; k < 16; ++k) {
      const float4 a4 = *(const float4*)&As[k][ty * 4];
      const float4 w4 = *(const float4*)&Ws[k][tx * 4];
      const float av[4] = {a4.x, a4.y, a4.z, a4.w};
      const float wv[4] = {w4.x, w4.y, w4.z, w4.w};
#pragma unroll
      for (int i = 0; i < 4; ++i)
#pragma unroll
        for (int j = 0; j < 4; ++j) acc[i][j] = fmaf(av[i], wv[j], acc[i][j]);
    }
    __syncthreads();
  }
#pragma unroll
  for (int i = 0; i < 4; ++i) {
    const size_t m = (size_t)bm + ty * 4 + i;
    float* crow = C + m * N + bn + tx * 4;
#pragma unroll
    for (int j = 0; j < 4; ++j) crow[j] = acc[i][j] + bias[bn + tx * 4 + j];
  }
}

// ==================== Path COOP: grid-cooperative decoder =====================
// R5: R4 proved the binding constraint is per-block weight re-streaming
// (every block reads all 15.5MB weights each step; desync -> LLC/HBM blowup).
// Fix: GRU GEMMs + qp are grid-cooperative: 256 blocks = 16 Mtiles(64 rows)
// x 16 Jtiles(32 gate-cols x3 gates); weights read ~16x less in aggregate and
// each Jtile's 16 reader-blocks land on ONE XCD ((jt+16k)%8 const) -> L2-
// resident weight slices. Phases split by a sense-reversing global barrier;
// LDS 89.8KB pins 1 block/CU so all 256 blocks are co-resident (no deadlock).

// ---- LDS layout (floats) ----
#define C_XS     0          // [64][260] GEMM x-stage   -> 16640
#define C_QPS    16640      // [4][512]                 -> 18688
#define C_VAS    18688      // [512]                    -> 19200
#define C_EP     19200      // [1024]                   -> 20224
#define C_WRS    20224      // [128]                    -> 20352
#define C_H1L    20352      // [4][512]                 -> 22400
#define C_WRED   22400      // [16]
#define C_WREDI  22416      // int[16]
#define C_MXV    22432      // [4]
#define C_LGT    22436      // [4]
#define C_TGV    22440      // int[4]
#define C_TOKB   22444      // int[4]
#define C_MFS    22448      // int[4]
#define C_LSENSE 22452      // unsigned
#define COOP_LDSF 22456
#define COOP_LDSB (COOP_LDSF * 4)   // 89824 B > 80KB -> 1 block/CU

__device__ __forceinline__ void gsync(unsigned* bar, unsigned* lsense) {
  // bar[0] = count, bar[1] = sense. Sense-reversing centralized barrier.
  __threadfence();       // each thread's global writes -> device scope
  __syncthreads();
  if (threadIdx.x == 0) {
    const unsigned target = 1u - *lsense;
    const unsigned old =
        __hip_atomic_fetch_add(&bar[0], 1u, __ATOMIC_ACQ_REL, __HIP_MEMORY_SCOPE_AGENT);
    if (old == gridDim.x - 1) {
      __hip_atomic_store(&bar[0], 0u, __ATOMIC_RELAXED, __HIP_MEMORY_SCOPE_AGENT);
      __hip_atomic_store(&bar[1], target, __ATOMIC_RELEASE, __HIP_MEMORY_SCOPE_AGENT);
    } else {
      while (__hip_atomic_load(&bar[1], __ATOMIC_ACQUIRE, __HIP_MEMORY_SCOPE_AGENT) !=
             target) {
        __builtin_amdgcn_s_sleep(2);
      }
    }
    *lsense = target;
  }
  __syncthreads();
  __threadfence();       // invalidate stale lines before reading others' data
}

// cooperative qp tile: qp[R0..R0+63][J0..J0+31] = h1src @ WaT + bWa
__device__ __forceinline__ void qp_coop(int R0, int J0, int ty, int tx,
                                        const float* __restrict__ h1src,
                                        const float4* __restrict__ WaT,
                                        const float* __restrict__ bWa,
                                        float* __restrict__ qp, float* xs) {
  float a0 = 0.f, a1 = 0.f;
  const int rg0 = 2 * ty, rg1 = 2 * ty + 1;
  for (int c = 0; c < 2; ++c) {
    const int k0 = c * 64;  // f4 units
    __syncthreads();
    {
      const int row = threadIdx.x >> 4;
      const float4* src = (const float4*)(h1src + (size_t)(R0 + row) * Hn) + k0;
#pragma unroll
      for (int u = 0; u < 4; ++u) {
        const int f = (threadIdx.x & 15) + 16 * u;
        *(float4*)&xs[row * 260 + f * 4] = src[f];
      }
    }
    __syncthreads();
    for (int k4 = 0; k4 < 64; ++k4) {
      const float4 w = WaT[(size_t)(k0 + k4) * Hn + (J0 + tx)];
      const float4 x0 = *(const float4*)&xs[rg0 * 260 + k4 * 4];
      const float4 x1 = *(const float4*)&xs[rg1 * 260 + k4 * 4];
      fma4(a0, w, x0);
      fma4(a1, w, x1);
    }
  }
  const float bb = bWa[J0 + tx];
  qp[(size_t)(R0 + rg0) * Hn + J0 + tx] = a0 + bb;
  qp[(size_t)(R0 + rg1) * Hn + J0 + tx] = a1 + bb;
}

// cooperative GRU tile: computes hdst[R0..+63][J0..+31] from xsrc (K=KIH4*4)
// and hsrc (K=512) with gates at cols {J0+tx, +512, +1024}.
template <int KIH4>
__device__ __forceinline__ void gru_coop(int R0, int J0, int ty, int tx,
                                         const float* __restrict__ xsrc, int xStrideF4,
                                         const float* __restrict__ hsrc,
                                         const float4* __restrict__ WihT,
                                         const float4* __restrict__ WhhT,
                                         const float* __restrict__ bih,
                                         const float* __restrict__ bhh,
                                         float* __restrict__ hdst, float* xs) {
  float r0 = 0.f, z0 = 0.f, i0 = 0.f, n0 = 0.f;
  float r1 = 0.f, z1 = 0.f, i1 = 0.f, n1 = 0.f;
  const int rg0 = 2 * ty, rg1 = 2 * ty + 1;
  const int g0 = J0 + tx, g1 = g0 + 512, g2 = g0 + 1024;
  // ---- ih GEMM in 256-float chunks ----
  for (int c = 0; c < KIH4 / 64; ++c) {
    const int k0 = c * 64;
    __syncthreads();
    {
      const int row = threadIdx.x >> 4;
      const float4* src = (const float4*)xsrc + (size_t)(R0 + row) * xStrideF4 + k0;
#pragma unroll
      for (int u = 0; u < 4; ++u) {
        const int f = (threadIdx.x & 15) + 16 * u;
        *(float4*)&xs[row * 260 + f * 4] = src[f];
      }
    }
    __syncthreads();
    for (int k4 = 0; k4 < 64; ++k4) {
      const size_t wb = (size_t)(k0 + k4) * G3;
      const float4 wr = WihT[wb + g0];
      const float4 wz = WihT[wb + g1];
      const float4 wn = WihT[wb + g2];
      const float4 x0 = *(const float4*)&xs[rg0 * 260 + k4 * 4];
      const float4 x1 = *(const float4*)&xs[rg1 * 260 + k4 * 4];
      fma4(r0, wr, x0); fma4(z0, wz, x0); fma4(i0, wn, x0);
      fma4(r1, wr, x1); fma4(z1, wz, x1); fma4(i1, wn, x1);
    }
  }
  // ---- hh GEMM (K=512 -> 2 chunks); n-part accumulates SEPARATELY ----
  for (int c = 0; c < 2; ++c) {
    const int k0 = c * 64;
    __syncthreads();
    {
      const int row = threadIdx.x >> 4;
      const float4* src = (const float4*)hsrc + (size_t)(R0 + row) * (Hn / 4) + k0;
#pragma unroll
      for (int u = 0; u < 4; ++u) {
        const int f = (threadIdx.x & 15) + 16 * u;
        *(float4*)&xs[row * 260 + f * 4] = src[f];
      }
    }
    __syncthreads();
    for (int k4 = 0; k4 < 64; ++k4) {
      const size_t wb = (size_t)(k0 + k4) * G3;
      const float4 wr = WhhT[wb + g0];
      const float4 wz = WhhT[wb + g1];
      const float4 wn = WhhT[wb + g2];
      const float4 x0 = *(const float4*)&xs[rg0 * 260 + k4 * 4];
      const float4 x1 = *(const float4*)&xs[rg1 * 260 + k4 * 4];
      fma4(r0, wr, x0); fma4(z0, wz, x0); fma4(n0, wn, x0);
      fma4(r1, wr, x1); fma4(z1, wz, x1); fma4(n1, wn, x1);
    }
  }
  const float bir = bih[g0], biz = bih[g1], bin = bih[g2];
  const float bhr = bhh[g0], bhz = bhh[g1], bhn = bhh[g2];
  {
    const float rg = 1.f / (1.f + expf(-(r0 + bir + bhr)));
    const float zg = 1.f / (1.f + expf(-(z0 + biz + bhz)));
    const float ng = tanhf(i0 + bin + rg * (n0 + bhn));
    const float hold = hsrc[(size_t)(R0 + rg0) * Hn + g0];
    hdst[(size_t)(R0 + rg0) * Hn + g0] = (1.f - zg) * ng + zg * hold;
  }
  {
    const float rg = 1.f / (1.f + expf(-(r1 + bir + bhr)));
    const float zg = 1.f / (1.f + expf(-(z1 + biz + bhz)));
    const float ng = tanhf(i1 + bin + rg * (n1 + bhn));
    const float hold = hsrc[(size_t)(R0 + rg1) * Hn + g0];
    hdst[(size_t)(R0 + rg1) * Hn + g0] = (1.f - zg) * ng + zg * hold;
  }
}

__global__ __launch_bounds__(1024) __attribute__((amdgpu_waves_per_eu(4, 4)))
void decoder_coop(
    const float* __restrict__ state, const float* __restrict__ enc,
    const int* __restrict__ target, const float* __restrict__ emb,
    const float4* __restrict__ WaT, const float* __restrict__ bWa,
    const float* __restrict__ Va, const float* __restrict__ bVa,
    const float4* __restrict__ W0ihT, const float4* __restrict__ W0hhT,
    const float* __restrict__ bih0, const float* __restrict__ bhh0,
    const float4* __restrict__ W1ihT, const float4* __restrict__ W1hhT,
    const float* __restrict__ bih1, const float* __restrict__ bhh1,
    const float4* __restrict__ fcWT, const float* __restrict__ fcb,
    const float* __restrict__ kproj,
    float* __restrict__ gin, float* __restrict__ h0A, float* __restrict__ h0B,
    float* __restrict__ h1A, float* __restrict__ h1B, float* __restrict__ qp,
    unsigned* __restrict__ bar,
    float* __restrict__ out, float* __restrict__ wsloss, int* __restrict__ wscorrect) {
  extern __shared__ float L[];
  float* xs = L + C_XS;
  float* qps = L + C_QPS;
  float* vas = L + C_VAS;
  float* ep = L + C_EP;
  float* wrs = L + C_WRS;
  float* h1l = L + C_H1L;
  float* wred = L + C_WRED;
  int* wredi = (int*)(L + C_WREDI);
  float* mxv = L + C_MXV;
  float* lgt = L + C_LGT;
  int* tgv = (int*)(L + C_TGV);
  int* tokb = (int*)(L + C_TOKB);
  int* mfs = (int*)(L + C_MFS);
  unsigned* lsense = (unsigned*)(L + C_LSENSE);

  const int tid = threadIdx.x;
  const int bid = blockIdx.x;
  const int b0 = bid * 4;                  // block-local rows (attention / fc)
  const int mt = bid >> 4, jt = bid & 15;  // GEMM tile coords
  const int R0 = mt * 64, J0 = jt * 32;
  const int ty = tid >> 5, tx = tid & 31;  // GEMM thread map (2 rows, 1 col)

  // ---- pre-phase: copy state into buffers A, init LDS ----
  for (int i = tid; i < 4 * Hn; i += 1024) {
    const int r = i >> 9, j = i & 511;
    h0A[(size_t)(b0 + r) * Hn + j] = state[(size_t)(b0 + r) * Hn + j];
    h1A[(size_t)(b0 + r) * Hn + j] = state[(size_t)(Bn + b0 + r) * Hn + j];
  }
  if (tid < 512) vas[tid] = Va[tid];
  if (tid < 4) { tokb[tid] = 1; mfs[tid] = 1; }
  if (tid == 0) *lsense = 0u;
  gsync(bar, lsense);
  qp_coop(R0, J0, ty, tx, h1A, WaT, bWa, qp, xs);   // qp for t=0
  gsync(bar, lsense);

  float run_loss = 0.f;  // tid 0 only

  for (int t = 0; t < Tn; ++t) {
    const float* h0cur = (t & 1) ? h0B : h0A;
    float* h0nxt = (t & 1) ? h0A : h0B;
    const float* h1cur = (t & 1) ? h1B : h1A;
    float* h1nxt = (t & 1) ? h1A : h1B;

    // ================= P1: attention + gin (block-local rows) =================
    for (int i = tid; i < 4 * Hn; i += 1024)
      qps[i] = qp[(size_t)(b0 + (i >> 9)) * Hn + (i & 511)];
    __syncthreads();
    {
      const int p = tid >> 3, q = tid & 7;  // p = r*32+s
      const int r = p >> 5, s = p & 31;
      const float4* kp4 = (const float4*)(kproj + ((size_t)s * Bn + (b0 + r)) * Hn);
      const float4* qp4 = (const float4*)(qps + r * Hn);
      const float4* va4 = (const float4*)vas;
      float partial = 0.f;
      for (int i = 0; i < 16; ++i) {
        const int f = q + (i << 3);
        const float4 k4 = kp4[f], q4 = qp4[f], v4 = va4[f];
        partial += v4.x * tanhf(q4.x + k4.x);
        partial += v4.y * tanhf(q4.y + k4.y);
        partial += v4.z * tanhf(q4.z + k4.z);
        partial += v4.w * tanhf(q4.w + k4.w);
      }
      ep[tid] = partial;
    }
    __syncthreads();
    if (tid < 128) {
      float e = ep[tid * 8] + ep[tid * 8 + 1] + ep[tid * 8 + 2] + ep[tid * 8 + 3] +
                ep[tid * 8 + 4] + ep[tid * 8 + 5] + ep[tid * 8 + 6] + ep[tid * 8 + 7] +
                bVa[0];
      float m = e;
#pragma unroll
      for (int off = 16; off; off >>= 1) m = fmaxf(m, __shfl_xor(m, off));
      const float ex = expf(e - m);
      float ss = ex;
#pragma unroll
      for (int off = 16; off; off >>= 1) ss += __shfl_xor(ss, off);
      const float w = ex / ss;
      const int r = tid >> 5, s = tid & 31;
      wrs[tid] = w;
      out[(size_t)(Bn * Tn) + (size_t)t * (Bn * Sn) + (size_t)(b0 + r) * Sn + s] = w;
    }
    __syncthreads();
    {
      const int h = tid & 511, rp = tid >> 9;  // rows 2rp, 2rp+1
      float c0 = 0.f, c1 = 0.f;
      const float* w0 = wrs + (2 * rp) * 32;
      const float* w1 = wrs + (2 * rp + 1) * 32;
      for (int s = 0; s < Sn; ++s) {
        const size_t base = ((size_t)s * Bn + b0 + 2 * rp) * Hn + h;
        c0 = fmaf(w0[s], enc[base], c0);
        c1 = fmaf(w1[s], enc[base + Hn], c1);
      }
      gin[(size_t)(b0 + 2 * rp) * EHn + En + h] = c0;
      gin[(size_t)(b0 + 2 * rp + 1) * EHn + En + h] = c1;
    }
    {
      const int r = tid >> 8, j = tid & 255;
      gin[(size_t)(b0 + r) * EHn + j] = fmaxf(emb[(size_t)tokb[r] * En + j], 0.f);
    }
    gsync(bar, lsense);  // S1: gin complete

    // ================= P2: GRU layer 0 (cooperative tile) =================
    gru_coop<192>(R0, J0, ty, tx, gin, EHn / 4, h0cur, W0ihT, W0hhT, bih0, bhh0,
                  h0nxt, xs);
    gsync(bar, lsense);  // S2: h0nxt complete

    // ================= P3: GRU layer 1 (cooperative tile) =================
    gru_coop<128>(R0, J0, ty, tx, h0nxt, Hn / 4, h1cur, W1ihT, W1hhT, bih1, bhh1,
                  h1nxt, xs);
    gsync(bar, lsense);  // S3: h1nxt complete

    // ================= P4: fc/argmax/loss (block-local) + qp for t+1 ==========
    if (tid < 4) tgv[tid] = target[(size_t)(b0 + tid) * Tn + t];
    for (int i = tid; i < 4 * Hn; i += 1024)
      h1l[i] = h1nxt[(size_t)(b0 + (i >> 9)) * Hn + (i & 511)];
    __syncthreads();
    const int v = tid & 255, rr = tid >> 8;
    float l;
    {
      const float4* wp = fcWT + v;
      const float4* xr = (const float4*)(h1l + rr * Hn);
      float acc = 0.f;
      for (int k4 = 0; k4 < (Hn >> 2); ++k4) {
        const float4 w = wp[(size_t)k4 * Vn];
        fma4(acc, w, xr[k4]);
      }
      l = acc + fcb[v];
    }
    if (v == tgv[rr]) lgt[rr] = l;
    {
      float m = l;
      int mi = v;
#pragma unroll
      for (int off = 32; off; off >>= 1) {
        const float om = __shfl_xor(m, off);
        const int oi = __shfl_xor(mi, off);
        if (om > m || (om == m && oi < mi)) { m = om; mi = oi; }
      }
      if ((tid & 63) == 0) {
        wred[tid >> 6] = m;
        wredi[tid >> 6] = mi;
      }
    }
    __syncthreads();
    int am_r = 0;
    if (tid < 4) {
      float bm = wred[4 * tid];
      int bi = wredi[4 * tid];
#pragma unroll
      for (int q = 1; q < 4; ++q) {
        const float o = wred[4 * tid + q];
        const int oi = wredi[4 * tid + q];
        if (o > bm || (o == bm && oi < bi)) { bm = o; bi = oi; }
      }
      mxv[tid] = bm;
      am_r = bi;
    }
    __syncthreads();
    {
      float ex = expf(l - mxv[rr]);
#pragma unroll
      for (int off = 32; off; off >>= 1) ex += __shfl_xor(ex, off);
      if ((tid & 63) == 0) wred[tid >> 6] = ex;
    }
    __syncthreads();
    if (tid < 4) {
      tokb[tid] = am_r;
      if (am_r != tgv[tid]) mfs[tid] = 0;
      out[(size_t)(b0 + tid) * Tn + t] = (float)am_r;
    }
    if (tid == 0) {
#pragma unroll
      for (int r = 0; r < 4; ++r) {
        const float s = wred[4 * r] + wred[4 * r + 1] + wred[4 * r + 2] + wred[4 * r + 3];
        run_loss += -(lgt[r] - mxv[r] - logf(s)) * (1.f / 1024.f);
      }
    }
    // qp for next step (cooperative; reads full h1nxt)
    qp_coop(R0, J0, ty, tx, h1nxt, WaT, bWa, qp, xs);
    gsync(bar, lsense);  // S4: qp + tokens complete
  }

  if (tid == 0) {
    atomicAdd(wsloss, run_loss);
    atomicAdd(wscorrect, mfs[0] + mfs[1] + mfs[2] + mfs[3]);
  }
}

// ============ Path A3 (tier-2 fallback): R=4 r4y decoder, verified 10.0ms ======
template <int KCI, int KCH>
__device__ __forceinline__ void gru_pair(
    int jj, int grp,
    const float4* __restrict__ WihT,
    const float4* __restrict__ WhhT,
    const float* __restrict__ x, int xstride,
    float* __restrict__ h,
    const float* __restrict__ bih, const float* __restrict__ bhh) {
  float ar[4] = {}, az[4] = {}, ain[4] = {}, ahn[4] = {};
  {
    const int k0 = grp * KCI;
    const float4* w0 = WihT + jj + (size_t)k0 * G3;
    const float4* w1 = WihT + jj + 512 + (size_t)k0 * G3;
    const float4* w2 = WihT + jj + 1024 + (size_t)k0 * G3;
    for (int k4 = 0; k4 < KCI; k4 += 2) {
#pragma unroll
      for (int u = 0; u < 2; ++u) {
        const float4 a = w0[(size_t)(k4 + u) * G3];
        const float4 b = w1[(size_t)(k4 + u) * G3];
        const float4 c = w2[(size_t)(k4 + u) * G3];
#pragma unroll
        for (int r = 0; r < 4; ++r) {
          const float4 xv = ((const float4*)(x + r * xstride))[k0 + k4 + u];
          fma4(ar[r], a, xv);
          fma4(az[r], b, xv);
          fma4(ain[r], c, xv);
        }
      }
    }
  }
  {
    const int k0 = grp * KCH;
    const float4* w0 = WhhT + jj + (size_t)k0 * G3;
    const float4* w1 = WhhT + jj + 512 + (size_t)k0 * G3;
    const float4* w2 = WhhT + jj + 1024 + (size_t)k0 * G3;
    for (int k4 = 0; k4 < KCH; k4 += 2) {
#pragma unroll
      for (int u = 0; u < 2; ++u) {
        const float4 a = w0[(size_t)(k4 + u) * G3];
        const float4 b = w1[(size_t)(k4 + u) * G3];
        const float4 c = w2[(size_t)(k4 + u) * G3];
#pragma unroll
        for (int r = 0; r < 4; ++r) {
          const float4 xv = ((const float4*)(h + r * Hn))[k0 + k4 + u];
          fma4(ar[r], a, xv);
          fma4(az[r], b, xv);
          fma4(ahn[r], c, xv);
        }
      }
    }
  }
#pragma unroll
  for (int r = 0; r < 4; ++r) {
    ar[r] += __shfl_xor(ar[r], 32);
    az[r] += __shfl_xor(az[r], 32);
    ain[r] += __shfl_xor(ain[r], 32);
    ahn[r] += __shfl_xor(ahn[r], 32);
  }
  const float bir = bih[jj], biz = bih[jj + 512], bin = bih[jj + 1024];
  const float bhr = bhh[jj], bhz = bhh[jj + 512], bhn = bhh[jj + 1024];
  const int r2 = grp * 2;
  const float s0r = (grp ? ar[2] : ar[0]) + bir + bhr;
  const float s0z = (grp ? az[2] : az[0]) + biz + bhz;
  const float s0i = (grp ? ain[2] : ain[0]) + bin;
  const float s0h = (grp ? ahn[2] : ahn[0]) + bhn;
  const float s1r = (grp ? ar[3] : ar[1]) + bir + bhr;
  const float s1z = (grp ? az[3] : az[1]) + biz + bhz;
  const float s1i = (grp ? ain[3] : ain[1]) + bin;
  const float s1h = (grp ? ahn[3] : ahn[1]) + bhn;
  const float rg0 = 1.f / (1.f + expf(-s0r));
  const float zg0 = 1.f / (1.f + expf(-s0z));
  const float ng0 = tanhf(s0i + rg0 * s0h);
  const float rg1 = 1.f / (1.f + expf(-s1r));
  const float zg1 = 1.f / (1.f + expf(-s1z));
  const float ng1 = tanhf(s1i + rg1 * s1h);
  const float h0old = h[(r2 + 0) * Hn + jj];
  const float h1old = h[(r2 + 1) * Hn + jj];
  const float hn0 = (1.f - zg0) * ng0 + zg0 * h0old;
  const float hn1 = (1.f - zg1) * ng1 + zg1 * h1old;
  __syncthreads();
  h[(r2 + 0) * Hn + jj] = hn0;
  h[(r2 + 1) * Hn + jj] = hn1;
  __syncthreads();
}

__global__ __launch_bounds__(1024) __attribute__((amdgpu_waves_per_eu(4, 4)))
void decoder_r4y(
    const float* __restrict__ state, const float* __restrict__ enc,
    const int* __restrict__ target, const float* __restrict__ emb,
    const float4* __restrict__ WaT, const float* __restrict__ bWa,
    const float* __restrict__ Va, const float* __restrict__ bVa,
    const float4* __restrict__ W0ihT, const float4* __restrict__ W0hhT,
    const float* __restrict__ bih0, const float* __restrict__ bhh0,
    const float4* __restrict__ W1ihT, const float4* __restrict__ W1hhT,
    const float* __restrict__ bih1, const float* __restrict__ bhh1,
    const float4* __restrict__ fcWT, const float* __restrict__ fcb,
    const float* __restrict__ kproj, float* __restrict__ out,
    float* __restrict__ wsloss, int* __restrict__ wscorrect) {
  __shared__ __attribute__((aligned(16))) float h0s[4 * Hn];
  __shared__ __attribute__((aligned(16))) float h1s[4 * Hn];
  __shared__ __attribute__((aligned(16))) float qps[4 * Hn];
  __shared__ __attribute__((aligned(16))) float gins[4 * EHn];
  __shared__ __attribute__((aligned(16))) float vas[Hn];
  __shared__ __attribute__((aligned(16))) float wrs[4 * Sn];
  __shared__ __attribute__((aligned(16))) float ep[1024];
  __shared__ float wred[16];
  __shared__ int wredi[16];
  __shared__ float mxv[4], lgt[4];
  __shared__ int tgv[4], tokb[4], mfs[4];

  const int tid = threadIdx.x;
  const int b0 = blockIdx.x * 4;
  const int jj = (tid & 31) | ((tid >> 6) << 5);
  const int grp = (tid >> 5) & 1;

  for (int i = tid; i < 4 * Hn; i += 1024) {
    const int r = i >> 9, j = i & 511;
    h0s[i] = state[(size_t)(b0 + r) * Hn + j];
    h1s[i] = state[(size_t)(Bn + b0 + r) * Hn + j];
  }
  if (tid < 512) vas[tid] = Va[tid];
  if (tid < 4) { tokb[tid] = 1; mfs[tid] = 1; }
  __syncthreads();

  float run_loss = 0.f;

  for (int t = 0; t < Tn; ++t) {
    {
      const int kc = (Hn >> 2) >> 1;
      const int k0 = grp * kc;
      const float4* wp = WaT + jj + (size_t)k0 * Hn;
      float a0 = 0.f, a1 = 0.f, a2 = 0.f, a3 = 0.f;
      for (int k4 = 0; k4 < 64; k4 += 2) {
#pragma unroll
        for (int u = 0; u < 2; ++u) {
          const float4 w = wp[(size_t)(k4 + u) * Hn];
          const float4 x0 = ((const float4*)(h1s))[k0 + k4 + u];
          const float4 x1 = ((const float4*)(h1s + Hn))[k0 + k4 + u];
          const float4 x2 = ((const float4*)(h1s + 2 * Hn))[k0 + k4 + u];
          const float4 x3 = ((const float4*)(h1s + 3 * Hn))[k0 + k4 + u];
          fma4(a0, w, x0); fma4(a1, w, x1); fma4(a2, w, x2); fma4(a3, w, x3);
        }
      }
      a0 += __shfl_xor(a0, 32);
      a1 += __shfl_xor(a1, 32);
      a2 += __shfl_xor(a2, 32);
      a3 += __shfl_xor(a3, 32);
      const float bb = bWa[jj];
      if (!grp) {
        qps[jj] = a0 + bb;
        qps[Hn + jj] = a1 + bb;
      } else {
        qps[2 * Hn + jj] = a2 + bb;
        qps[3 * Hn + jj] = a3 + bb;
      }
    }
    __syncthreads();
    {
      const int p = tid >> 3, q = tid & 7;
      const int r = p >> 5, s = p & 31;
      const float4* kp4 = (const float4*)(kproj + ((size_t)s * Bn + (b0 + r)) * Hn);
      const float4* qp4 = (const float4*)(qps + r * Hn);
      const float4* va4 = (const float4*)vas;
      float partial = 0.f;
      for (int i = 0; i < 16; i += 2) {
#pragma unroll
        for (int u = 0; u < 2; ++u) {
          const int f = q + ((i + u) << 3);
          const float4 k4 = kp4[f], q4 = qp4[f], v4 = va4[f];
          partial += v4.x * tanhf(q4.x + k4.x);
          partial += v4.y * tanhf(q4.y + k4.y);
          partial += v4.z * tanhf(q4.z + k4.z);
          partial += v4.w * tanhf(q4.w + k4.w);
        }
      }
      ep[tid] = partial;
    }
    __syncthreads();
    if (tid < 128) {
      float e = ep[tid * 8] + ep[tid * 8 + 1] + ep[tid * 8 + 2] + ep[tid * 8 + 3] +
                ep[tid * 8 + 4] + ep[tid * 8 + 5] + ep[tid * 8 + 6] + ep[tid * 8 + 7] +
                bVa[0];
      float m = e;
#pragma unroll
      for (int off = 16; off; off >>= 1) m = fmaxf(m, __shfl_xor(m, off));
      const float ex = expf(e - m);
      float ss = ex;
#pragma unroll
      for (int off = 16; off; off >>= 1) ss += __shfl_xor(ss, off);
      const float w = ex / ss;
      const int r = tid >> 5, s = tid & 31;
      wrs[tid] = w;
      out[(size_t)(Bn * Tn) + (size_t)t * (Bn * Sn) + (size_t)(b0 + r) * Sn + s] = w;
    }
    __syncthreads();
    {
      const int h = tid & 511, rp = tid >> 9;
      float c0 = 0.f, c1 = 0.f;
      const float* w0 = wrs + (2 * rp) * 32;
      const float* w1 = wrs + (2 * rp + 1) * 32;
#pragma unroll 4
      for (int s = 0; s < Sn; ++s) {
        const size_t base = ((size_t)s * Bn + b0 + 2 * rp) * Hn + h;
        c0 = fmaf(w0[s], enc[base], c0);
        c1 = fmaf(w1[s], enc[base + Hn], c1);
      }
      gins[(2 * rp) * EHn + En + h] = c0;
      gins[(2 * rp + 1) * EHn + En + h] = c1;
    }
    {
      const int r = tid >> 8, j = tid & 255;
      gins[r * EHn + j] = fmaxf(emb[(size_t)tokb[r] * En + j], 0.f);
    }
    if (tid < 4) tgv[tid] = target[(size_t)(b0 + tid) * Tn + t];
    __syncthreads();
    gru_pair<96, 64>(jj, grp, W0ihT, W0hhT, gins, EHn, h0s, bih0, bhh0);
    gru_pair<64, 64>(jj, grp, W1ihT, W1hhT, h0s, Hn, h1s, bih1, bhh1);
    const int v = tid & 255, rr = tid >> 8;
    float l;
    {
      const float4* wp = fcWT + v;
      const float4* xr = (const float4*)(h1s + rr * Hn);
      float acc = 0.f;
      for (int k4 = 0; k4 < (Hn >> 2); k4 += 4) {
#pragma unroll
        for (int u = 0; u < 4; ++u) {
          const float4 w = wp[(size_t)(k4 + u) * Vn];
          fma4(acc, w, xr[k4 + u]);
        }
      }
      l = acc + fcb[v];
    }
    if (v == tgv[rr]) lgt[rr] = l;
    {
      float m = l;
      int mi = v;
#pragma unroll
      for (int off = 32; off; off >>= 1) {
        const float om = __shfl_xor(m, off);
        const int oi = __shfl_xor(mi, off);
        if (om > m || (om == m && oi < mi)) { m = om; mi = oi; }
      }
      if ((tid & 63) == 0) {
        wred[tid >> 6] = m;
        wredi[tid >> 6] = mi;
      }
    }
    __syncthreads();
    int am_r = 0;
    if (tid < 4) {
      float bm = wred[4 * tid];
      int bi = wredi[4 * tid];
#pragma unroll
      for (int q = 1; q < 4; ++q) {
        const float o = wred[4 * tid + q];
        const int oi = wredi[4 * tid + q];
        if (o > bm || (o == bm && oi < bi)) { bm = o; bi = oi; }
      }
      mxv[tid] = bm;
      am_r = bi;
    }
    __syncthreads();
    {
      float ex = expf(l - mxv[rr]);
#pragma unroll
      for (int off = 32; off; off >>= 1) ex += __shfl_xor(ex, off);
      if ((tid & 63) == 0) wred[tid >> 6] = ex;
    }
    __syncthreads();
    if (tid < 4) {
      tokb[tid] = am_r;
      if (am_r != tgv[tid]) mfs[tid] = 0;
      out[(size_t)(b0 + tid) * Tn + t] = (float)am_r;
    }
    if (tid == 0) {
#pragma unroll
      for (int r = 0; r < 4; ++r) {
        const float s = wred[4 * r] + wred[4 * r + 1] + wred[4 * r + 2] + wred[4 * r + 3];
        run_loss += -(lgt[r] - mxv[r] - logf(s)) * (1.f / 1024.f);
      }
    }
  }

  __syncthreads();
  if (tid == 0) {
    atomicAdd(wsloss, run_loss);
    atomicAdd(wscorrect, mfs[0] + mfs[1] + mfs[2] + mfs[3]);
  }
}

// ============ Path A fallback (tier-3): R5-verified decoder ====================
__device__ __forceinline__ void gru_layer4(int j, const float* __restrict__ x,
                                           int xstride, int K,
                                           float* __restrict__ h,
                                           const float* __restrict__ Wih,
                                           const float* __restrict__ Whh,
                                           const float* __restrict__ bih,
                                           const float* __restrict__ bhh) {
  float ai0[4] = {}, ai1[4] = {}, ai2[4] = {};
  {
    const float4* w0 = (const float4*)(Wih + (size_t)j * K);
    const float4* w1 = (const float4*)(Wih + (size_t)(j + 512) * K);
    const float4* w2 = (const float4*)(Wih + (size_t)(j + 1024) * K);
    for (int i = 0; i < K / 4; ++i) {
      const float4 a = w0[i], b = w1[i], c = w2[i];
#pragma unroll
      for (int r = 0; r < 4; ++r) {
        const float4 xv = ((const float4*)(x + r * xstride))[i];
        fma4(ai0[r], a, xv); fma4(ai1[r], b, xv); fma4(ai2[r], c, xv);
      }
    }
  }
  float ah0[4] = {}, ah1[4] = {}, ah2[4] = {};
  {
    const float4* w0 = (const float4*)(Whh + (size_t)j * Hn);
    const float4* w1 = (const float4*)(Whh + (size_t)(j + 512) * Hn);
    const float4* w2 = (const float4*)(Whh + (size_t)(j + 1024) * Hn);
    for (int i = 0; i < Hn / 4; ++i) {
      const float4 a = w0[i], b = w1[i], c = w2[i];
#pragma unroll
      for (int r = 0; r < 4; ++r) {
        const float4 xv = ((const float4*)(h + r * Hn))[i];
        fma4(ah0[r], a, xv); fma4(ah1[r], b, xv); fma4(ah2[r], c, xv);
      }
    }
  }
  const float bi0 = bih[j], bi1 = bih[j + 512], bi2 = bih[j + 1024];
  const float bh0 = bhh[j], bh1 = bhh[j + 512], bh2 = bhh[j + 1024];
  float hn[4];
#pragma unroll
  for (int r = 0; r < 4; ++r) {
    const float ir = ai0[r] + bi0, iz = ai1[r] + bi1, in_ = ai2[r] + bi2;
    const float hr = ah0[r] + bh0, hz = ah1[r] + bh1, hnn = ah2[r] + bh2;
    const float rg = 1.f / (1.f + expf(-(ir + hr)));
    const float zg = 1.f / (1.f + expf(-(iz + hz)));
    const float ng = tanhf(in_ + rg * hnn);
    hn[r] = (1.f - zg) * ng + zg * h[r * Hn + j];
  }
  __syncthreads();
#pragma unroll
  for (int r = 0; r < 4; ++r) h[r * Hn + j] = hn[r];
  __syncthreads();
}

__global__ __launch_bounds__(512, 1) void decoder_r4(
    const float* __restrict__ state, const float* __restrict__ enc,
    const int* __restrict__ target, const float* __restrict__ emb,
    const float* __restrict__ Wa, const float* __restrict__ bWa,
    const float* __restrict__ Va, const float* __restrict__ bVa,
    const float* __restrict__ Wih0, const float* __restrict__ Whh0,
    const float* __restrict__ bih0, const float* __restrict__ bhh0,
    const float* __restrict__ Wih1, const float* __restrict__ Whh1,
    const float* __restrict__ bih1, const float* __restrict__ bhh1,
    const float* __restrict__ fcW, const float* __restrict__ fcb,
    const float* __restrict__ kproj, float* __restrict__ out,
    float* __restrict__ wsloss, int* __restrict__ wscorrect) {
  __shared__ float h0s[4 * Hn], h1s[4 * Hn], qps[4 * Hn], gins[4 * EHn], vas[Hn];
  __shared__ float red[1024], lg[1024];
  __shared__ int ridx[1024];
  __shared__ float wrs[4 * Sn];
  __shared__ float mxv[4], lzv[4], llv[4];
  __shared__ int amv[4], tgv[4], tokb[4], mfs[4];

  const int tid = threadIdx.x;
  const int b0 = blockIdx.x * 4;

  for (int i = tid; i < 4 * Hn; i += 512) {
    const int r = i >> 9, j = i & 511;
    h0s[i] = state[(size_t)(b0 + r) * Hn + j];
    h1s[i] = state[(size_t)(Bn + b0 + r) * Hn + j];
  }
  vas[tid] = Va[tid];
  if (tid < 4) { tokb[tid] = 1; mfs[tid] = 1; llv[tid] = 0.f; }
  __syncthreads();

  float run_loss = 0.f;

  for (int t = 0; t < Tn; ++t) {
    {
      const int h = tid;
      const float4* w4 = (const float4*)(Wa + (size_t)h * Hn);
      float a0 = 0.f, a1 = 0.f, a2 = 0.f, a3 = 0.f;
      for (int i = 0; i < Hn / 4; ++i) {
        const float4 w = w4[i];
        const float4 x0 = ((const float4*)(h1s))[i];
        const float4 x1 = ((const float4*)(h1s + Hn))[i];
        const float4 x2 = ((const float4*)(h1s + 2 * Hn))[i];
        const float4 x3 = ((const float4*)(h1s + 3 * Hn))[i];
        fma4(a0, w, x0); fma4(a1, w, x1); fma4(a2, w, x2); fma4(a3, w, x3);
      }
      const float bb = bWa[h];
      qps[h] = a0 + bb; qps[Hn + h] = a1 + bb;
      qps[2 * Hn + h] = a2 + bb; qps[3 * Hn + h] = a3 + bb;
    }
    __syncthreads();
    {
      const int p = tid >> 2, q = tid & 3;
      const int r = p >> 5, s = p & 31;
      const float4* kp4 = (const float4*)(kproj + ((size_t)s * Bn + (b0 + r)) * Hn);
      const float4* qp4 = (const float4*)(qps + r * Hn);
      const float4* va4 = (const float4*)vas;
      float partial = 0.f;
      for (int i = 0; i < 32; ++i) {
        const int f = q + (i << 2);
        const float4 k4 = kp4[f], q4 = qp4[f], v4 = va4[f];
        partial += v4.x * tanhf(q4.x + k4.x);
        partial += v4.y * tanhf(q4.y + k4.y);
        partial += v4.z * tanhf(q4.z + k4.z);
        partial += v4.w * tanhf(q4.w + k4.w);
      }
      red[tid] = partial;
    }
    __syncthreads();
    if (tid < 128) {
      float e = red[tid * 4] + red[tid * 4 + 1] + red[tid * 4 + 2] + red[tid * 4 + 3] + bVa[0];
      float m = e;
#pragma unroll
      for (int off = 16; off; off >>= 1) m = fmaxf(m, __shfl_xor(m, off));
      const float ex = expf(e - m);
      float ss = ex;
#pragma unroll
      for (int off = 16; off; off >>= 1) ss += __shfl_xor(ss, off);
      const float w = ex / ss;
      const int r = tid >> 5, s = tid & 31;
      wrs[tid] = w;
      out[(size_t)(Bn * Tn) + (size_t)t * (Bn * Sn) + (size_t)(b0 + r) * Sn + s] = w;
    }
    __syncthreads();
    {
      const int h = tid;
      float c0 = 0.f, c1 = 0.f, c2 = 0.f, c3 = 0.f;
      for (int s = 0; s < Sn; ++s) {
        const size_t base = ((size_t)s * Bn + b0) * Hn + h;
        c0 = fmaf(wrs[s], enc[base], c0);
        c1 = fmaf(wrs[32 + s], enc[base + Hn], c1);
        c2 = fmaf(wrs[64 + s], enc[base + 2 * Hn], c2);
        c3 = fmaf(wrs[96 + s], enc[base + 3 * Hn], c3);
      }
      gins[En + h] = c0; gins[EHn + En + h] = c1;
      gins[2 * EHn + En + h] = c2; gins[3 * EHn + En + h] = c3;
    }
    for (int i = tid; i < 4 * En; i += 512) {
      const int r = i >> 8, j = i & 255;
      gins[r * EHn + j] = fmaxf(emb[(size_t)tokb[r] * En + j], 0.f);
    }
    __syncthreads();
    gru_layer4(tid, gins, EHn, EHn, h0s, Wih0, Whh0, bih0, bhh0);
    gru_layer4(tid, h0s, Hn, Hn, h1s, Wih1, Whh1, bih1, bhh1);
    {
      const int v = tid & 255;
      const int rA = tid >> 8, rB = rA + 2;
      const float4* w4 = (const float4*)(fcW + (size_t)v * Hn);
      const float4* xA = (const float4*)(h1s + rA * Hn);
      const float4* xB = (const float4*)(h1s + rB * Hn);
      float aA = 0.f, aB = 0.f;
      for (int i = 0; i < Hn / 4; ++i) {
        const float4 w = w4[i];
        const float4 a = xA[i], b = xB[i];
        fma4(aA, w, a); fma4(aB, w, b);
      }
      const float fb = fcb[v];
      const float lA = aA + fb, lB = aB + fb;
      lg[rA * 256 + v] = lA; red[rA * 256 + v] = lA; ridx[rA * 256 + v] = v;
      lg[rB * 256 + v] = lB; red[rB * 256 + v] = lB; ridx[rB * 256 + v] = v;
    }
    __syncthreads();
    for (int off = 128; off; off >>= 1) {
#pragma unroll
      for (int half = 0; half < 2; ++half) {
        const int u = tid + half * 512;
        if ((u & 255) < off) {
          const int u2 = u + off;
          const float o = red[u2]; const int oi = ridx[u2];
          if (o > red[u] || (o == red[u] && oi < ridx[u])) { red[u] = o; ridx[u] = oi; }
        }
      }
      __syncthreads();
    }
    if (tid < 4) {
      mxv[tid] = red[tid * 256];
      amv[tid] = ridx[tid * 256];
      tgv[tid] = target[(size_t)(b0 + tid) * Tn + t];
    }
    __syncthreads();
#pragma unroll
    for (int half = 0; half < 2; ++half) {
      const int u = tid + half * 512;
      red[u] = expf(lg[u] - mxv[u >> 8]);
    }
    __syncthreads();
    for (int off = 128; off; off >>= 1) {
#pragma unroll
      for (int half = 0; half < 2; ++half) {
        const int u = tid + half * 512;
        if ((u & 255) < off) red[u] += red[u + off];
      }
      __syncthreads();
    }
    if (tid < 4) {
      const int r = tid;
      lzv[r] = logf(red[r * 256]);
      tokb[r] = amv[r];
      if (amv[r] != tgv[r]) mfs[r] = 0;
      out[(size_t)(b0 + r) * Tn + t] = (float)amv[r];
    }
    __syncthreads();
#pragma unroll
    for (int half = 0; half < 2; ++half) {
      const int u = tid + half * 512;
      const int r = u >> 8, v = u & 255;
      if (v == tgv[r]) llv[r] = -(lg[u] - mxv[r] - lzv[r]) * (1.f / 1024.f);
    }
    __syncthreads();
    if (tid == 0) run_loss += llv[0] + llv[1] + llv[2] + llv[3];
    __syncthreads();
  }

  if (tid == 0) {
    atomicAdd(wsloss, run_loss);
    atomicAdd(wscorrect, mfs[0] + mfs[1] + mfs[2] + mfs[3]);
  }
}

// ============ common epilogue ============
__global__ void ws_init(float* wsloss, int* wscorrect, unsigned* bar) {
  wsloss[0] = 0.f;
  wscorrect[0] = 0;
  if (bar) { bar[0] = 0u; bar[1] = 0u; }
}

__global__ void finisher(const float* __restrict__ wsloss,
                         const int* __restrict__ wscorrect, float* __restrict__ out) {
  const size_t base = (size_t)Bn * Tn + (size_t)Tn * Bn * Sn;
  out[base] = wsloss[0];
  out[base + 1] = (float)wscorrect[0];
}

extern "C" void kernel_launch(void* const* d_in, const int* in_sizes, int n_in,
                              void* d_out, int out_size, void* d_ws, size_t ws_size,
                              hipStream_t stream) {
  const float* state = (const float*)d_in[0];
  const float* enc = (const float*)d_in[1];
  const int* target = (const int*)d_in[2];
  const float* emb = (const float*)d_in[3];
  const float* Wa = (const float*)d_in[4];
  const float* bWa = (const float*)d_in[5];
  const float* Ua = (const float*)d_in[6];
  const float* bUa = (const float*)d_in[7];
  const float* Va = (const float*)d_in[8];
  const float* bVa = (const float*)d_in[9];
  const float* Wih0 = (const float*)d_in[10];
  const float* Whh0 = (const float*)d_in[11];
  const float* bih0 = (const float*)d_in[12];
  const float* bhh0 = (const float*)d_in[13];
  const float* Wih1 = (const float*)d_in[14];
  const float* Whh1 = (const float*)d_in[15];
  const float* bih1 = (const float*)d_in[16];
  const float* bhh1 = (const float*)d_in[17];
  const float* fcW = (const float*)d_in[18];
  const float* fcb = (const float*)d_in[19];
  float* out = (float*)d_out;

  const size_t KPROJ_FLOATS = (size_t)Sn * Bn * Hn;  // 64 MB

  const size_t N0IH = (size_t)G3 * (EHn / 4);
  const size_t NHH = (size_t)G3 * (Hn / 4);
  const size_t NWA = (size_t)Hn * (Hn / 4);
  const size_t NFC = (size_t)Vn * (Hn / 4);
  const size_t WT_TOTAL = N0IH + 3 * NHH + NWA + NFC;  // 15 MB of float4s
  const size_t NEED_A2 = WT_TOTAL * 16 + KPROJ_FLOATS * 4 + 256;

  const size_t NGIN = (size_t)Bn * EHn;   // 786432 floats
  const size_t NH = (size_t)Bn * Hn;      // 524288 floats
  const size_t COOP_EXTRA = NGIN + 4 * NH + NH;  // gin + h0A/B,h1A/B + qp
  const size_t NEED_COOP = NEED_A2 + COOP_EXTRA * 4 + 256;

  if (ws_size >= NEED_COOP) {
    float4* W0ihT = (float4*)d_ws;
    float4* W0hhT = W0ihT + N0IH;
    float4* W1ihT = W0hhT + NHH;
    float4* W1hhT = W1ihT + NHH;
    float4* WaT = W1hhT + NHH;
    float4* fcWT = WaT + NWA;
    float* kproj = (float*)(fcWT + NFC);
    float* gin = kproj + KPROJ_FLOATS;
    float* h0A = gin + NGIN;
    float* h0B = h0A + NH;
    float* h1A = h0B + NH;
    float* h1B = h1A + NH;
    float* qp = h1B + NH;
    unsigned* bar = (unsigned*)(qp + NH);
    float* wsloss = (float*)(bar + 2);
    int* wscorrect = (int*)(wsloss + 1);

    hipFuncSetAttribute((const void*)decoder_coop,
                        hipFuncAttributeMaxDynamicSharedMemorySize, COOP_LDSB);

    ws_init<<<1, 1, 0, stream>>>(wsloss, wscorrect, bar);
    transpose_pack<<<(int)((N0IH + 255) / 256), 256, 0, stream>>>(Wih0, W0ihT, G3, EHn);
    transpose_pack<<<(int)((NHH + 255) / 256), 256, 0, stream>>>(Whh0, W0hhT, G3, Hn);
    transpose_pack<<<(int)((NHH + 255) / 256), 256, 0, stream>>>(Wih1, W1ihT, G3, Hn);
    transpose_pack<<<(int)((NHH + 255) / 256), 256, 0, stream>>>(Whh1, W1hhT, G3, Hn);
    transpose_pack<<<(int)((NWA + 255) / 256), 256, 0, stream>>>(Wa, WaT, Hn, Hn);
    transpose_pack<<<(int)((NFC + 255) / 256), 256, 0, stream>>>(fcW, fcWT, Vn, Hn);
    gemm_bias<<<dim3(Hn / 64, (Sn * Bn) / 64), 256, 0, stream>>>(
        enc, Ua, bUa, kproj, Sn * Bn, Hn, Hn);
    decoder_coop<<<256, 1024, COOP_LDSB, stream>>>(
        state, enc, target, emb, WaT, bWa, Va, bVa, W0ihT, W0hhT, bih0, bhh0,
        W1ihT, W1hhT, bih1, bhh1, fcWT, fcb, kproj,
        gin, h0A, h0B, h1A, h1B, qp, bar, out, wsloss, wscorrect);
    finisher<<<1, 1, 0, stream>>>(wsloss, wscorrect, out);
  } else if (ws_size >= NEED_A2) {
    float4* W0ihT = (float4*)d_ws;
    float4* W0hhT = W0ihT + N0IH;
    float4* W1ihT = W0hhT + NHH;
    float4* W1hhT = W1ihT + NHH;
    float4* WaT = W1hhT + NHH;
    float4* fcWT = WaT + NWA;
    float* kproj = (float*)(fcWT + NFC);
    float* wsloss = kproj + KPROJ_FLOATS;
    int* wscorrect = (int*)(wsloss + 1);

    ws_init<<<1, 1, 0, stream>>>(wsloss, wscorrect, nullptr);
    transpose_pack<<<(int)((N0IH + 255) / 256), 256, 0, stream>>>(Wih0, W0ihT, G3, EHn);
    transpose_pack<<<(int)((NHH + 255) / 256), 256, 0, stream>>>(Whh0, W0hhT, G3, Hn);
    transpose_pack<<<(int)((NHH + 255) / 256), 256, 0, stream>>>(Wih1, W1ihT, G3, Hn);
    transpose_pack<<<(int)((NHH + 255) / 256), 256, 0, stream>>>(Whh1, W1hhT, G3, Hn);
    transpose_pack<<<(int)((NWA + 255) / 256), 256, 0, stream>>>(Wa, WaT, Hn, Hn);
    transpose_pack<<<(int)((NFC + 255) / 256), 256, 0, stream>>>(fcW, fcWT, Vn, Hn);
    gemm_bias<<<dim3(Hn / 64, (Sn * Bn) / 64), 256, 0, stream>>>(
        enc, Ua, bUa, kproj, Sn * Bn, Hn, Hn);
    decoder_r4y<<<Bn / 4, 1024, 0, stream>>>(
        state, enc, target, emb, WaT, bWa, Va, bVa, W0ihT, W0hhT, bih0, bhh0,
        W1ihT, W1hhT, bih1, bhh1, fcWT, fcb, kproj, out, wsloss, wscorrect);
    finisher<<<1, 1, 0, stream>>>(wsloss, wscorrect, out);
  } else {
    float* kproj = (float*)d_ws;
    float* wsloss = (float*)d_ws + KPROJ_FLOATS;
    int* wscorrect = (int*)((float*)d_ws + KPROJ_FLOATS + 1);
    ws_init<<<1, 1, 0, stream>>>(wsloss, wscorrect, nullptr);
    gemm_bias<<<dim3(Hn / 64, (Sn * Bn) / 64), 256, 0, stream>>>(
        enc, Ua, bUa, kproj, Sn * Bn, Hn, Hn);
    decoder_r4<<<Bn / 4, 512, 0, stream>>>(
        state, enc, target, emb, Wa, bWa, Va, bVa, Wih0, Whh0, bih0, bhh0,
        Wih1, Whh1, bih1, bhh1, fcW, fcb, kproj, out, wsloss, wscorrect);
    finisher<<<1, 1, 0, stream>>>(wsloss, wscorrect, out);
  }
}

// Round 6
// 10830.774 us; speedup vs baseline: 3.8651x; 3.8651x over previous
//
#include <hip/hip_runtime.h>
#include <math.h>

#define Hn 512
#define En 256
#define Sn 32
#define Bn 1024
#define Tn 32
#define Vn 256
#define G3 1536
#define EHn 768

// fma4 as a FUNCTION, not a macro (R6 lesson: macro param `w` collides with `.w`).
__device__ __forceinline__ void fma4(float& acc, const float4 w, const float4 x) {
  acc = fmaf(w.x, x.x, acc);
  acc = fmaf(w.y, x.y, acc);
  acc = fmaf(w.z, x.z, acc);
  acc = fmaf(w.w, x.w, acc);
}

// ============ one-time weight transpose: W[gate][K] -> WT4[k4*G + g] ============
__global__ __launch_bounds__(256) void transpose_pack(const float* __restrict__ W,
                                                      float4* __restrict__ WT4,
                                                      int G, int K) {
  const int idx = blockIdx.x * blockDim.x + threadIdx.x;
  const int n = G * (K >> 2);
  if (idx >= n) return;
  const int k4 = idx / G, g = idx - k4 * G;
  WT4[idx] = *(const float4*)(W + (size_t)g * K + (k4 << 2));
}

// ============ kproj GEMM: C(M,N) = A(M,K) @ W(N,K)^T + bias ============
__global__ __launch_bounds__(256) void gemm_bias(const float* __restrict__ A,
                                                 const float* __restrict__ Wt,
                                                 const float* __restrict__ bias,
                                                 float* __restrict__ C,
                                                 int M, int N, int K) {
  __shared__ float As[16][68];
  __shared__ float Ws[16][68];
  const int bm = blockIdx.y * 64;
  const int bn = blockIdx.x * 64;
  const int tid = threadIdx.x;
  const int tx = tid & 15;
  const int ty = tid >> 4;
  const int kk = tid & 15;
  const int r0 = tid >> 4;
  float acc[4][4] = {};
  for (int k0 = 0; k0 < K; k0 += 16) {
#pragma unroll
    for (int i = 0; i < 4; ++i) {
      const int m = r0 + (i << 4);
      As[kk][m] = A[(size_t)(bm + m) * K + (k0 + kk)];
      Ws[kk][m] = Wt[(size_t)(bn + m) * K + (k0 + kk)];
    }
    __syncthreads();
#pragma unroll
    for (int k = 0; k < 16; ++k) {
      const float4 a4 = *(const float4*)&As[k][ty * 4];
      const float4 w4 = *(const float4*)&Ws[k][tx * 4];
      const float av[4] = {a4.x, a4.y, a4.z, a4.w};
      const float wv[4] = {w4.x, w4.y, w4.z, w4.w};
#pragma unroll
      for (int i = 0; i < 4; ++i)
#pragma unroll
        for (int j = 0; j < 4; ++j) acc[i][j] = fmaf(av[i], wv[j], acc[i][j]);
    }
    __syncthreads();
  }
#pragma unroll
  for (int i = 0; i < 4; ++i) {
    const size_t m = (size_t)bm + ty * 4 + i;
    float* crow = C + m * N + bn + tx * 4;
#pragma unroll
    for (int j = 0; j < 4; ++j) crow[j] = acc[i][j] + bias[bn + tx * 4 + j];
  }
}

// ============ Path A3+: R=4, 1024-thread decoder, in-wave K-split, staggered ====
// History: R2 in-wave K-split (11 barriers) flat; R3 unroll flat; R4 2 blocks/CU
// -> desync'd weight windows spill L2 -> LLC-bound, 1.5x WORSE; R5 grid-coop ->
// agent fences invalidate per-XCD L2 -> 4x WORSE. Conclusion: synchronized
// block-local streaming is forced; residual limiter is the weight stream
// through L2 where all 32 same-XCD blocks hit the SAME lines simultaneously
// (same-bank serialization; demand ~4.2 TB/s/XCD = the L2 ceiling).
// R6: stagger each block's K-loop start by group sg=(bid>>3)&7 (same-XCD
// blocks get distinct groups under round-robin dispatch; perf-only heuristic).
// 8 groups spread the instantaneous read window over ~1.4MB (< 4MB L2 so lines
// stay shared / FETCH bounded) but across many banks (contention broken).

template <int KCI, int KCH>
__device__ __forceinline__ void gru_pair(
    int jj, int grp, int rotI, int rotH,
    const float4* __restrict__ WihT,
    const float4* __restrict__ WhhT,
    const float* __restrict__ x, int xstride,  // LDS [4][xstride]
    float* __restrict__ h,                     // LDS [4][Hn]
    const float* __restrict__ bih, const float* __restrict__ bhh) {
  float ar[4] = {}, az[4] = {}, ain[4] = {}, ahn[4] = {};
  {
    const int k0 = grp * KCI;
    const float4* w0 = WihT + jj + (size_t)k0 * G3;
    const float4* w1 = WihT + jj + 512 + (size_t)k0 * G3;
    const float4* w2 = WihT + jj + 1024 + (size_t)k0 * G3;
    for (int ii = 0; ii < KCI; ii += 2) {
      int k4 = ii + rotI;
      if (k4 >= KCI) k4 -= KCI;  // uniform scalar wrap (stagger start)
#pragma unroll
      for (int u = 0; u < 2; ++u) {
        const float4 a = w0[(size_t)(k4 + u) * G3];
        const float4 b = w1[(size_t)(k4 + u) * G3];
        const float4 c = w2[(size_t)(k4 + u) * G3];
#pragma unroll
        for (int r = 0; r < 4; ++r) {
          const float4 xv = ((const float4*)(x + r * xstride))[k0 + k4 + u];
          fma4(ar[r], a, xv);
          fma4(az[r], b, xv);
          fma4(ain[r], c, xv);
        }
      }
    }
  }
  {
    const int k0 = grp * KCH;
    const float4* w0 = WhhT + jj + (size_t)k0 * G3;
    const float4* w1 = WhhT + jj + 512 + (size_t)k0 * G3;
    const float4* w2 = WhhT + jj + 1024 + (size_t)k0 * G3;
    for (int ii = 0; ii < KCH; ii += 2) {
      int k4 = ii + rotH;
      if (k4 >= KCH) k4 -= KCH;
#pragma unroll
      for (int u = 0; u < 2; ++u) {
        const float4 a = w0[(size_t)(k4 + u) * G3];
        const float4 b = w1[(size_t)(k4 + u) * G3];
        const float4 c = w2[(size_t)(k4 + u) * G3];
#pragma unroll
        for (int r = 0; r < 4; ++r) {
          const float4 xv = ((const float4*)(h + r * Hn))[k0 + k4 + u];
          fma4(ar[r], a, xv);
          fma4(az[r], b, xv);
          fma4(ahn[r], c, xv);
        }
      }
    }
  }
  // combine K-halves with the partner lane (same wave, lane^32)
#pragma unroll
  for (int r = 0; r < 4; ++r) {
    ar[r] += __shfl_xor(ar[r], 32);
    az[r] += __shfl_xor(az[r], 32);
    ain[r] += __shfl_xor(ain[r], 32);
    ahn[r] += __shfl_xor(ahn[r], 32);
  }
  // gate math: grp 0 -> rows 0,1 ; grp 1 -> rows 2,3 (static selects, rule #20)
  const float bir = bih[jj], biz = bih[jj + 512], bin = bih[jj + 1024];
  const float bhr = bhh[jj], bhz = bhh[jj + 512], bhn = bhh[jj + 1024];
  const int r2 = grp * 2;
  const float s0r = (grp ? ar[2] : ar[0]) + bir + bhr;
  const float s0z = (grp ? az[2] : az[0]) + biz + bhz;
  const float s0i = (grp ? ain[2] : ain[0]) + bin;
  const float s0h = (grp ? ahn[2] : ahn[0]) + bhn;
  const float s1r = (grp ? ar[3] : ar[1]) + bir + bhr;
  const float s1z = (grp ? az[3] : az[1]) + biz + bhz;
  const float s1i = (grp ? ain[3] : ain[1]) + bin;
  const float s1h = (grp ? ahn[3] : ahn[1]) + bhn;
  const float rg0 = 1.f / (1.f + expf(-s0r));
  const float zg0 = 1.f / (1.f + expf(-s0z));
  const float ng0 = tanhf(s0i + rg0 * s0h);
  const float rg1 = 1.f / (1.f + expf(-s1r));
  const float zg1 = 1.f / (1.f + expf(-s1z));
  const float ng1 = tanhf(s1i + rg1 * s1h);
  const float h0old = h[(r2 + 0) * Hn + jj];
  const float h1old = h[(r2 + 1) * Hn + jj];
  const float hn0 = (1.f - zg0) * ng0 + zg0 * h0old;
  const float hn1 = (1.f - zg1) * ng1 + zg1 * h1old;
  __syncthreads();  // all lanes done READING h before anyone writes it
  h[(r2 + 0) * Hn + jj] = hn0;
  h[(r2 + 1) * Hn + jj] = hn1;
  __syncthreads();
}

__global__ __launch_bounds__(1024) __attribute__((amdgpu_waves_per_eu(4, 4)))
void decoder_r4y(
    const float* __restrict__ state, const float* __restrict__ enc,
    const int* __restrict__ target, const float* __restrict__ emb,
    const float4* __restrict__ WaT, const float* __restrict__ bWa,
    const float* __restrict__ Va, const float* __restrict__ bVa,
    const float4* __restrict__ W0ihT, const float4* __restrict__ W0hhT,
    const float* __restrict__ bih0, const float* __restrict__ bhh0,
    const float4* __restrict__ W1ihT, const float4* __restrict__ W1hhT,
    const float* __restrict__ bih1, const float* __restrict__ bhh1,
    const float4* __restrict__ fcWT, const float* __restrict__ fcb,
    const float* __restrict__ kproj, float* __restrict__ out,
    float* __restrict__ wsloss, int* __restrict__ wscorrect) {
  __shared__ __attribute__((aligned(16))) float h0s[4 * Hn];
  __shared__ __attribute__((aligned(16))) float h1s[4 * Hn];
  __shared__ __attribute__((aligned(16))) float qps[4 * Hn];
  __shared__ __attribute__((aligned(16))) float gins[4 * EHn];
  __shared__ __attribute__((aligned(16))) float vas[Hn];
  __shared__ __attribute__((aligned(16))) float wrs[4 * Sn];
  __shared__ __attribute__((aligned(16))) float ep[1024];
  __shared__ float wred[16];
  __shared__ int wredi[16];
  __shared__ float mxv[4], lgt[4];
  __shared__ int tgv[4], tokb[4], mfs[4];

  const int tid = threadIdx.x;
  const int b0 = blockIdx.x * 4;
  const int jj = (tid & 31) | ((tid >> 6) << 5);  // 0..511, each twice
  const int grp = (tid >> 5) & 1;                 // K-half / row-group
  // stagger group: same-XCD blocks (bid mod 8 under round-robin) get distinct sg
  const int sg = ((int)blockIdx.x >> 3) & 7;
  const int rot8 = sg * 8;    // for kc=64 streams (qp, gru hh, gru1 ih)
  const int rot12 = sg * 12;  // for kc=96 stream (gru0 ih)
  const int rot16 = sg * 16;  // for kc=128 stream (fc)

  for (int i = tid; i < 4 * Hn; i += 1024) {
    const int r = i >> 9, j = i & 511;
    h0s[i] = state[(size_t)(b0 + r) * Hn + j];
    h1s[i] = state[(size_t)(Bn + b0 + r) * Hn + j];
  }
  if (tid < 512) vas[tid] = Va[tid];
  if (tid < 4) { tokb[tid] = 1; mfs[tid] = 1; }
  __syncthreads();

  float run_loss = 0.f;  // tid 0 only

  for (int t = 0; t < Tn; ++t) {
    // ---- qp = h1 @ Wa^T + bWa, in-wave K-split (staggered start) ----
    {
      const int kc = (Hn >> 2) >> 1;  // 64
      const int k0 = grp * kc;
      const float4* wp = WaT + jj + (size_t)k0 * Hn;
      float a0 = 0.f, a1 = 0.f, a2 = 0.f, a3 = 0.f;
      for (int ii = 0; ii < 64; ii += 2) {
        int k4 = ii + rot8;
        if (k4 >= 64) k4 -= 64;
#pragma unroll
        for (int u = 0; u < 2; ++u) {
          const float4 w = wp[(size_t)(k4 + u) * Hn];
          const float4 x0 = ((const float4*)(h1s))[k0 + k4 + u];
          const float4 x1 = ((const float4*)(h1s + Hn))[k0 + k4 + u];
          const float4 x2 = ((const float4*)(h1s + 2 * Hn))[k0 + k4 + u];
          const float4 x3 = ((const float4*)(h1s + 3 * Hn))[k0 + k4 + u];
          fma4(a0, w, x0); fma4(a1, w, x1); fma4(a2, w, x2); fma4(a3, w, x3);
        }
      }
      a0 += __shfl_xor(a0, 32);
      a1 += __shfl_xor(a1, 32);
      a2 += __shfl_xor(a2, 32);
      a3 += __shfl_xor(a3, 32);
      const float bb = bWa[jj];
      if (!grp) {
        qps[jj] = a0 + bb;
        qps[Hn + jj] = a1 + bb;
      } else {
        qps[2 * Hn + jj] = a2 + bb;
        qps[3 * Hn + jj] = a3 + bb;
      }
    }
    __syncthreads();  // B1
    // ---- e: 8 threads per (r,s) pair; kproj streamed from global ----
    {
      const int p = tid >> 3, q = tid & 7;  // p = r*32+s
      const int r = p >> 5, s = p & 31;
      const float4* kp4 = (const float4*)(kproj + ((size_t)s * Bn + (b0 + r)) * Hn);
      const float4* qp4 = (const float4*)(qps + r * Hn);
      const float4* va4 = (const float4*)vas;
      float partial = 0.f;
      for (int i = 0; i < 16; i += 2) {
#pragma unroll
        for (int u = 0; u < 2; ++u) {
          const int f = q + ((i + u) << 3);
          const float4 k4 = kp4[f], q4 = qp4[f], v4 = va4[f];
          partial += v4.x * tanhf(q4.x + k4.x);
          partial += v4.y * tanhf(q4.y + k4.y);
          partial += v4.z * tanhf(q4.z + k4.z);
          partial += v4.w * tanhf(q4.w + k4.w);
        }
      }
      ep[tid] = partial;
    }
    __syncthreads();  // B2
    if (tid < 128) {
      float e = ep[tid * 8] + ep[tid * 8 + 1] + ep[tid * 8 + 2] + ep[tid * 8 + 3] +
                ep[tid * 8 + 4] + ep[tid * 8 + 5] + ep[tid * 8 + 6] + ep[tid * 8 + 7] +
                bVa[0];
      float m = e;
#pragma unroll
      for (int off = 16; off; off >>= 1) m = fmaxf(m, __shfl_xor(m, off));
      const float ex = expf(e - m);
      float ss = ex;
#pragma unroll
      for (int off = 16; off; off >>= 1) ss += __shfl_xor(ss, off);
      const float w = ex / ss;
      const int r = tid >> 5, s = tid & 31;
      wrs[tid] = w;
      out[(size_t)(Bn * Tn) + (size_t)t * (Bn * Sn) + (size_t)(b0 + r) * Sn + s] = w;
    }
    __syncthreads();  // B3
    // ---- context (2 rows per thread) + relu(emb[tok]) -> gin; preload target ----
    {
      const int h = tid & 511, rp = tid >> 9;  // rows 2rp, 2rp+1
      float c0 = 0.f, c1 = 0.f;
      const float* w0 = wrs + (2 * rp) * 32;
      const float* w1 = wrs + (2 * rp + 1) * 32;
#pragma unroll 4
      for (int s = 0; s < Sn; ++s) {
        const size_t base = ((size_t)s * Bn + b0 + 2 * rp) * Hn + h;
        c0 = fmaf(w0[s], enc[base], c0);
        c1 = fmaf(w1[s], enc[base + Hn], c1);
      }
      gins[(2 * rp) * EHn + En + h] = c0;
      gins[(2 * rp + 1) * EHn + En + h] = c1;
    }
    {
      const int r = tid >> 8, j = tid & 255;
      gins[r * EHn + j] = fmaxf(emb[(size_t)tokb[r] * En + j], 0.f);
    }
    if (tid < 4) tgv[tid] = target[(size_t)(b0 + tid) * Tn + t];
    __syncthreads();  // B4
    // ---- GRU layers (in-wave K-split; staggered; 2 barriers each) ----
    gru_pair<96, 64>(jj, grp, rot12, rot8, W0ihT, W0hhT, gins, EHn, h0s, bih0, bhh0);
    gru_pair<64, 64>(jj, grp, rot8, rot8, W1ihT, W1hhT, h0s, Hn, h1s, bih1, bhh1);
    // ---- fc: one (v, row) per thread; staggered; logit stays in a register ----
    const int v = tid & 255, rr = tid >> 8;
    float l;
    {
      const float4* wp = fcWT + v;
      const float4* xr = (const float4*)(h1s + rr * Hn);
      float acc = 0.f;
      for (int ii = 0; ii < (Hn >> 2); ii += 4) {
        int k4 = ii + rot16;
        if (k4 >= (Hn >> 2)) k4 -= (Hn >> 2);
#pragma unroll
        for (int u = 0; u < 4; ++u) {
          const float4 w = wp[(size_t)(k4 + u) * Vn];
          fma4(acc, w, xr[k4 + u]);
        }
      }
      l = acc + fcb[v];
    }
    if (v == tgv[rr]) lgt[rr] = l;  // target logit for the loss
    // wave-level argmax (first-max tie-break), 4 waves per row
    {
      float m = l;
      int mi = v;
#pragma unroll
      for (int off = 32; off; off >>= 1) {
        const float om = __shfl_xor(m, off);
        const int oi = __shfl_xor(mi, off);
        if (om > m || (om == m && oi < mi)) { m = om; mi = oi; }
      }
      if ((tid & 63) == 0) {
        wred[tid >> 6] = m;
        wredi[tid >> 6] = mi;
      }
    }
    __syncthreads();  // B9
    int am_r = 0;  // valid only in tid<4
    if (tid < 4) {
      float bm = wred[4 * tid];
      int bi = wredi[4 * tid];
#pragma unroll
      for (int q = 1; q < 4; ++q) {
        const float o = wred[4 * tid + q];
        const int oi = wredi[4 * tid + q];
        if (o > bm || (o == bm && oi < bi)) { bm = o; bi = oi; }
      }
      mxv[tid] = bm;
      am_r = bi;
    }
    __syncthreads();  // B10
    {
      float ex = expf(l - mxv[rr]);
#pragma unroll
      for (int off = 32; off; off >>= 1) ex += __shfl_xor(ex, off);
      if ((tid & 63) == 0) wred[tid >> 6] = ex;
    }
    __syncthreads();  // B11
    if (tid < 4) {
      tokb[tid] = am_r;
      if (am_r != tgv[tid]) mfs[tid] = 0;
      out[(size_t)(b0 + tid) * Tn + t] = (float)am_r;
    }
    if (tid == 0) {
#pragma unroll
      for (int r = 0; r < 4; ++r) {
        const float s = wred[4 * r] + wred[4 * r + 1] + wred[4 * r + 2] + wred[4 * r + 3];
        run_loss += -(lgt[r] - mxv[r] - logf(s)) * (1.f / 1024.f);
      }
    }
    // no trailing barrier needed: next-step hazards are covered by B1..B11
  }

  __syncthreads();
  if (tid == 0) {
    atomicAdd(wsloss, run_loss);
    atomicAdd(wscorrect, mfs[0] + mfs[1] + mfs[2] + mfs[3]);
  }
}

// ============ Path A fallback: R5-verified decoder (uncoalesced weights) ========
__device__ __forceinline__ void gru_layer4(int j, const float* __restrict__ x,
                                           int xstride, int K,
                                           float* __restrict__ h,
                                           const float* __restrict__ Wih,
                                           const float* __restrict__ Whh,
                                           const float* __restrict__ bih,
                                           const float* __restrict__ bhh) {
  float ai0[4] = {}, ai1[4] = {}, ai2[4] = {};
  {
    const float4* w0 = (const float4*)(Wih + (size_t)j * K);
    const float4* w1 = (const float4*)(Wih + (size_t)(j + 512) * K);
    const float4* w2 = (const float4*)(Wih + (size_t)(j + 1024) * K);
    for (int i = 0; i < K / 4; ++i) {
      const float4 a = w0[i], b = w1[i], c = w2[i];
#pragma unroll
      for (int r = 0; r < 4; ++r) {
        const float4 xv = ((const float4*)(x + r * xstride))[i];
        fma4(ai0[r], a, xv); fma4(ai1[r], b, xv); fma4(ai2[r], c, xv);
      }
    }
  }
  float ah0[4] = {}, ah1[4] = {}, ah2[4] = {};
  {
    const float4* w0 = (const float4*)(Whh + (size_t)j * Hn);
    const float4* w1 = (const float4*)(Whh + (size_t)(j + 512) * Hn);
    const float4* w2 = (const float4*)(Whh + (size_t)(j + 1024) * Hn);
    for (int i = 0; i < Hn / 4; ++i) {
      const float4 a = w0[i], b = w1[i], c = w2[i];
#pragma unroll
      for (int r = 0; r < 4; ++r) {
        const float4 xv = ((const float4*)(h + r * Hn))[i];
        fma4(ah0[r], a, xv); fma4(ah1[r], b, xv); fma4(ah2[r], c, xv);
      }
    }
  }
  const float bi0 = bih[j], bi1 = bih[j + 512], bi2 = bih[j + 1024];
  const float bh0 = bhh[j], bh1 = bhh[j + 512], bh2 = bhh[j + 1024];
  float hn[4];
#pragma unroll
  for (int r = 0; r < 4; ++r) {
    const float ir = ai0[r] + bi0, iz = ai1[r] + bi1, in_ = ai2[r] + bi2;
    const float hr = ah0[r] + bh0, hz = ah1[r] + bh1, hnn = ah2[r] + bh2;
    const float rg = 1.f / (1.f + expf(-(ir + hr)));
    const float zg = 1.f / (1.f + expf(-(iz + hz)));
    const float ng = tanhf(in_ + rg * hnn);
    hn[r] = (1.f - zg) * ng + zg * h[r * Hn + j];
  }
  __syncthreads();
#pragma unroll
  for (int r = 0; r < 4; ++r) h[r * Hn + j] = hn[r];
  __syncthreads();
}

__global__ __launch_bounds__(512, 1) void decoder_r4(
    const float* __restrict__ state, const float* __restrict__ enc,
    const int* __restrict__ target, const float* __restrict__ emb,
    const float* __restrict__ Wa, const float* __restrict__ bWa,
    const float* __restrict__ Va, const float* __restrict__ bVa,
    const float* __restrict__ Wih0, const float* __restrict__ Whh0,
    const float* __restrict__ bih0, const float* __restrict__ bhh0,
    const float* __restrict__ Wih1, const float* __restrict__ Whh1,
    const float* __restrict__ bih1, const float* __restrict__ bhh1,
    const float* __restrict__ fcW, const float* __restrict__ fcb,
    const float* __restrict__ kproj, float* __restrict__ out,
    float* __restrict__ wsloss, int* __restrict__ wscorrect) {
  __shared__ float h0s[4 * Hn], h1s[4 * Hn], qps[4 * Hn], gins[4 * EHn], vas[Hn];
  __shared__ float red[1024], lg[1024];
  __shared__ int ridx[1024];
  __shared__ float wrs[4 * Sn];
  __shared__ float mxv[4], lzv[4], llv[4];
  __shared__ int amv[4], tgv[4], tokb[4], mfs[4];

  const int tid = threadIdx.x;
  const int b0 = blockIdx.x * 4;

  for (int i = tid; i < 4 * Hn; i += 512) {
    const int r = i >> 9, j = i & 511;
    h0s[i] = state[(size_t)(b0 + r) * Hn + j];
    h1s[i] = state[(size_t)(Bn + b0 + r) * Hn + j];
  }
  vas[tid] = Va[tid];
  if (tid < 4) { tokb[tid] = 1; mfs[tid] = 1; llv[tid] = 0.f; }
  __syncthreads();

  float run_loss = 0.f;

  for (int t = 0; t < Tn; ++t) {
    {
      const int h = tid;
      const float4* w4 = (const float4*)(Wa + (size_t)h * Hn);
      float a0 = 0.f, a1 = 0.f, a2 = 0.f, a3 = 0.f;
      for (int i = 0; i < Hn / 4; ++i) {
        const float4 w = w4[i];
        const float4 x0 = ((const float4*)(h1s))[i];
        const float4 x1 = ((const float4*)(h1s + Hn))[i];
        const float4 x2 = ((const float4*)(h1s + 2 * Hn))[i];
        const float4 x3 = ((const float4*)(h1s + 3 * Hn))[i];
        fma4(a0, w, x0); fma4(a1, w, x1); fma4(a2, w, x2); fma4(a3, w, x3);
      }
      const float bb = bWa[h];
      qps[h] = a0 + bb; qps[Hn + h] = a1 + bb;
      qps[2 * Hn + h] = a2 + bb; qps[3 * Hn + h] = a3 + bb;
    }
    __syncthreads();
    {
      const int p = tid >> 2, q = tid & 3;
      const int r = p >> 5, s = p & 31;
      const float4* kp4 = (const float4*)(kproj + ((size_t)s * Bn + (b0 + r)) * Hn);
      const float4* qp4 = (const float4*)(qps + r * Hn);
      const float4* va4 = (const float4*)vas;
      float partial = 0.f;
      for (int i = 0; i < 32; ++i) {
        const int f = q + (i << 2);
        const float4 k4 = kp4[f], q4 = qp4[f], v4 = va4[f];
        partial += v4.x * tanhf(q4.x + k4.x);
        partial += v4.y * tanhf(q4.y + k4.y);
        partial += v4.z * tanhf(q4.z + k4.z);
        partial += v4.w * tanhf(q4.w + k4.w);
      }
      red[tid] = partial;
    }
    __syncthreads();
    if (tid < 128) {
      float e = red[tid * 4] + red[tid * 4 + 1] + red[tid * 4 + 2] + red[tid * 4 + 3] + bVa[0];
      float m = e;
#pragma unroll
      for (int off = 16; off; off >>= 1) m = fmaxf(m, __shfl_xor(m, off));
      const float ex = expf(e - m);
      float ss = ex;
#pragma unroll
      for (int off = 16; off; off >>= 1) ss += __shfl_xor(ss, off);
      const float w = ex / ss;
      const int r = tid >> 5, s = tid & 31;
      wrs[tid] = w;
      out[(size_t)(Bn * Tn) + (size_t)t * (Bn * Sn) + (size_t)(b0 + r) * Sn + s] = w;
    }
    __syncthreads();
    {
      const int h = tid;
      float c0 = 0.f, c1 = 0.f, c2 = 0.f, c3 = 0.f;
      for (int s = 0; s < Sn; ++s) {
        const size_t base = ((size_t)s * Bn + b0) * Hn + h;
        c0 = fmaf(wrs[s], enc[base], c0);
        c1 = fmaf(wrs[32 + s], enc[base + Hn], c1);
        c2 = fmaf(wrs[64 + s], enc[base + 2 * Hn], c2);
        c3 = fmaf(wrs[96 + s], enc[base + 3 * Hn], c3);
      }
      gins[En + h] = c0; gins[EHn + En + h] = c1;
      gins[2 * EHn + En + h] = c2; gins[3 * EHn + En + h] = c3;
    }
    for (int i = tid; i < 4 * En; i += 512) {
      const int r = i >> 8, j = i & 255;
      gins[r * EHn + j] = fmaxf(emb[(size_t)tokb[r] * En + j], 0.f);
    }
    __syncthreads();
    gru_layer4(tid, gins, EHn, EHn, h0s, Wih0, Whh0, bih0, bhh0);
    gru_layer4(tid, h0s, Hn, Hn, h1s, Wih1, Whh1, bih1, bhh1);
    {
      const int v = tid & 255;
      const int rA = tid >> 8, rB = rA + 2;
      const float4* w4 = (const float4*)(fcW + (size_t)v * Hn);
      const float4* xA = (const float4*)(h1s + rA * Hn);
      const float4* xB = (const float4*)(h1s + rB * Hn);
      float aA = 0.f, aB = 0.f;
      for (int i = 0; i < Hn / 4; ++i) {
        const float4 w = w4[i];
        const float4 a = xA[i], b = xB[i];
        fma4(aA, w, a); fma4(aB, w, b);
      }
      const float fb = fcb[v];
      const float lA = aA + fb, lB = aB + fb;
      lg[rA * 256 + v] = lA; red[rA * 256 + v] = lA; ridx[rA * 256 + v] = v;
      lg[rB * 256 + v] = lB; red[rB * 256 + v] = lB; ridx[rB * 256 + v] = v;
    }
    __syncthreads();
    for (int off = 128; off; off >>= 1) {
#pragma unroll
      for (int half = 0; half < 2; ++half) {
        const int u = tid + half * 512;
        if ((u & 255) < off) {
          const int u2 = u + off;
          const float o = red[u2]; const int oi = ridx[u2];
          if (o > red[u] || (o == red[u] && oi < ridx[u])) { red[u] = o; ridx[u] = oi; }
        }
      }
      __syncthreads();
    }
    if (tid < 4) {
      mxv[tid] = red[tid * 256];
      amv[tid] = ridx[tid * 256];
      tgv[tid] = target[(size_t)(b0 + tid) * Tn + t];
    }
    __syncthreads();
#pragma unroll
    for (int half = 0; half < 2; ++half) {
      const int u = tid + half * 512;
      red[u] = expf(lg[u] - mxv[u >> 8]);
    }
    __syncthreads();
    for (int off = 128; off; off >>= 1) {
#pragma unroll
      for (int half = 0; half < 2; ++half) {
        const int u = tid + half * 512;
        if ((u & 255) < off) red[u] += red[u + off];
      }
      __syncthreads();
    }
    if (tid < 4) {
      const int r = tid;
      lzv[r] = logf(red[r * 256]);
      tokb[r] = amv[r];
      if (amv[r] != tgv[r]) mfs[r] = 0;
      out[(size_t)(b0 + r) * Tn + t] = (float)amv[r];
    }
    __syncthreads();
#pragma unroll
    for (int half = 0; half < 2; ++half) {
      const int u = tid + half * 512;
      const int r = u >> 8, v = u & 255;
      if (v == tgv[r]) llv[r] = -(lg[u] - mxv[r] - lzv[r]) * (1.f / 1024.f);
    }
    __syncthreads();
    if (tid == 0) run_loss += llv[0] + llv[1] + llv[2] + llv[3];
    __syncthreads();
  }

  if (tid == 0) {
    atomicAdd(wsloss, run_loss);
    atomicAdd(wscorrect, mfs[0] + mfs[1] + mfs[2] + mfs[3]);
  }
}

// ============ common epilogue ============
__global__ void ws_init(float* wsloss, int* wscorrect) {
  wsloss[0] = 0.f;
  wscorrect[0] = 0;
}

__global__ void finisher(const float* __restrict__ wsloss,
                         const int* __restrict__ wscorrect, float* __restrict__ out) {
  const size_t base = (size_t)Bn * Tn + (size_t)Tn * Bn * Sn;
  out[base] = wsloss[0];
  out[base + 1] = (float)wscorrect[0];
}

extern "C" void kernel_launch(void* const* d_in, const int* in_sizes, int n_in,
                              void* d_out, int out_size, void* d_ws, size_t ws_size,
                              hipStream_t stream) {
  const float* state = (const float*)d_in[0];
  const float* enc = (const float*)d_in[1];
  const int* target = (const int*)d_in[2];
  const float* emb = (const float*)d_in[3];
  const float* Wa = (const float*)d_in[4];
  const float* bWa = (const float*)d_in[5];
  const float* Ua = (const float*)d_in[6];
  const float* bUa = (const float*)d_in[7];
  const float* Va = (const float*)d_in[8];
  const float* bVa = (const float*)d_in[9];
  const float* Wih0 = (const float*)d_in[10];
  const float* Whh0 = (const float*)d_in[11];
  const float* bih0 = (const float*)d_in[12];
  const float* bhh0 = (const float*)d_in[13];
  const float* Wih1 = (const float*)d_in[14];
  const float* Whh1 = (const float*)d_in[15];
  const float* bih1 = (const float*)d_in[16];
  const float* bhh1 = (const float*)d_in[17];
  const float* fcW = (const float*)d_in[18];
  const float* fcb = (const float*)d_in[19];
  float* out = (float*)d_out;

  const size_t KPROJ_FLOATS = (size_t)Sn * Bn * Hn;  // 64 MB

  const size_t N0IH = (size_t)G3 * (EHn / 4);
  const size_t NHH = (size_t)G3 * (Hn / 4);
  const size_t NWA = (size_t)Hn * (Hn / 4);
  const size_t NFC = (size_t)Vn * (Hn / 4);
  const size_t WT_TOTAL = N0IH + 3 * NHH + NWA + NFC;  // 15 MB
  const size_t NEED_A2 = WT_TOTAL * 16 + KPROJ_FLOATS * 4 + 256;

  if (ws_size >= NEED_A2) {
    float4* W0ihT = (float4*)d_ws;
    float4* W0hhT = W0ihT + N0IH;
    float4* W1ihT = W0hhT + NHH;
    float4* W1hhT = W1ihT + NHH;
    float4* WaT = W1hhT + NHH;
    float4* fcWT = WaT + NWA;
    float* kproj = (float*)(fcWT + NFC);
    float* wsloss = kproj + KPROJ_FLOATS;
    int* wscorrect = (int*)(wsloss + 1);

    ws_init<<<1, 1, 0, stream>>>(wsloss, wscorrect);
    transpose_pack<<<(int)((N0IH + 255) / 256), 256, 0, stream>>>(Wih0, W0ihT, G3, EHn);
    transpose_pack<<<(int)((NHH + 255) / 256), 256, 0, stream>>>(Whh0, W0hhT, G3, Hn);
    transpose_pack<<<(int)((NHH + 255) / 256), 256, 0, stream>>>(Wih1, W1ihT, G3, Hn);
    transpose_pack<<<(int)((NHH + 255) / 256), 256, 0, stream>>>(Whh1, W1hhT, G3, Hn);
    transpose_pack<<<(int)((NWA + 255) / 256), 256, 0, stream>>>(Wa, WaT, Hn, Hn);
    transpose_pack<<<(int)((NFC + 255) / 256), 256, 0, stream>>>(fcW, fcWT, Vn, Hn);
    gemm_bias<<<dim3(Hn / 64, (Sn * Bn) / 64), 256, 0, stream>>>(
        enc, Ua, bUa, kproj, Sn * Bn, Hn, Hn);
    decoder_r4y<<<Bn / 4, 1024, 0, stream>>>(
        state, enc, target, emb, WaT, bWa, Va, bVa, W0ihT, W0hhT, bih0, bhh0,
        W1ihT, W1hhT, bih1, bhh1, fcWT, fcb, kproj, out, wsloss, wscorrect);
    finisher<<<1, 1, 0, stream>>>(wsloss, wscorrect, out);
  } else {
    float* kproj = (float*)d_ws;
    float* wsloss = (float*)d_ws + KPROJ_FLOATS;
    int* wscorrect = (int*)((float*)d_ws + KPROJ_FLOATS + 1);
    ws_init<<<1, 1, 0, stream>>>(wsloss, wscorrect);
    gemm_bias<<<dim3(Hn / 64, (Sn * Bn) / 64), 256, 0, stream>>>(
        enc, Ua, bUa, kproj, Sn * Bn, Hn, Hn);
    decoder_r4<<<Bn / 4, 512, 0, stream>>>(
        state, enc, target, emb, Wa, bWa, Va, bVa, Wih0, Whh0, bih0, bhh0,
        Wih1, Whh1, bih1, bhh1, fcW, fcb, kproj, out, wsloss, wscorrect);
    finisher<<<1, 1, 0, stream>>>(wsloss, wscorrect, out);
  }
}

// Round 7
// 10244.751 us; speedup vs baseline: 4.0862x; 1.0572x over previous
//
#include <hip/hip_runtime.h>
#include <math.h>

#define Hn 512
#define En 256
#define Sn 32
#define Bn 1024
#define Tn 32
#define Vn 256
#define G3 1536
#define EHn 768

// fma4 as a FUNCTION, not a macro (R6 lesson: macro param `w` collides with `.w`).
__device__ __forceinline__ void fma4(float& acc, const float4 w, const float4 x) {
  acc = fmaf(w.x, x.x, acc);
  acc = fmaf(w.y, x.y, acc);
  acc = fmaf(w.z, x.z, acc);
  acc = fmaf(w.w, x.w, acc);
}

// ============ one-time weight transpose: W[gate][K] -> WT4[k4*G + g] ============
__global__ __launch_bounds__(256) void transpose_pack(const float* __restrict__ W,
                                                      float4* __restrict__ WT4,
                                                      int G, int K) {
  const int idx = blockIdx.x * blockDim.x + threadIdx.x;
  const int n = G * (K >> 2);
  if (idx >= n) return;
  const int k4 = idx / G, g = idx - k4 * G;
  WT4[idx] = *(const float4*)(W + (size_t)g * K + (k4 << 2));
}

// ============ kproj GEMM: C(M,N) = A(M,K) @ W(N,K)^T + bias ============
__global__ __launch_bounds__(256) void gemm_bias(const float* __restrict__ A,
                                                 const float* __restrict__ Wt,
                                                 const float* __restrict__ bias,
                                                 float* __restrict__ C,
                                                 int M, int N, int K) {
  __shared__ float As[16][68];
  __shared__ float Ws[16][68];
  const int bm = blockIdx.y * 64;
  const int bn = blockIdx.x * 64;
  const int tid = threadIdx.x;
  const int tx = tid & 15;
  const int ty = tid >> 4;
  const int kk = tid & 15;
  const int r0 = tid >> 4;
  float acc[4][4] = {};
  for (int k0 = 0; k0 < K; k0 += 16) {
#pragma unroll
    for (int i = 0; i < 4; ++i) {
      const int m = r0 + (i << 4);
      As[kk][m] = A[(size_t)(bm + m) * K + (k0 + kk)];
      Ws[kk][m] = Wt[(size_t)(bn + m) * K + (k0 + kk)];
    }
    __syncthreads();
#pragma unroll
    for (int k = 0; k < 16; ++k) {
      const float4 a4 = *(const float4*)&As[k][ty * 4];
      const float4 w4 = *(const float4*)&Ws[k][tx * 4];
      const float av[4] = {a4.x, a4.y, a4.z, a4.w};
      const float wv[4] = {w4.x, w4.y, w4.z, w4.w};
#pragma unroll
      for (int i = 0; i < 4; ++i)
#pragma unroll
        for (int j = 0; j < 4; ++j) acc[i][j] = fmaf(av[i], wv[j], acc[i][j]);
    }
    __syncthreads();
  }
#pragma unroll
  for (int i = 0; i < 4; ++i) {
    const size_t m = (size_t)bm + ty * 4 + i;
    float* crow = C + m * N + bn + tx * 4;
#pragma unroll
    for (int j = 0; j < 4; ++j) crow[j] = acc[i][j] + bias[bn + tx * 4 + j];
  }
}

// =================== Path G: per-phase GEMM decomposition =====================
// R7: R0-R6 proved the persistent-block design is bound by its own GEMV
// decomposition: every block re-reads all 15.5MB weights each step -> 127 GB
// streamed at ~12 TB/s = the measured 10 ms. Desync (R4/R6) or fences (R5)
// only make it worse. Fix: per-phase KERNELS. Kernel boundaries provide grid
// sync with natural coherence; GRU becomes a tiled GEMM (x staged in LDS,
// 32-row x 32-gate-col tiles) cutting weight traffic 256x -> 32x per step.

// ---- K1: attention + gin assembly (block-local 4 rows, weight-free) ----
__global__ __launch_bounds__(1024) void attn_gin(
    const float* __restrict__ qp, const float* __restrict__ kproj,
    const float* __restrict__ enc, const float* __restrict__ emb,
    const int* __restrict__ tok, const float* __restrict__ Va,
    const float* __restrict__ bVa, float* __restrict__ gin,
    float* __restrict__ out, int t) {
  __shared__ __attribute__((aligned(16))) float qps[4 * Hn];
  __shared__ __attribute__((aligned(16))) float vas[Hn];
  __shared__ __attribute__((aligned(16))) float ep[1024];
  __shared__ float wrs[128];
  __shared__ int tokb[4];
  const int tid = threadIdx.x;
  const int b0 = blockIdx.x * 4;
  for (int i = tid; i < 4 * Hn; i += 1024)
    qps[i] = qp[(size_t)(b0 + (i >> 9)) * Hn + (i & 511)];
  if (tid < 512) vas[tid] = Va[tid];
  if (tid < 4) tokb[tid] = tok[b0 + tid];
  __syncthreads();
  // e: 8 threads per (r,s) pair
  {
    const int p = tid >> 3, q = tid & 7;
    const int r = p >> 5, s = p & 31;
    const float4* kp4 = (const float4*)(kproj + ((size_t)s * Bn + (b0 + r)) * Hn);
    const float4* qp4 = (const float4*)(qps + r * Hn);
    const float4* va4 = (const float4*)vas;
    float partial = 0.f;
    for (int i = 0; i < 16; i += 2) {
#pragma unroll
      for (int u = 0; u < 2; ++u) {
        const int f = q + ((i + u) << 3);
        const float4 k4 = kp4[f], q4 = qp4[f], v4 = va4[f];
        partial += v4.x * tanhf(q4.x + k4.x);
        partial += v4.y * tanhf(q4.y + k4.y);
        partial += v4.z * tanhf(q4.z + k4.z);
        partial += v4.w * tanhf(q4.w + k4.w);
      }
    }
    ep[tid] = partial;
  }
  __syncthreads();
  if (tid < 128) {
    float e = ep[tid * 8] + ep[tid * 8 + 1] + ep[tid * 8 + 2] + ep[tid * 8 + 3] +
              ep[tid * 8 + 4] + ep[tid * 8 + 5] + ep[tid * 8 + 6] + ep[tid * 8 + 7] +
              bVa[0];
    float m = e;
#pragma unroll
    for (int off = 16; off; off >>= 1) m = fmaxf(m, __shfl_xor(m, off));
    const float ex = expf(e - m);
    float ss = ex;
#pragma unroll
    for (int off = 16; off; off >>= 1) ss += __shfl_xor(ss, off);
    const float w = ex / ss;
    const int r = tid >> 5, s = tid & 31;
    wrs[tid] = w;
    out[(size_t)(Bn * Tn) + (size_t)t * (Bn * Sn) + (size_t)(b0 + r) * Sn + s] = w;
  }
  __syncthreads();
  // context (2 rows per thread) -> gin[.., 256..767]
  {
    const int h = tid & 511, rp = tid >> 9;
    float c0 = 0.f, c1 = 0.f;
    const float* w0 = wrs + (2 * rp) * 32;
    const float* w1 = wrs + (2 * rp + 1) * 32;
#pragma unroll 4
    for (int s = 0; s < Sn; ++s) {
      const size_t base = ((size_t)s * Bn + b0 + 2 * rp) * Hn + h;
      c0 = fmaf(w0[s], enc[base], c0);
      c1 = fmaf(w1[s], enc[base + Hn], c1);
    }
    gin[(size_t)(b0 + 2 * rp) * EHn + En + h] = c0;
    gin[(size_t)(b0 + 2 * rp + 1) * EHn + En + h] = c1;
  }
  // relu(emb[tok]) -> gin[.., 0..255]
  {
    const int r = tid >> 8, j = tid & 255;
    gin[(size_t)(b0 + r) * EHn + j] = fmaxf(emb[(size_t)tokb[r] * En + j], 0.f);
  }
}

// ---- K2/K3: GRU cell as tiled GEMM. Block = 32 rows x 32 gate-cols x3 gates.
// Grid (16 j, 32 m) = 512 blocks. x-tile staged in LDS; weights streamed
// (ty-redundant reads are L1-broadcast). i_n and h_n kept separate (PyTorch).
template <int KIH4>
__global__ __launch_bounds__(512) void gru_gemm(
    const float* __restrict__ xsrc, int xsF4,
    const float* __restrict__ hsrc,
    const float4* __restrict__ WihT, const float4* __restrict__ WhhT,
    const float* __restrict__ bih, const float* __restrict__ bhh,
    float* __restrict__ hdst) {
  __shared__ float4 xs4[32 * 32];  // 16 KB
  const int tid = threadIdx.x;
  const int J0 = blockIdx.x * 32;
  const int R0 = blockIdx.y * 32;
  const int tx = tid & 31;
  const int ty = tid >> 5;  // 0..15
  const int r0 = 2 * ty, r1 = r0 + 1;
  const int g0 = J0 + tx, g1 = g0 + 512, g2 = g0 + 1024;
  float ar0 = 0.f, az0 = 0.f, ai0 = 0.f, an0 = 0.f;
  float ar1 = 0.f, az1 = 0.f, ai1 = 0.f, an1 = 0.f;
  const float4* x4 = (const float4*)xsrc;
  for (int c = 0; c < KIH4 / 32; ++c) {
    __syncthreads();
#pragma unroll
    for (int i = 0; i < 2; ++i) {
      const int idx = tid + i * 512;
      const int row = idx >> 5, f = idx & 31;
      xs4[idx] = x4[(size_t)(R0 + row) * xsF4 + c * 32 + f];
    }
    __syncthreads();
#pragma unroll 2
    for (int k = 0; k < 32; ++k) {
      const size_t wb = (size_t)(c * 32 + k) * G3;
      const float4 wr = WihT[wb + g0];
      const float4 wz = WihT[wb + g1];
      const float4 wn = WihT[wb + g2];
      const float4 x0 = xs4[r0 * 32 + k];
      const float4 x1 = xs4[r1 * 32 + k];
      fma4(ar0, wr, x0); fma4(az0, wz, x0); fma4(ai0, wn, x0);
      fma4(ar1, wr, x1); fma4(az1, wz, x1); fma4(ai1, wn, x1);
    }
  }
  const float4* h4 = (const float4*)hsrc;
  for (int c = 0; c < 4; ++c) {  // K=512 -> 4 chunks of 32 f4
    __syncthreads();
#pragma unroll
    for (int i = 0; i < 2; ++i) {
      const int idx = tid + i * 512;
      const int row = idx >> 5, f = idx & 31;
      xs4[idx] = h4[(size_t)(R0 + row) * (Hn / 4) + c * 32 + f];
    }
    __syncthreads();
#pragma unroll 2
    for (int k = 0; k < 32; ++k) {
      const size_t wb = (size_t)(c * 32 + k) * G3;
      const float4 wr = WhhT[wb + g0];
      const float4 wz = WhhT[wb + g1];
      const float4 wn = WhhT[wb + g2];
      const float4 x0 = xs4[r0 * 32 + k];
      const float4 x1 = xs4[r1 * 32 + k];
      fma4(ar0, wr, x0); fma4(az0, wz, x0); fma4(an0, wn, x0);
      fma4(ar1, wr, x1); fma4(az1, wz, x1); fma4(an1, wn, x1);
    }
  }
  const float bir = bih[g0], biz = bih[g1], bin = bih[g2];
  const float bhr = bhh[g0], bhz = bhh[g1], bhn = bhh[g2];
  {
    const float rg = 1.f / (1.f + expf(-(ar0 + bir + bhr)));
    const float zg = 1.f / (1.f + expf(-(az0 + biz + bhz)));
    const float ng = tanhf(ai0 + bin + rg * (an0 + bhn));
    const float hold = hsrc[(size_t)(R0 + r0) * Hn + g0];
    hdst[(size_t)(R0 + r0) * Hn + g0] = (1.f - zg) * ng + zg * hold;
  }
  {
    const float rg = 1.f / (1.f + expf(-(ar1 + bir + bhr)));
    const float zg = 1.f / (1.f + expf(-(az1 + biz + bhz)));
    const float ng = tanhf(ai1 + bin + rg * (an1 + bhn));
    const float hold = hsrc[(size_t)(R0 + r1) * Hn + g0];
    hdst[(size_t)(R0 + r1) * Hn + g0] = (1.f - zg) * ng + zg * hold;
  }
}

// ---- K4: fc + argmax + loss + token + qp(t+1) (block-local 4 rows) ----
__global__ __launch_bounds__(1024) void fc_qp(
    const float* __restrict__ h1src,
    const float4* __restrict__ fcWT, const float* __restrict__ fcb,
    const float4* __restrict__ WaT, const float* __restrict__ bWa,
    const int* __restrict__ target, int t,
    float* __restrict__ qp, int* __restrict__ tok, int* __restrict__ mf,
    float* __restrict__ out, float* __restrict__ wsloss) {
  __shared__ __attribute__((aligned(16))) float h1s[4 * Hn];
  __shared__ float wred[16];
  __shared__ int wredi[16];
  __shared__ float mxv[4], lgt[4];
  __shared__ int tgv[4];
  const int tid = threadIdx.x;
  const int b0 = blockIdx.x * 4;
  for (int i = tid; i < 4 * Hn; i += 1024)
    h1s[i] = h1src[(size_t)(b0 + (i >> 9)) * Hn + (i & 511)];
  if (tid < 4) tgv[tid] = target[(size_t)(b0 + tid) * Tn + t];
  __syncthreads();
  const int v = tid & 255, rr = tid >> 8;
  float l;
  {
    const float4* wp = fcWT + v;
    const float4* xr = (const float4*)(h1s + rr * Hn);
    float acc = 0.f;
    for (int k4 = 0; k4 < (Hn >> 2); k4 += 4) {
#pragma unroll
      for (int u = 0; u < 4; ++u) {
        const float4 w = wp[(size_t)(k4 + u) * Vn];
        fma4(acc, w, xr[k4 + u]);
      }
    }
    l = acc + fcb[v];
  }
  if (v == tgv[rr]) lgt[rr] = l;
  {
    float m = l;
    int mi = v;
#pragma unroll
    for (int off = 32; off; off >>= 1) {
      const float om = __shfl_xor(m, off);
      const int oi = __shfl_xor(mi, off);
      if (om > m || (om == m && oi < mi)) { m = om; mi = oi; }
    }
    if ((tid & 63) == 0) {
      wred[tid >> 6] = m;
      wredi[tid >> 6] = mi;
    }
  }
  __syncthreads();
  int am_r = 0;
  if (tid < 4) {
    float bm = wred[4 * tid];
    int bi = wredi[4 * tid];
#pragma unroll
    for (int q = 1; q < 4; ++q) {
      const float o = wred[4 * tid + q];
      const int oi = wredi[4 * tid + q];
      if (o > bm || (o == bm && oi < bi)) { bm = o; bi = oi; }
    }
    mxv[tid] = bm;
    am_r = bi;
  }
  __syncthreads();
  {
    float ex = expf(l - mxv[rr]);
#pragma unroll
    for (int off = 32; off; off >>= 1) ex += __shfl_xor(ex, off);
    if ((tid & 63) == 0) wred[tid >> 6] = ex;
  }
  __syncthreads();
  if (tid < 4) {
    tok[b0 + tid] = am_r;
    if (am_r != tgv[tid]) mf[b0 + tid] = 0;
    out[(size_t)(b0 + tid) * Tn + t] = (float)am_r;
  }
  if (tid == 0) {
    float lp = 0.f;
#pragma unroll
    for (int r = 0; r < 4; ++r) {
      const float s = wred[4 * r] + wred[4 * r + 1] + wred[4 * r + 2] + wred[4 * r + 3];
      lp += -(lgt[r] - mxv[r] - logf(s)) * (1.f / 1024.f);
    }
    atomicAdd(wsloss, lp);
  }
  // ---- qp for t+1 (in-wave K-split; reads h1s, read-only since stage) ----
  {
    const int jj = (tid & 31) | ((tid >> 6) << 5);
    const int grp = (tid >> 5) & 1;
    const int k0 = grp * 64;
    const float4* wp = WaT + jj + (size_t)k0 * Hn;
    float a0 = 0.f, a1 = 0.f, a2 = 0.f, a3 = 0.f;
    for (int k4 = 0; k4 < 64; k4 += 2) {
#pragma unroll
      for (int u = 0; u < 2; ++u) {
        const float4 w = wp[(size_t)(k4 + u) * Hn];
        const float4 x0 = ((const float4*)(h1s))[k0 + k4 + u];
        const float4 x1 = ((const float4*)(h1s + Hn))[k0 + k4 + u];
        const float4 x2 = ((const float4*)(h1s + 2 * Hn))[k0 + k4 + u];
        const float4 x3 = ((const float4*)(h1s + 3 * Hn))[k0 + k4 + u];
        fma4(a0, w, x0); fma4(a1, w, x1); fma4(a2, w, x2); fma4(a3, w, x3);
      }
    }
    a0 += __shfl_xor(a0, 32);
    a1 += __shfl_xor(a1, 32);
    a2 += __shfl_xor(a2, 32);
    a3 += __shfl_xor(a3, 32);
    const float bb = bWa[jj];
    if (!grp) {
      qp[(size_t)(b0 + 0) * Hn + jj] = a0 + bb;
      qp[(size_t)(b0 + 1) * Hn + jj] = a1 + bb;
    } else {
      qp[(size_t)(b0 + 2) * Hn + jj] = a2 + bb;
      qp[(size_t)(b0 + 3) * Hn + jj] = a3 + bb;
    }
  }
}

// ---- qp for t=0 (from initial h1 = state layer 1) ----
__global__ __launch_bounds__(1024) void qp_only(
    const float* __restrict__ h1src, const float4* __restrict__ WaT,
    const float* __restrict__ bWa, float* __restrict__ qp) {
  __shared__ __attribute__((aligned(16))) float h1s[4 * Hn];
  const int tid = threadIdx.x;
  const int b0 = blockIdx.x * 4;
  for (int i = tid; i < 4 * Hn; i += 1024)
    h1s[i] = h1src[(size_t)(b0 + (i >> 9)) * Hn + (i & 511)];
  __syncthreads();
  const int jj = (tid & 31) | ((tid >> 6) << 5);
  const int grp = (tid >> 5) & 1;
  const int k0 = grp * 64;
  const float4* wp = WaT + jj + (size_t)k0 * Hn;
  float a0 = 0.f, a1 = 0.f, a2 = 0.f, a3 = 0.f;
  for (int k4 = 0; k4 < 64; k4 += 2) {
#pragma unroll
    for (int u = 0; u < 2; ++u) {
      const float4 w = wp[(size_t)(k4 + u) * Hn];
      const float4 x0 = ((const float4*)(h1s))[k0 + k4 + u];
      const float4 x1 = ((const float4*)(h1s + Hn))[k0 + k4 + u];
      const float4 x2 = ((const float4*)(h1s + 2 * Hn))[k0 + k4 + u];
      const float4 x3 = ((const float4*)(h1s + 3 * Hn))[k0 + k4 + u];
      fma4(a0, w, x0); fma4(a1, w, x1); fma4(a2, w, x2); fma4(a3, w, x3);
    }
  }
  a0 += __shfl_xor(a0, 32);
  a1 += __shfl_xor(a1, 32);
  a2 += __shfl_xor(a2, 32);
  a3 += __shfl_xor(a3, 32);
  const float bb = bWa[jj];
  if (!grp) {
    qp[(size_t)(b0 + 0) * Hn + jj] = a0 + bb;
    qp[(size_t)(b0 + 1) * Hn + jj] = a1 + bb;
  } else {
    qp[(size_t)(b0 + 2) * Hn + jj] = a2 + bb;
    qp[(size_t)(b0 + 3) * Hn + jj] = a3 + bb;
  }
}

__global__ void init_bufs(int* tok, int* mf, float* wsloss) {
  const int i = blockIdx.x * blockDim.x + threadIdx.x;
  if (i < Bn) { tok[i] = 1; mf[i] = 1; }
  if (i == 0) wsloss[0] = 0.f;
}

__global__ __launch_bounds__(1024) void finisher2(const float* __restrict__ wsloss,
                                                  const int* __restrict__ mf,
                                                  float* __restrict__ out) {
  __shared__ int s[1024];
  const int tid = threadIdx.x;
  s[tid] = mf[tid];
  __syncthreads();
  for (int off = 512; off; off >>= 1) {
    if (tid < off) s[tid] += s[tid + off];
    __syncthreads();
  }
  if (tid == 0) {
    const size_t base = (size_t)Bn * Tn + (size_t)Tn * Bn * Sn;
    out[base] = wsloss[0];
    out[base + 1] = (float)s[0];
  }
}

// ============ tier-2 fallback: R3-verified r4y decoder (9.95 ms) ===============
template <int KCI, int KCH>
__device__ __forceinline__ void gru_pair(
    int jj, int grp,
    const float4* __restrict__ WihT,
    const float4* __restrict__ WhhT,
    const float* __restrict__ x, int xstride,
    float* __restrict__ h,
    const float* __restrict__ bih, const float* __restrict__ bhh) {
  float ar[4] = {}, az[4] = {}, ain[4] = {}, ahn[4] = {};
  {
    const int k0 = grp * KCI;
    const float4* w0 = WihT + jj + (size_t)k0 * G3;
    const float4* w1 = WihT + jj + 512 + (size_t)k0 * G3;
    const float4* w2 = WihT + jj + 1024 + (size_t)k0 * G3;
    for (int k4 = 0; k4 < KCI; k4 += 2) {
#pragma unroll
      for (int u = 0; u < 2; ++u) {
        const float4 a = w0[(size_t)(k4 + u) * G3];
        const float4 b = w1[(size_t)(k4 + u) * G3];
        const float4 c = w2[(size_t)(k4 + u) * G3];
#pragma unroll
        for (int r = 0; r < 4; ++r) {
          const float4 xv = ((const float4*)(x + r * xstride))[k0 + k4 + u];
          fma4(ar[r], a, xv);
          fma4(az[r], b, xv);
          fma4(ain[r], c, xv);
        }
      }
    }
  }
  {
    const int k0 = grp * KCH;
    const float4* w0 = WhhT + jj + (size_t)k0 * G3;
    const float4* w1 = WhhT + jj + 512 + (size_t)k0 * G3;
    const float4* w2 = WhhT + jj + 1024 + (size_t)k0 * G3;
    for (int k4 = 0; k4 < KCH; k4 += 2) {
#pragma unroll
      for (int u = 0; u < 2; ++u) {
        const float4 a = w0[(size_t)(k4 + u) * G3];
        const float4 b = w1[(size_t)(k4 + u) * G3];
        const float4 c = w2[(size_t)(k4 + u) * G3];
#pragma unroll
        for (int r = 0; r < 4; ++r) {
          const float4 xv = ((const float4*)(h + r * Hn))[k0 + k4 + u];
          fma4(ar[r], a, xv);
          fma4(az[r], b, xv);
          fma4(ahn[r], c, xv);
        }
      }
    }
  }
#pragma unroll
  for (int r = 0; r < 4; ++r) {
    ar[r] += __shfl_xor(ar[r], 32);
    az[r] += __shfl_xor(az[r], 32);
    ain[r] += __shfl_xor(ain[r], 32);
    ahn[r] += __shfl_xor(ahn[r], 32);
  }
  const float bir = bih[jj], biz = bih[jj + 512], bin = bih[jj + 1024];
  const float bhr = bhh[jj], bhz = bhh[jj + 512], bhn = bhh[jj + 1024];
  const int r2 = grp * 2;
  const float s0r = (grp ? ar[2] : ar[0]) + bir + bhr;
  const float s0z = (grp ? az[2] : az[0]) + biz + bhz;
  const float s0i = (grp ? ain[2] : ain[0]) + bin;
  const float s0h = (grp ? ahn[2] : ahn[0]) + bhn;
  const float s1r = (grp ? ar[3] : ar[1]) + bir + bhr;
  const float s1z = (grp ? az[3] : az[1]) + biz + bhz;
  const float s1i = (grp ? ain[3] : ain[1]) + bin;
  const float s1h = (grp ? ahn[3] : ahn[1]) + bhn;
  const float rg0 = 1.f / (1.f + expf(-s0r));
  const float zg0 = 1.f / (1.f + expf(-s0z));
  const float ng0 = tanhf(s0i + rg0 * s0h);
  const float rg1 = 1.f / (1.f + expf(-s1r));
  const float zg1 = 1.f / (1.f + expf(-s1z));
  const float ng1 = tanhf(s1i + rg1 * s1h);
  const float h0old = h[(r2 + 0) * Hn + jj];
  const float h1old = h[(r2 + 1) * Hn + jj];
  const float hn0 = (1.f - zg0) * ng0 + zg0 * h0old;
  const float hn1 = (1.f - zg1) * ng1 + zg1 * h1old;
  __syncthreads();
  h[(r2 + 0) * Hn + jj] = hn0;
  h[(r2 + 1) * Hn + jj] = hn1;
  __syncthreads();
}

__global__ __launch_bounds__(1024) __attribute__((amdgpu_waves_per_eu(4, 4)))
void decoder_r4y(
    const float* __restrict__ state, const float* __restrict__ enc,
    const int* __restrict__ target, const float* __restrict__ emb,
    const float4* __restrict__ WaT, const float* __restrict__ bWa,
    const float* __restrict__ Va, const float* __restrict__ bVa,
    const float4* __restrict__ W0ihT, const float4* __restrict__ W0hhT,
    const float* __restrict__ bih0, const float* __restrict__ bhh0,
    const float4* __restrict__ W1ihT, const float4* __restrict__ W1hhT,
    const float* __restrict__ bih1, const float* __restrict__ bhh1,
    const float4* __restrict__ fcWT, const float* __restrict__ fcb,
    const float* __restrict__ kproj, float* __restrict__ out,
    float* __restrict__ wsloss, int* __restrict__ wscorrect) {
  __shared__ __attribute__((aligned(16))) float h0s[4 * Hn];
  __shared__ __attribute__((aligned(16))) float h1s[4 * Hn];
  __shared__ __attribute__((aligned(16))) float qps[4 * Hn];
  __shared__ __attribute__((aligned(16))) float gins[4 * EHn];
  __shared__ __attribute__((aligned(16))) float vas[Hn];
  __shared__ __attribute__((aligned(16))) float wrs[4 * Sn];
  __shared__ __attribute__((aligned(16))) float ep[1024];
  __shared__ float wred[16];
  __shared__ int wredi[16];
  __shared__ float mxv[4], lgt[4];
  __shared__ int tgv[4], tokb[4], mfs[4];

  const int tid = threadIdx.x;
  const int b0 = blockIdx.x * 4;
  const int jj = (tid & 31) | ((tid >> 6) << 5);
  const int grp = (tid >> 5) & 1;

  for (int i = tid; i < 4 * Hn; i += 1024) {
    const int r = i >> 9, j = i & 511;
    h0s[i] = state[(size_t)(b0 + r) * Hn + j];
    h1s[i] = state[(size_t)(Bn + b0 + r) * Hn + j];
  }
  if (tid < 512) vas[tid] = Va[tid];
  if (tid < 4) { tokb[tid] = 1; mfs[tid] = 1; }
  __syncthreads();

  float run_loss = 0.f;

  for (int t = 0; t < Tn; ++t) {
    {
      const int kc = (Hn >> 2) >> 1;
      const int k0 = grp * kc;
      const float4* wp = WaT + jj + (size_t)k0 * Hn;
      float a0 = 0.f, a1 = 0.f, a2 = 0.f, a3 = 0.f;
      for (int k4 = 0; k4 < 64; k4 += 2) {
#pragma unroll
        for (int u = 0; u < 2; ++u) {
          const float4 w = wp[(size_t)(k4 + u) * Hn];
          const float4 x0 = ((const float4*)(h1s))[k0 + k4 + u];
          const float4 x1 = ((const float4*)(h1s + Hn))[k0 + k4 + u];
          const float4 x2 = ((const float4*)(h1s + 2 * Hn))[k0 + k4 + u];
          const float4 x3 = ((const float4*)(h1s + 3 * Hn))[k0 + k4 + u];
          fma4(a0, w, x0); fma4(a1, w, x1); fma4(a2, w, x2); fma4(a3, w, x3);
        }
      }
      a0 += __shfl_xor(a0, 32);
      a1 += __shfl_xor(a1, 32);
      a2 += __shfl_xor(a2, 32);
      a3 += __shfl_xor(a3, 32);
      const float bb = bWa[jj];
      if (!grp) {
        qps[jj] = a0 + bb;
        qps[Hn + jj] = a1 + bb;
      } else {
        qps[2 * Hn + jj] = a2 + bb;
        qps[3 * Hn + jj] = a3 + bb;
      }
    }
    __syncthreads();
    {
      const int p = tid >> 3, q = tid & 7;
      const int r = p >> 5, s = p & 31;
      const float4* kp4 = (const float4*)(kproj + ((size_t)s * Bn + (b0 + r)) * Hn);
      const float4* qp4 = (const float4*)(qps + r * Hn);
      const float4* va4 = (const float4*)vas;
      float partial = 0.f;
      for (int i = 0; i < 16; i += 2) {
#pragma unroll
        for (int u = 0; u < 2; ++u) {
          const int f = q + ((i + u) << 3);
          const float4 k4 = kp4[f], q4 = qp4[f], v4 = va4[f];
          partial += v4.x * tanhf(q4.x + k4.x);
          partial += v4.y * tanhf(q4.y + k4.y);
          partial += v4.z * tanhf(q4.z + k4.z);
          partial += v4.w * tanhf(q4.w + k4.w);
        }
      }
      ep[tid] = partial;
    }
    __syncthreads();
    if (tid < 128) {
      float e = ep[tid * 8] + ep[tid * 8 + 1] + ep[tid * 8 + 2] + ep[tid * 8 + 3] +
                ep[tid * 8 + 4] + ep[tid * 8 + 5] + ep[tid * 8 + 6] + ep[tid * 8 + 7] +
                bVa[0];
      float m = e;
#pragma unroll
      for (int off = 16; off; off >>= 1) m = fmaxf(m, __shfl_xor(m, off));
      const float ex = expf(e - m);
      float ss = ex;
#pragma unroll
      for (int off = 16; off; off >>= 1) ss += __shfl_xor(ss, off);
      const float w = ex / ss;
      const int r = tid >> 5, s = tid & 31;
      wrs[tid] = w;
      out[(size_t)(Bn * Tn) + (size_t)t * (Bn * Sn) + (size_t)(b0 + r) * Sn + s] = w;
    }
    __syncthreads();
    {
      const int h = tid & 511, rp = tid >> 9;
      float c0 = 0.f, c1 = 0.f;
      const float* w0 = wrs + (2 * rp) * 32;
      const float* w1 = wrs + (2 * rp + 1) * 32;
#pragma unroll 4
      for (int s = 0; s < Sn; ++s) {
        const size_t base = ((size_t)s * Bn + b0 + 2 * rp) * Hn + h;
        c0 = fmaf(w0[s], enc[base], c0);
        c1 = fmaf(w1[s], enc[base + Hn], c1);
      }
      gins[(2 * rp) * EHn + En + h] = c0;
      gins[(2 * rp + 1) * EHn + En + h] = c1;
    }
    {
      const int r = tid >> 8, j = tid & 255;
      gins[r * EHn + j] = fmaxf(emb[(size_t)tokb[r] * En + j], 0.f);
    }
    if (tid < 4) tgv[tid] = target[(size_t)(b0 + tid) * Tn + t];
    __syncthreads();
    gru_pair<96, 64>(jj, grp, W0ihT, W0hhT, gins, EHn, h0s, bih0, bhh0);
    gru_pair<64, 64>(jj, grp, W1ihT, W1hhT, h0s, Hn, h1s, bih1, bhh1);
    const int v = tid & 255, rr = tid >> 8;
    float l;
    {
      const float4* wp = fcWT + v;
      const float4* xr = (const float4*)(h1s + rr * Hn);
      float acc = 0.f;
      for (int k4 = 0; k4 < (Hn >> 2); k4 += 4) {
#pragma unroll
        for (int u = 0; u < 4; ++u) {
          const float4 w = wp[(size_t)(k4 + u) * Vn];
          fma4(acc, w, xr[k4 + u]);
        }
      }
      l = acc + fcb[v];
    }
    if (v == tgv[rr]) lgt[rr] = l;
    {
      float m = l;
      int mi = v;
#pragma unroll
      for (int off = 32; off; off >>= 1) {
        const float om = __shfl_xor(m, off);
        const int oi = __shfl_xor(mi, off);
        if (om > m || (om == m && oi < mi)) { m = om; mi = oi; }
      }
      if ((tid & 63) == 0) {
        wred[tid >> 6] = m;
        wredi[tid >> 6] = mi;
      }
    }
    __syncthreads();
    int am_r = 0;
    if (tid < 4) {
      float bm = wred[4 * tid];
      int bi = wredi[4 * tid];
#pragma unroll
      for (int q = 1; q < 4; ++q) {
        const float o = wred[4 * tid + q];
        const int oi = wredi[4 * tid + q];
        if (o > bm || (o == bm && oi < bi)) { bm = o; bi = oi; }
      }
      mxv[tid] = bm;
      am_r = bi;
    }
    __syncthreads();
    {
      float ex = expf(l - mxv[rr]);
#pragma unroll
      for (int off = 32; off; off >>= 1) ex += __shfl_xor(ex, off);
      if ((tid & 63) == 0) wred[tid >> 6] = ex;
    }
    __syncthreads();
    if (tid < 4) {
      tokb[tid] = am_r;
      if (am_r != tgv[tid]) mfs[tid] = 0;
      out[(size_t)(b0 + tid) * Tn + t] = (float)am_r;
    }
    if (tid == 0) {
#pragma unroll
      for (int r = 0; r < 4; ++r) {
        const float s = wred[4 * r] + wred[4 * r + 1] + wred[4 * r + 2] + wred[4 * r + 3];
        run_loss += -(lgt[r] - mxv[r] - logf(s)) * (1.f / 1024.f);
      }
    }
  }

  __syncthreads();
  if (tid == 0) {
    atomicAdd(wsloss, run_loss);
    atomicAdd(wscorrect, mfs[0] + mfs[1] + mfs[2] + mfs[3]);
  }
}

__global__ void ws_init(float* wsloss, int* wscorrect) {
  wsloss[0] = 0.f;
  wscorrect[0] = 0;
}

__global__ void finisher(const float* __restrict__ wsloss,
                         const int* __restrict__ wscorrect, float* __restrict__ out) {
  const size_t base = (size_t)Bn * Tn + (size_t)Tn * Bn * Sn;
  out[base] = wsloss[0];
  out[base + 1] = (float)wscorrect[0];
}

extern "C" void kernel_launch(void* const* d_in, const int* in_sizes, int n_in,
                              void* d_out, int out_size, void* d_ws, size_t ws_size,
                              hipStream_t stream) {
  const float* state = (const float*)d_in[0];
  const float* enc = (const float*)d_in[1];
  const int* target = (const int*)d_in[2];
  const float* emb = (const float*)d_in[3];
  const float* Wa = (const float*)d_in[4];
  const float* bWa = (const float*)d_in[5];
  const float* Ua = (const float*)d_in[6];
  const float* bUa = (const float*)d_in[7];
  const float* Va = (const float*)d_in[8];
  const float* bVa = (const float*)d_in[9];
  const float* Wih0 = (const float*)d_in[10];
  const float* Whh0 = (const float*)d_in[11];
  const float* bih0 = (const float*)d_in[12];
  const float* bhh0 = (const float*)d_in[13];
  const float* Wih1 = (const float*)d_in[14];
  const float* Whh1 = (const float*)d_in[15];
  const float* bih1 = (const float*)d_in[16];
  const float* bhh1 = (const float*)d_in[17];
  const float* fcW = (const float*)d_in[18];
  const float* fcb = (const float*)d_in[19];
  float* out = (float*)d_out;

  const size_t KPROJ_FLOATS = (size_t)Sn * Bn * Hn;  // 64 MB

  const size_t N0IH = (size_t)G3 * (EHn / 4);
  const size_t NHH = (size_t)G3 * (Hn / 4);
  const size_t NWA = (size_t)Hn * (Hn / 4);
  const size_t NFC = (size_t)Vn * (Hn / 4);
  const size_t WT_TOTAL = N0IH + 3 * NHH + NWA + NFC;
  const size_t NEED_A2 = WT_TOTAL * 16 + KPROJ_FLOATS * 4 + 256;

  const size_t NGIN = (size_t)Bn * EHn;
  const size_t NH = (size_t)Bn * Hn;
  const size_t EXTRA = NGIN + 5 * NH;  // gin + h0A/B + h1A/B + qp
  const size_t NEED_NEW = NEED_A2 + EXTRA * 4 + 4 * 2048 + 256;

  if (ws_size >= NEED_NEW) {
    float4* W0ihT = (float4*)d_ws;
    float4* W0hhT = W0ihT + N0IH;
    float4* W1ihT = W0hhT + NHH;
    float4* W1hhT = W1ihT + NHH;
    float4* WaT = W1hhT + NHH;
    float4* fcWT = WaT + NWA;
    float* kproj = (float*)(fcWT + NFC);
    float* gin = kproj + KPROJ_FLOATS;
    float* h0A = gin + NGIN;
    float* h0B = h0A + NH;
    float* h1A = h0B + NH;
    float* h1B = h1A + NH;
    float* qpbuf = h1B + NH;
    int* tok = (int*)(qpbuf + NH);
    int* mf = tok + Bn;
    float* wsloss = (float*)(mf + Bn);

    init_bufs<<<2, 512, 0, stream>>>(tok, mf, wsloss);
    transpose_pack<<<(int)((N0IH + 255) / 256), 256, 0, stream>>>(Wih0, W0ihT, G3, EHn);
    transpose_pack<<<(int)((NHH + 255) / 256), 256, 0, stream>>>(Whh0, W0hhT, G3, Hn);
    transpose_pack<<<(int)((NHH + 255) / 256), 256, 0, stream>>>(Wih1, W1ihT, G3, Hn);
    transpose_pack<<<(int)((NHH + 255) / 256), 256, 0, stream>>>(Whh1, W1hhT, G3, Hn);
    transpose_pack<<<(int)((NWA + 255) / 256), 256, 0, stream>>>(Wa, WaT, Hn, Hn);
    transpose_pack<<<(int)((NFC + 255) / 256), 256, 0, stream>>>(fcW, fcWT, Vn, Hn);
    gemm_bias<<<dim3(Hn / 64, (Sn * Bn) / 64), 256, 0, stream>>>(
        enc, Ua, bUa, kproj, Sn * Bn, Hn, Hn);
    qp_only<<<Bn / 4, 1024, 0, stream>>>(state + (size_t)Bn * Hn, WaT, bWa, qpbuf);

    for (int t = 0; t < Tn; ++t) {
      const float* h0cur = (t == 0) ? state : ((t & 1) ? h0A : h0B);
      float* h0nxt = (t & 1) ? h0B : h0A;
      const float* h1cur =
          (t == 0) ? (state + (size_t)Bn * Hn) : ((t & 1) ? h1A : h1B);
      float* h1nxt = (t & 1) ? h1B : h1A;

      attn_gin<<<Bn / 4, 1024, 0, stream>>>(qpbuf, kproj, enc, emb, tok, Va, bVa,
                                            gin, out, t);
      gru_gemm<192><<<dim3(16, 32), 512, 0, stream>>>(
          gin, EHn / 4, h0cur, W0ihT, W0hhT, bih0, bhh0, h0nxt);
      gru_gemm<128><<<dim3(16, 32), 512, 0, stream>>>(
          h0nxt, Hn / 4, h1cur, W1ihT, W1hhT, bih1, bhh1, h1nxt);
      fc_qp<<<Bn / 4, 1024, 0, stream>>>(h1nxt, fcWT, fcb, WaT, bWa, target, t,
                                         qpbuf, tok, mf, out, wsloss);
    }
    finisher2<<<1, 1024, 0, stream>>>(wsloss, mf, out);
  } else if (ws_size >= NEED_A2) {
    float4* W0ihT = (float4*)d_ws;
    float4* W0hhT = W0ihT + N0IH;
    float4* W1ihT = W0hhT + NHH;
    float4* W1hhT = W1ihT + NHH;
    float4* WaT = W1hhT + NHH;
    float4* fcWT = WaT + NWA;
    float* kproj = (float*)(fcWT + NFC);
    float* wsloss = kproj + KPROJ_FLOATS;
    int* wscorrect = (int*)(wsloss + 1);

    ws_init<<<1, 1, 0, stream>>>(wsloss, wscorrect);
    transpose_pack<<<(int)((N0IH + 255) / 256), 256, 0, stream>>>(Wih0, W0ihT, G3, EHn);
    transpose_pack<<<(int)((NHH + 255) / 256), 256, 0, stream>>>(Whh0, W0hhT, G3, Hn);
    transpose_pack<<<(int)((NHH + 255) / 256), 256, 0, stream>>>(Wih1, W1ihT, G3, Hn);
    transpose_pack<<<(int)((NHH + 255) / 256), 256, 0, stream>>>(Whh1, W1hhT, G3, Hn);
    transpose_pack<<<(int)((NWA + 255) / 256), 256, 0, stream>>>(Wa, WaT, Hn, Hn);
    transpose_pack<<<(int)((NFC + 255) / 256), 256, 0, stream>>>(fcW, fcWT, Vn, Hn);
    gemm_bias<<<dim3(Hn / 64, (Sn * Bn) / 64), 256, 0, stream>>>(
        enc, Ua, bUa, kproj, Sn * Bn, Hn, Hn);
    decoder_r4y<<<Bn / 4, 1024, 0, stream>>>(
        state, enc, target, emb, WaT, bWa, Va, bVa, W0ihT, W0hhT, bih0, bhh0,
        W1ihT, W1hhT, bih1, bhh1, fcWT, fcb, kproj, out, wsloss, wscorrect);
    finisher<<<1, 1, 0, stream>>>(wsloss, wscorrect, out);
  }
}

// Round 8
// 7808.979 us; speedup vs baseline: 5.3607x; 1.3119x over previous
//
#include <hip/hip_runtime.h>
#include <math.h>

#define Hn 512
#define En 256
#define Sn 32
#define Bn 1024
#define Tn 32
#define Vn 256
#define G3 1536
#define EHn 768

// fma4 as a FUNCTION, not a macro (R6 lesson: macro param `w` collides with `.w`).
__device__ __forceinline__ void fma4(float& acc, const float4 w, const float4 x) {
  acc = fmaf(w.x, x.x, acc);
  acc = fmaf(w.y, x.y, acc);
  acc = fmaf(w.z, x.z, acc);
  acc = fmaf(w.w, x.w, acc);
}

// ============ one-time weight transpose: W[gate][K] -> WT4[k4*G + g] ============
__global__ __launch_bounds__(256) void transpose_pack(const float* __restrict__ W,
                                                      float4* __restrict__ WT4,
                                                      int G, int K) {
  const int idx = blockIdx.x * blockDim.x + threadIdx.x;
  const int n = G * (K >> 2);
  if (idx >= n) return;
  const int k4 = idx / G, g = idx - k4 * G;
  WT4[idx] = *(const float4*)(W + (size_t)g * K + (k4 << 2));
}

// ============ kproj GEMM: C(M,N) = A(M,K) @ W(N,K)^T + bias ============
__global__ __launch_bounds__(256) void gemm_bias(const float* __restrict__ A,
                                                 const float* __restrict__ Wt,
                                                 const float* __restrict__ bias,
                                                 float* __restrict__ C,
                                                 int M, int N, int K) {
  __shared__ float As[16][68];
  __shared__ float Ws[16][68];
  const int bm = blockIdx.y * 64;
  const int bn = blockIdx.x * 64;
  const int tid = threadIdx.x;
  const int tx = tid & 15;
  const int ty = tid >> 4;
  const int kk = tid & 15;
  const int r0 = tid >> 4;
  float acc[4][4] = {};
  for (int k0 = 0; k0 < K; k0 += 16) {
#pragma unroll
    for (int i = 0; i < 4; ++i) {
      const int m = r0 + (i << 4);
      As[kk][m] = A[(size_t)(bm + m) * K + (k0 + kk)];
      Ws[kk][m] = Wt[(size_t)(bn + m) * K + (k0 + kk)];
    }
    __syncthreads();
#pragma unroll
    for (int k = 0; k < 16; ++k) {
      const float4 a4 = *(const float4*)&As[k][ty * 4];
      const float4 w4 = *(const float4*)&Ws[k][tx * 4];
      const float av[4] = {a4.x, a4.y, a4.z, a4.w};
      const float wv[4] = {w4.x, w4.y, w4.z, w4.w};
#pragma unroll
      for (int i = 0; i < 4; ++i)
#pragma unroll
        for (int j = 0; j < 4; ++j) acc[i][j] = fmaf(av[i], wv[j], acc[i][j]);
    }
    __syncthreads();
  }
#pragma unroll
  for (int i = 0; i < 4; ++i) {
    const size_t m = (size_t)bm + ty * 4 + i;
    float* crow = C + m * N + bn + tx * 4;
#pragma unroll
    for (int j = 0; j < 4; ++j) crow[j] = acc[i][j] + bias[bn + tx * 4 + j];
  }
}

// =================== Path G2: per-phase GEMM, fully LDS-staged =================
// R8: R7's gru_gemm had 16x redundant weight loads through L1 (g0 = f(tx)
// only) and fc_qp kept per-block weight re-streaming (384 MB/step). Fix:
// stage BOTH operand tiles in LDS (w-tile 24KB + x-tile 16KB); fc+qp become
// m/j-tiled GEMM tiles in one kernel; argmax/loss split into a tiny kernel.

// ---- K1: attention + gin assembly (block-local 4 rows, weight-free) ----
__global__ __launch_bounds__(1024) void attn_gin(
    const float* __restrict__ qp, const float* __restrict__ kproj,
    const float* __restrict__ enc, const float* __restrict__ emb,
    const int* __restrict__ tok, const float* __restrict__ Va,
    const float* __restrict__ bVa, float* __restrict__ gin,
    float* __restrict__ out, int t) {
  __shared__ __attribute__((aligned(16))) float qps[4 * Hn];
  __shared__ __attribute__((aligned(16))) float vas[Hn];
  __shared__ __attribute__((aligned(16))) float ep[1024];
  __shared__ float wrs[128];
  __shared__ int tokb[4];
  const int tid = threadIdx.x;
  const int b0 = blockIdx.x * 4;
  for (int i = tid; i < 4 * Hn; i += 1024)
    qps[i] = qp[(size_t)(b0 + (i >> 9)) * Hn + (i & 511)];
  if (tid < 512) vas[tid] = Va[tid];
  if (tid < 4) tokb[tid] = tok[b0 + tid];
  __syncthreads();
  {
    const int p = tid >> 3, q = tid & 7;
    const int r = p >> 5, s = p & 31;
    const float4* kp4 = (const float4*)(kproj + ((size_t)s * Bn + (b0 + r)) * Hn);
    const float4* qp4 = (const float4*)(qps + r * Hn);
    const float4* va4 = (const float4*)vas;
    float partial = 0.f;
    for (int i = 0; i < 16; i += 2) {
#pragma unroll
      for (int u = 0; u < 2; ++u) {
        const int f = q + ((i + u) << 3);
        const float4 k4 = kp4[f], q4 = qp4[f], v4 = va4[f];
        partial += v4.x * tanhf(q4.x + k4.x);
        partial += v4.y * tanhf(q4.y + k4.y);
        partial += v4.z * tanhf(q4.z + k4.z);
        partial += v4.w * tanhf(q4.w + k4.w);
      }
    }
    ep[tid] = partial;
  }
  __syncthreads();
  if (tid < 128) {
    float e = ep[tid * 8] + ep[tid * 8 + 1] + ep[tid * 8 + 2] + ep[tid * 8 + 3] +
              ep[tid * 8 + 4] + ep[tid * 8 + 5] + ep[tid * 8 + 6] + ep[tid * 8 + 7] +
              bVa[0];
    float m = e;
#pragma unroll
    for (int off = 16; off; off >>= 1) m = fmaxf(m, __shfl_xor(m, off));
    const float ex = expf(e - m);
    float ss = ex;
#pragma unroll
    for (int off = 16; off; off >>= 1) ss += __shfl_xor(ss, off);
    const float w = ex / ss;
    const int r = tid >> 5, s = tid & 31;
    wrs[tid] = w;
    out[(size_t)(Bn * Tn) + (size_t)t * (Bn * Sn) + (size_t)(b0 + r) * Sn + s] = w;
  }
  __syncthreads();
  {
    const int h = tid & 511, rp = tid >> 9;
    float c0 = 0.f, c1 = 0.f;
    const float* w0 = wrs + (2 * rp) * 32;
    const float* w1 = wrs + (2 * rp + 1) * 32;
#pragma unroll 4
    for (int s = 0; s < Sn; ++s) {
      const size_t base = ((size_t)s * Bn + b0 + 2 * rp) * Hn + h;
      c0 = fmaf(w0[s], enc[base], c0);
      c1 = fmaf(w1[s], enc[base + Hn], c1);
    }
    gin[(size_t)(b0 + 2 * rp) * EHn + En + h] = c0;
    gin[(size_t)(b0 + 2 * rp + 1) * EHn + En + h] = c1;
  }
  {
    const int r = tid >> 8, j = tid & 255;
    gin[(size_t)(b0 + r) * EHn + j] = fmaxf(emb[(size_t)tokb[r] * En + j], 0.f);
  }
}

// ---- K2/K3: GRU as doubly-LDS-staged GEMM. BM=64 x BN=32(x3 gates).
// Grid (16 j, 16 m) = 256 blocks, 512 threads, 4 rows/thread.
template <int KIH4>
__global__ __launch_bounds__(512) void gru_gemm2(
    const float* __restrict__ xsrc, int xsF4,
    const float* __restrict__ hsrc,
    const float4* __restrict__ WihT, const float4* __restrict__ WhhT,
    const float* __restrict__ bih, const float* __restrict__ bhh,
    float* __restrict__ hdst) {
  __shared__ float4 xs4[64 * 16];      // 16 KB
  __shared__ float4 ws4[16 * 3 * 32];  // 24 KB, layout [k4][g][col]
  const int tid = threadIdx.x;
  const int J0 = blockIdx.x * 32;
  const int R0 = blockIdx.y * 64;
  const int tx = tid & 31;
  const int ty = tid >> 5;  // 0..15
  const int row0 = ty * 4;
  float ar[4] = {}, az[4] = {}, ai[4] = {}, an[4] = {};
  // ---- ih chunks ----
  const float4* x4 = (const float4*)xsrc;
  for (int c = 0; c < KIH4 / 16; ++c) {
    __syncthreads();
#pragma unroll
    for (int i = 0; i < 2; ++i) {
      const int idx = tid + i * 512;
      xs4[idx] = x4[(size_t)(R0 + (idx >> 4)) * xsF4 + c * 16 + (idx & 15)];
    }
#pragma unroll
    for (int i = 0; i < 3; ++i) {
      const int idx = tid + i * 512;  // idx = k4*96 + g*32 + col
      const int k4 = idx / 96;
      const int rem = idx - k4 * 96;
      ws4[idx] = WihT[(size_t)(c * 16 + k4) * G3 + (rem >> 5) * 512 + J0 + (rem & 31)];
    }
    __syncthreads();
#pragma unroll 2
    for (int k4 = 0; k4 < 16; ++k4) {
      const float4 wr = ws4[(k4 * 3 + 0) * 32 + tx];
      const float4 wz = ws4[(k4 * 3 + 1) * 32 + tx];
      const float4 wn = ws4[(k4 * 3 + 2) * 32 + tx];
      float4 xr[4];
#pragma unroll
      for (int rr = 0; rr < 4; ++rr) xr[rr] = xs4[(row0 + rr) * 16 + k4];
#pragma unroll
      for (int rr = 0; rr < 4; ++rr) {
        fma4(ar[rr], wr, xr[rr]);
        fma4(az[rr], wz, xr[rr]);
        fma4(ai[rr], wn, xr[rr]);
      }
    }
  }
  // ---- hh chunks (K=512 -> 8 chunks); n-part accumulates separately ----
  const float4* h4 = (const float4*)hsrc;
  for (int c = 0; c < 8; ++c) {
    __syncthreads();
#pragma unroll
    for (int i = 0; i < 2; ++i) {
      const int idx = tid + i * 512;
      xs4[idx] = h4[(size_t)(R0 + (idx >> 4)) * (Hn / 4) + c * 16 + (idx & 15)];
    }
#pragma unroll
    for (int i = 0; i < 3; ++i) {
      const int idx = tid + i * 512;
      const int k4 = idx / 96;
      const int rem = idx - k4 * 96;
      ws4[idx] = WhhT[(size_t)(c * 16 + k4) * G3 + (rem >> 5) * 512 + J0 + (rem & 31)];
    }
    __syncthreads();
#pragma unroll 2
    for (int k4 = 0; k4 < 16; ++k4) {
      const float4 wr = ws4[(k4 * 3 + 0) * 32 + tx];
      const float4 wz = ws4[(k4 * 3 + 1) * 32 + tx];
      const float4 wn = ws4[(k4 * 3 + 2) * 32 + tx];
      float4 xr[4];
#pragma unroll
      for (int rr = 0; rr < 4; ++rr) xr[rr] = xs4[(row0 + rr) * 16 + k4];
#pragma unroll
      for (int rr = 0; rr < 4; ++rr) {
        fma4(ar[rr], wr, xr[rr]);
        fma4(az[rr], wz, xr[rr]);
        fma4(an[rr], wn, xr[rr]);
      }
    }
  }
  const int g0 = J0 + tx;
  const float bir = bih[g0], biz = bih[g0 + 512], bin = bih[g0 + 1024];
  const float bhr = bhh[g0], bhz = bhh[g0 + 512], bhn = bhh[g0 + 1024];
#pragma unroll
  for (int rr = 0; rr < 4; ++rr) {
    const int row = R0 + row0 + rr;
    const float rg = 1.f / (1.f + expf(-(ar[rr] + bir + bhr)));
    const float zg = 1.f / (1.f + expf(-(az[rr] + biz + bhz)));
    const float ng = tanhf(ai[rr] + bin + rg * (an[rr] + bhn));
    const float hold = hsrc[(size_t)row * Hn + g0];
    hdst[(size_t)row * Hn + g0] = (1.f - zg) * ng + zg * hold;
  }
}

// ---- K4: fc and qp as tiled GEMM, fused in one launch.
// Grid (24 j, 16 m): jt<8 -> fc tile (cols 32 of 256); jt>=8 -> qp tile.
__global__ __launch_bounds__(512) void fcqp_gemm(
    const float* __restrict__ h1,
    const float4* __restrict__ fcWT, const float* __restrict__ fcb,
    const float4* __restrict__ WaT, const float* __restrict__ bWa,
    float* __restrict__ logits, float* __restrict__ qp) {
  __shared__ float4 xs4[64 * 16];  // 16 KB
  __shared__ float4 ws4[16 * 32];  // 8 KB
  const int tid = threadIdx.x;
  const int jt = blockIdx.x;
  const int R0 = blockIdx.y * 64;
  const bool isfc = jt < 8;
  const int J0 = isfc ? jt * 32 : (jt - 8) * 32;
  const float4* W = isfc ? fcWT : WaT;
  const int ldW = isfc ? Vn : Hn;
  const int tx = tid & 31;
  const int ty = tid >> 5;
  const int row0 = ty * 4;
  float a[4] = {};
  const float4* h4 = (const float4*)h1;
  for (int c = 0; c < 8; ++c) {
    __syncthreads();
#pragma unroll
    for (int i = 0; i < 2; ++i) {
      const int idx = tid + i * 512;
      xs4[idx] = h4[(size_t)(R0 + (idx >> 4)) * (Hn / 4) + c * 16 + (idx & 15)];
    }
    ws4[tid] = W[(size_t)(c * 16 + (tid >> 5)) * ldW + J0 + (tid & 31)];
    __syncthreads();
#pragma unroll 4
    for (int k4 = 0; k4 < 16; ++k4) {
      const float4 w = ws4[k4 * 32 + tx];
      float4 xr[4];
#pragma unroll
      for (int rr = 0; rr < 4; ++rr) xr[rr] = xs4[(row0 + rr) * 16 + k4];
#pragma unroll
      for (int rr = 0; rr < 4; ++rr) fma4(a[rr], w, xr[rr]);
    }
  }
  if (isfc) {
    const float bb = fcb[J0 + tx];
#pragma unroll
    for (int rr = 0; rr < 4; ++rr)
      logits[(size_t)(R0 + row0 + rr) * Vn + J0 + tx] = a[rr] + bb;
  } else {
    const float bb = bWa[J0 + tx];
#pragma unroll
    for (int rr = 0; rr < 4; ++rr)
      qp[(size_t)(R0 + row0 + rr) * Hn + J0 + tx] = a[rr] + bb;
  }
}

// ---- K5: argmax + loss + token (block-local 4 rows; reads logits only) ----
__global__ __launch_bounds__(1024) void argmax_loss(
    const float* __restrict__ logits, const int* __restrict__ target, int t,
    int* __restrict__ tok, int* __restrict__ mf,
    float* __restrict__ out, float* __restrict__ wsloss) {
  __shared__ float wred[16];
  __shared__ int wredi[16];
  __shared__ float mxv[4], lgt[4];
  __shared__ int tgv[4];
  const int tid = threadIdx.x;
  const int b0 = blockIdx.x * 4;
  const int v = tid & 255, rr = tid >> 8;
  const float l = logits[(size_t)(b0 + rr) * Vn + v];
  if (tid < 4) tgv[tid] = target[(size_t)(b0 + tid) * Tn + t];
  __syncthreads();
  if (v == tgv[rr]) lgt[rr] = l;
  {
    float m = l;
    int mi = v;
#pragma unroll
    for (int off = 32; off; off >>= 1) {
      const float om = __shfl_xor(m, off);
      const int oi = __shfl_xor(mi, off);
      if (om > m || (om == m && oi < mi)) { m = om; mi = oi; }
    }
    if ((tid & 63) == 0) {
      wred[tid >> 6] = m;
      wredi[tid >> 6] = mi;
    }
  }
  __syncthreads();
  int am_r = 0;
  if (tid < 4) {
    float bm = wred[4 * tid];
    int bi = wredi[4 * tid];
#pragma unroll
    for (int q = 1; q < 4; ++q) {
      const float o = wred[4 * tid + q];
      const int oi = wredi[4 * tid + q];
      if (o > bm || (o == bm && oi < bi)) { bm = o; bi = oi; }
    }
    mxv[tid] = bm;
    am_r = bi;
  }
  __syncthreads();
  {
    float ex = expf(l - mxv[rr]);
#pragma unroll
    for (int off = 32; off; off >>= 1) ex += __shfl_xor(ex, off);
    if ((tid & 63) == 0) wred[tid >> 6] = ex;
  }
  __syncthreads();
  if (tid < 4) {
    tok[b0 + tid] = am_r;
    if (am_r != tgv[tid]) mf[b0 + tid] = 0;
    out[(size_t)(b0 + tid) * Tn + t] = (float)am_r;
  }
  if (tid == 0) {
    float lp = 0.f;
#pragma unroll
    for (int r = 0; r < 4; ++r) {
      const float s = wred[4 * r] + wred[4 * r + 1] + wred[4 * r + 2] + wred[4 * r + 3];
      lp += -(lgt[r] - mxv[r] - logf(s)) * (1.f / 1024.f);
    }
    atomicAdd(wsloss, lp);
  }
}

// ---- qp for t=0 (from initial h1 = state layer 1) ----
__global__ __launch_bounds__(1024) void qp_only(
    const float* __restrict__ h1src, const float4* __restrict__ WaT,
    const float* __restrict__ bWa, float* __restrict__ qp) {
  __shared__ __attribute__((aligned(16))) float h1s[4 * Hn];
  const int tid = threadIdx.x;
  const int b0 = blockIdx.x * 4;
  for (int i = tid; i < 4 * Hn; i += 1024)
    h1s[i] = h1src[(size_t)(b0 + (i >> 9)) * Hn + (i & 511)];
  __syncthreads();
  const int jj = (tid & 31) | ((tid >> 6) << 5);
  const int grp = (tid >> 5) & 1;
  const int k0 = grp * 64;
  const float4* wp = WaT + jj + (size_t)k0 * Hn;
  float a0 = 0.f, a1 = 0.f, a2 = 0.f, a3 = 0.f;
  for (int k4 = 0; k4 < 64; k4 += 2) {
#pragma unroll
    for (int u = 0; u < 2; ++u) {
      const float4 w = wp[(size_t)(k4 + u) * Hn];
      const float4 x0 = ((const float4*)(h1s))[k0 + k4 + u];
      const float4 x1 = ((const float4*)(h1s + Hn))[k0 + k4 + u];
      const float4 x2 = ((const float4*)(h1s + 2 * Hn))[k0 + k4 + u];
      const float4 x3 = ((const float4*)(h1s + 3 * Hn))[k0 + k4 + u];
      fma4(a0, w, x0); fma4(a1, w, x1); fma4(a2, w, x2); fma4(a3, w, x3);
    }
  }
  a0 += __shfl_xor(a0, 32);
  a1 += __shfl_xor(a1, 32);
  a2 += __shfl_xor(a2, 32);
  a3 += __shfl_xor(a3, 32);
  const float bb = bWa[jj];
  if (!grp) {
    qp[(size_t)(b0 + 0) * Hn + jj] = a0 + bb;
    qp[(size_t)(b0 + 1) * Hn + jj] = a1 + bb;
  } else {
    qp[(size_t)(b0 + 2) * Hn + jj] = a2 + bb;
    qp[(size_t)(b0 + 3) * Hn + jj] = a3 + bb;
  }
}

__global__ void init_bufs(int* tok, int* mf, float* wsloss) {
  const int i = blockIdx.x * blockDim.x + threadIdx.x;
  if (i < Bn) { tok[i] = 1; mf[i] = 1; }
  if (i == 0) wsloss[0] = 0.f;
}

__global__ __launch_bounds__(1024) void finisher2(const float* __restrict__ wsloss,
                                                  const int* __restrict__ mf,
                                                  float* __restrict__ out) {
  __shared__ int s[1024];
  const int tid = threadIdx.x;
  s[tid] = mf[tid];
  __syncthreads();
  for (int off = 512; off; off >>= 1) {
    if (tid < off) s[tid] += s[tid + off];
    __syncthreads();
  }
  if (tid == 0) {
    const size_t base = (size_t)Bn * Tn + (size_t)Tn * Bn * Sn;
    out[base] = wsloss[0];
    out[base + 1] = (float)s[0];
  }
}

// ============ tier-2 fallback: R3-verified r4y decoder (9.95 ms) ===============
template <int KCI, int KCH>
__device__ __forceinline__ void gru_pair(
    int jj, int grp,
    const float4* __restrict__ WihT,
    const float4* __restrict__ WhhT,
    const float* __restrict__ x, int xstride,
    float* __restrict__ h,
    const float* __restrict__ bih, const float* __restrict__ bhh) {
  float ar[4] = {}, az[4] = {}, ain[4] = {}, ahn[4] = {};
  {
    const int k0 = grp * KCI;
    const float4* w0 = WihT + jj + (size_t)k0 * G3;
    const float4* w1 = WihT + jj + 512 + (size_t)k0 * G3;
    const float4* w2 = WihT + jj + 1024 + (size_t)k0 * G3;
    for (int k4 = 0; k4 < KCI; k4 += 2) {
#pragma unroll
      for (int u = 0; u < 2; ++u) {
        const float4 a = w0[(size_t)(k4 + u) * G3];
        const float4 b = w1[(size_t)(k4 + u) * G3];
        const float4 c = w2[(size_t)(k4 + u) * G3];
#pragma unroll
        for (int r = 0; r < 4; ++r) {
          const float4 xv = ((const float4*)(x + r * xstride))[k0 + k4 + u];
          fma4(ar[r], a, xv);
          fma4(az[r], b, xv);
          fma4(ain[r], c, xv);
        }
      }
    }
  }
  {
    const int k0 = grp * KCH;
    const float4* w0 = WhhT + jj + (size_t)k0 * G3;
    const float4* w1 = WhhT + jj + 512 + (size_t)k0 * G3;
    const float4* w2 = WhhT + jj + 1024 + (size_t)k0 * G3;
    for (int k4 = 0; k4 < KCH; k4 += 2) {
#pragma unroll
      for (int u = 0; u < 2; ++u) {
        const float4 a = w0[(size_t)(k4 + u) * G3];
        const float4 b = w1[(size_t)(k4 + u) * G3];
        const float4 c = w2[(size_t)(k4 + u) * G3];
#pragma unroll
        for (int r = 0; r < 4; ++r) {
          const float4 xv = ((const float4*)(h + r * Hn))[k0 + k4 + u];
          fma4(ar[r], a, xv);
          fma4(az[r], b, xv);
          fma4(ahn[r], c, xv);
        }
      }
    }
  }
#pragma unroll
  for (int r = 0; r < 4; ++r) {
    ar[r] += __shfl_xor(ar[r], 32);
    az[r] += __shfl_xor(az[r], 32);
    ain[r] += __shfl_xor(ain[r], 32);
    ahn[r] += __shfl_xor(ahn[r], 32);
  }
  const float bir = bih[jj], biz = bih[jj + 512], bin = bih[jj + 1024];
  const float bhr = bhh[jj], bhz = bhh[jj + 512], bhn = bhh[jj + 1024];
  const int r2 = grp * 2;
  const float s0r = (grp ? ar[2] : ar[0]) + bir + bhr;
  const float s0z = (grp ? az[2] : az[0]) + biz + bhz;
  const float s0i = (grp ? ain[2] : ain[0]) + bin;
  const float s0h = (grp ? ahn[2] : ahn[0]) + bhn;
  const float s1r = (grp ? ar[3] : ar[1]) + bir + bhr;
  const float s1z = (grp ? az[3] : az[1]) + biz + bhz;
  const float s1i = (grp ? ain[3] : ain[1]) + bin;
  const float s1h = (grp ? ahn[3] : ahn[1]) + bhn;
  const float rg0 = 1.f / (1.f + expf(-s0r));
  const float zg0 = 1.f / (1.f + expf(-s0z));
  const float ng0 = tanhf(s0i + rg0 * s0h);
  const float rg1 = 1.f / (1.f + expf(-s1r));
  const float zg1 = 1.f / (1.f + expf(-s1z));
  const float ng1 = tanhf(s1i + rg1 * s1h);
  const float h0old = h[(r2 + 0) * Hn + jj];
  const float h1old = h[(r2 + 1) * Hn + jj];
  const float hn0 = (1.f - zg0) * ng0 + zg0 * h0old;
  const float hn1 = (1.f - zg1) * ng1 + zg1 * h1old;
  __syncthreads();
  h[(r2 + 0) * Hn + jj] = hn0;
  h[(r2 + 1) * Hn + jj] = hn1;
  __syncthreads();
}

__global__ __launch_bounds__(1024) __attribute__((amdgpu_waves_per_eu(4, 4)))
void decoder_r4y(
    const float* __restrict__ state, const float* __restrict__ enc,
    const int* __restrict__ target, const float* __restrict__ emb,
    const float4* __restrict__ WaT, const float* __restrict__ bWa,
    const float* __restrict__ Va, const float* __restrict__ bVa,
    const float4* __restrict__ W0ihT, const float4* __restrict__ W0hhT,
    const float* __restrict__ bih0, const float* __restrict__ bhh0,
    const float4* __restrict__ W1ihT, const float4* __restrict__ W1hhT,
    const float* __restrict__ bih1, const float* __restrict__ bhh1,
    const float4* __restrict__ fcWT, const float* __restrict__ fcb,
    const float* __restrict__ kproj, float* __restrict__ out,
    float* __restrict__ wsloss, int* __restrict__ wscorrect) {
  __shared__ __attribute__((aligned(16))) float h0s[4 * Hn];
  __shared__ __attribute__((aligned(16))) float h1s[4 * Hn];
  __shared__ __attribute__((aligned(16))) float qps[4 * Hn];
  __shared__ __attribute__((aligned(16))) float gins[4 * EHn];
  __shared__ __attribute__((aligned(16))) float vas[Hn];
  __shared__ __attribute__((aligned(16))) float wrs[4 * Sn];
  __shared__ __attribute__((aligned(16))) float ep[1024];
  __shared__ float wred[16];
  __shared__ int wredi[16];
  __shared__ float mxv[4], lgt[4];
  __shared__ int tgv[4], tokb[4], mfs[4];

  const int tid = threadIdx.x;
  const int b0 = blockIdx.x * 4;
  const int jj = (tid & 31) | ((tid >> 6) << 5);
  const int grp = (tid >> 5) & 1;

  for (int i = tid; i < 4 * Hn; i += 1024) {
    const int r = i >> 9, j = i & 511;
    h0s[i] = state[(size_t)(b0 + r) * Hn + j];
    h1s[i] = state[(size_t)(Bn + b0 + r) * Hn + j];
  }
  if (tid < 512) vas[tid] = Va[tid];
  if (tid < 4) { tokb[tid] = 1; mfs[tid] = 1; }
  __syncthreads();

  float run_loss = 0.f;

  for (int t = 0; t < Tn; ++t) {
    {
      const int kc = (Hn >> 2) >> 1;
      const int k0 = grp * kc;
      const float4* wp = WaT + jj + (size_t)k0 * Hn;
      float a0 = 0.f, a1 = 0.f, a2 = 0.f, a3 = 0.f;
      for (int k4 = 0; k4 < 64; k4 += 2) {
#pragma unroll
        for (int u = 0; u < 2; ++u) {
          const float4 w = wp[(size_t)(k4 + u) * Hn];
          const float4 x0 = ((const float4*)(h1s))[k0 + k4 + u];
          const float4 x1 = ((const float4*)(h1s + Hn))[k0 + k4 + u];
          const float4 x2 = ((const float4*)(h1s + 2 * Hn))[k0 + k4 + u];
          const float4 x3 = ((const float4*)(h1s + 3 * Hn))[k0 + k4 + u];
          fma4(a0, w, x0); fma4(a1, w, x1); fma4(a2, w, x2); fma4(a3, w, x3);
        }
      }
      a0 += __shfl_xor(a0, 32);
      a1 += __shfl_xor(a1, 32);
      a2 += __shfl_xor(a2, 32);
      a3 += __shfl_xor(a3, 32);
      const float bb = bWa[jj];
      if (!grp) {
        qps[jj] = a0 + bb;
        qps[Hn + jj] = a1 + bb;
      } else {
        qps[2 * Hn + jj] = a2 + bb;
        qps[3 * Hn + jj] = a3 + bb;
      }
    }
    __syncthreads();
    {
      const int p = tid >> 3, q = tid & 7;
      const int r = p >> 5, s = p & 31;
      const float4* kp4 = (const float4*)(kproj + ((size_t)s * Bn + (b0 + r)) * Hn);
      const float4* qp4 = (const float4*)(qps + r * Hn);
      const float4* va4 = (const float4*)vas;
      float partial = 0.f;
      for (int i = 0; i < 16; i += 2) {
#pragma unroll
        for (int u = 0; u < 2; ++u) {
          const int f = q + ((i + u) << 3);
          const float4 k4 = kp4[f], q4 = qp4[f], v4 = va4[f];
          partial += v4.x * tanhf(q4.x + k4.x);
          partial += v4.y * tanhf(q4.y + k4.y);
          partial += v4.z * tanhf(q4.z + k4.z);
          partial += v4.w * tanhf(q4.w + k4.w);
        }
      }
      ep[tid] = partial;
    }
    __syncthreads();
    if (tid < 128) {
      float e = ep[tid * 8] + ep[tid * 8 + 1] + ep[tid * 8 + 2] + ep[tid * 8 + 3] +
                ep[tid * 8 + 4] + ep[tid * 8 + 5] + ep[tid * 8 + 6] + ep[tid * 8 + 7] +
                bVa[0];
      float m = e;
#pragma unroll
      for (int off = 16; off; off >>= 1) m = fmaxf(m, __shfl_xor(m, off));
      const float ex = expf(e - m);
      float ss = ex;
#pragma unroll
      for (int off = 16; off; off >>= 1) ss += __shfl_xor(ss, off);
      const float w = ex / ss;
      const int r = tid >> 5, s = tid & 31;
      wrs[tid] = w;
      out[(size_t)(Bn * Tn) + (size_t)t * (Bn * Sn) + (size_t)(b0 + r) * Sn + s] = w;
    }
    __syncthreads();
    {
      const int h = tid & 511, rp = tid >> 9;
      float c0 = 0.f, c1 = 0.f;
      const float* w0 = wrs + (2 * rp) * 32;
      const float* w1 = wrs + (2 * rp + 1) * 32;
#pragma unroll 4
      for (int s = 0; s < Sn; ++s) {
        const size_t base = ((size_t)s * Bn + b0 + 2 * rp) * Hn + h;
        c0 = fmaf(w0[s], enc[base], c0);
        c1 = fmaf(w1[s], enc[base + Hn], c1);
      }
      gins[(2 * rp) * EHn + En + h] = c0;
      gins[(2 * rp + 1) * EHn + En + h] = c1;
    }
    {
      const int r = tid >> 8, j = tid & 255;
      gins[r * EHn + j] = fmaxf(emb[(size_t)tokb[r] * En + j], 0.f);
    }
    if (tid < 4) tgv[tid] = target[(size_t)(b0 + tid) * Tn + t];
    __syncthreads();
    gru_pair<96, 64>(jj, grp, W0ihT, W0hhT, gins, EHn, h0s, bih0, bhh0);
    gru_pair<64, 64>(jj, grp, W1ihT, W1hhT, h0s, Hn, h1s, bih1, bhh1);
    const int v = tid & 255, rr = tid >> 8;
    float l;
    {
      const float4* wp = fcWT + v;
      const float4* xr = (const float4*)(h1s + rr * Hn);
      float acc = 0.f;
      for (int k4 = 0; k4 < (Hn >> 2); k4 += 4) {
#pragma unroll
        for (int u = 0; u < 4; ++u) {
          const float4 w = wp[(size_t)(k4 + u) * Vn];
          fma4(acc, w, xr[k4 + u]);
        }
      }
      l = acc + fcb[v];
    }
    if (v == tgv[rr]) lgt[rr] = l;
    {
      float m = l;
      int mi = v;
#pragma unroll
      for (int off = 32; off; off >>= 1) {
        const float om = __shfl_xor(m, off);
        const int oi = __shfl_xor(mi, off);
        if (om > m || (om == m && oi < mi)) { m = om; mi = oi; }
      }
      if ((tid & 63) == 0) {
        wred[tid >> 6] = m;
        wredi[tid >> 6] = mi;
      }
    }
    __syncthreads();
    int am_r = 0;
    if (tid < 4) {
      float bm = wred[4 * tid];
      int bi = wredi[4 * tid];
#pragma unroll
      for (int q = 1; q < 4; ++q) {
        const float o = wred[4 * tid + q];
        const int oi = wredi[4 * tid + q];
        if (o > bm || (o == bm && oi < bi)) { bm = o; bi = oi; }
      }
      mxv[tid] = bm;
      am_r = bi;
    }
    __syncthreads();
    {
      float ex = expf(l - mxv[rr]);
#pragma unroll
      for (int off = 32; off; off >>= 1) ex += __shfl_xor(ex, off);
      if ((tid & 63) == 0) wred[tid >> 6] = ex;
    }
    __syncthreads();
    if (tid < 4) {
      tokb[tid] = am_r;
      if (am_r != tgv[tid]) mfs[tid] = 0;
      out[(size_t)(b0 + tid) * Tn + t] = (float)am_r;
    }
    if (tid == 0) {
#pragma unroll
      for (int r = 0; r < 4; ++r) {
        const float s = wred[4 * r] + wred[4 * r + 1] + wred[4 * r + 2] + wred[4 * r + 3];
        run_loss += -(lgt[r] - mxv[r] - logf(s)) * (1.f / 1024.f);
      }
    }
  }

  __syncthreads();
  if (tid == 0) {
    atomicAdd(wsloss, run_loss);
    atomicAdd(wscorrect, mfs[0] + mfs[1] + mfs[2] + mfs[3]);
  }
}

__global__ void ws_init(float* wsloss, int* wscorrect) {
  wsloss[0] = 0.f;
  wscorrect[0] = 0;
}

__global__ void finisher(const float* __restrict__ wsloss,
                         const int* __restrict__ wscorrect, float* __restrict__ out) {
  const size_t base = (size_t)Bn * Tn + (size_t)Tn * Bn * Sn;
  out[base] = wsloss[0];
  out[base + 1] = (float)wscorrect[0];
}

extern "C" void kernel_launch(void* const* d_in, const int* in_sizes, int n_in,
                              void* d_out, int out_size, void* d_ws, size_t ws_size,
                              hipStream_t stream) {
  const float* state = (const float*)d_in[0];
  const float* enc = (const float*)d_in[1];
  const int* target = (const int*)d_in[2];
  const float* emb = (const float*)d_in[3];
  const float* Wa = (const float*)d_in[4];
  const float* bWa = (const float*)d_in[5];
  const float* Ua = (const float*)d_in[6];
  const float* bUa = (const float*)d_in[7];
  const float* Va = (const float*)d_in[8];
  const float* bVa = (const float*)d_in[9];
  const float* Wih0 = (const float*)d_in[10];
  const float* Whh0 = (const float*)d_in[11];
  const float* bih0 = (const float*)d_in[12];
  const float* bhh0 = (const float*)d_in[13];
  const float* Wih1 = (const float*)d_in[14];
  const float* Whh1 = (const float*)d_in[15];
  const float* bih1 = (const float*)d_in[16];
  const float* bhh1 = (const float*)d_in[17];
  const float* fcW = (const float*)d_in[18];
  const float* fcb = (const float*)d_in[19];
  float* out = (float*)d_out;

  const size_t KPROJ_FLOATS = (size_t)Sn * Bn * Hn;  // 64 MB

  const size_t N0IH = (size_t)G3 * (EHn / 4);
  const size_t NHH = (size_t)G3 * (Hn / 4);
  const size_t NWA = (size_t)Hn * (Hn / 4);
  const size_t NFC = (size_t)Vn * (Hn / 4);
  const size_t WT_TOTAL = N0IH + 3 * NHH + NWA + NFC;
  const size_t NEED_A2 = WT_TOTAL * 16 + KPROJ_FLOATS * 4 + 256;

  const size_t NGIN = (size_t)Bn * EHn;
  const size_t NH = (size_t)Bn * Hn;
  const size_t NLG = (size_t)Bn * Vn;
  const size_t EXTRA = NGIN + 5 * NH + NLG;  // gin + h0A/B + h1A/B + qp + logits
  const size_t NEED_NEW = NEED_A2 + EXTRA * 4 + 4 * 2048 + 256;

  if (ws_size >= NEED_NEW) {
    float4* W0ihT = (float4*)d_ws;
    float4* W0hhT = W0ihT + N0IH;
    float4* W1ihT = W0hhT + NHH;
    float4* W1hhT = W1ihT + NHH;
    float4* WaT = W1hhT + NHH;
    float4* fcWT = WaT + NWA;
    float* kproj = (float*)(fcWT + NFC);
    float* gin = kproj + KPROJ_FLOATS;
    float* h0A = gin + NGIN;
    float* h0B = h0A + NH;
    float* h1A = h0B + NH;
    float* h1B = h1A + NH;
    float* qpbuf = h1B + NH;
    float* logits = qpbuf + NH;
    int* tok = (int*)(logits + NLG);
    int* mf = tok + Bn;
    float* wsloss = (float*)(mf + Bn);

    init_bufs<<<2, 512, 0, stream>>>(tok, mf, wsloss);
    transpose_pack<<<(int)((N0IH + 255) / 256), 256, 0, stream>>>(Wih0, W0ihT, G3, EHn);
    transpose_pack<<<(int)((NHH + 255) / 256), 256, 0, stream>>>(Whh0, W0hhT, G3, Hn);
    transpose_pack<<<(int)((NHH + 255) / 256), 256, 0, stream>>>(Wih1, W1ihT, G3, Hn);
    transpose_pack<<<(int)((NHH + 255) / 256), 256, 0, stream>>>(Whh1, W1hhT, G3, Hn);
    transpose_pack<<<(int)((NWA + 255) / 256), 256, 0, stream>>>(Wa, WaT, Hn, Hn);
    transpose_pack<<<(int)((NFC + 255) / 256), 256, 0, stream>>>(fcW, fcWT, Vn, Hn);
    gemm_bias<<<dim3(Hn / 64, (Sn * Bn) / 64), 256, 0, stream>>>(
        enc, Ua, bUa, kproj, Sn * Bn, Hn, Hn);
    qp_only<<<Bn / 4, 1024, 0, stream>>>(state + (size_t)Bn * Hn, WaT, bWa, qpbuf);

    for (int t = 0; t < Tn; ++t) {
      const float* h0cur = (t == 0) ? state : ((t & 1) ? h0A : h0B);
      float* h0nxt = (t & 1) ? h0B : h0A;
      const float* h1cur =
          (t == 0) ? (state + (size_t)Bn * Hn) : ((t & 1) ? h1A : h1B);
      float* h1nxt = (t & 1) ? h1B : h1A;

      attn_gin<<<Bn / 4, 1024, 0, stream>>>(qpbuf, kproj, enc, emb, tok, Va, bVa,
                                            gin, out, t);
      gru_gemm2<192><<<dim3(16, 16), 512, 0, stream>>>(
          gin, EHn / 4, h0cur, W0ihT, W0hhT, bih0, bhh0, h0nxt);
      gru_gemm2<128><<<dim3(16, 16), 512, 0, stream>>>(
          h0nxt, Hn / 4, h1cur, W1ihT, W1hhT, bih1, bhh1, h1nxt);
      fcqp_gemm<<<dim3(24, 16), 512, 0, stream>>>(h1nxt, fcWT, fcb, WaT, bWa,
                                                  logits, qpbuf);
      argmax_loss<<<Bn / 4, 1024, 0, stream>>>(logits, target, t, tok, mf, out,
                                               wsloss);
    }
    finisher2<<<1, 1024, 0, stream>>>(wsloss, mf, out);
  } else if (ws_size >= NEED_A2) {
    float4* W0ihT = (float4*)d_ws;
    float4* W0hhT = W0ihT + N0IH;
    float4* W1ihT = W0hhT + NHH;
    float4* W1hhT = W1ihT + NHH;
    float4* WaT = W1hhT + NHH;
    float4* fcWT = WaT + NWA;
    float* kproj = (float*)(fcWT + NFC);
    float* wsloss = kproj + KPROJ_FLOATS;
    int* wscorrect = (int*)(wsloss + 1);

    ws_init<<<1, 1, 0, stream>>>(wsloss, wscorrect);
    transpose_pack<<<(int)((N0IH + 255) / 256), 256, 0, stream>>>(Wih0, W0ihT, G3, EHn);
    transpose_pack<<<(int)((NHH + 255) / 256), 256, 0, stream>>>(Whh0, W0hhT, G3, Hn);
    transpose_pack<<<(int)((NHH + 255) / 256), 256, 0, stream>>>(Wih1, W1ihT, G3, Hn);
    transpose_pack<<<(int)((NHH + 255) / 256), 256, 0, stream>>>(Whh1, W1hhT, G3, Hn);
    transpose_pack<<<(int)((NWA + 255) / 256), 256, 0, stream>>>(Wa, WaT, Hn, Hn);
    transpose_pack<<<(int)((NFC + 255) / 256), 256, 0, stream>>>(fcW, fcWT, Vn, Hn);
    gemm_bias<<<dim3(Hn / 64, (Sn * Bn) / 64), 256, 0, stream>>>(
        enc, Ua, bUa, kproj, Sn * Bn, Hn, Hn);
    decoder_r4y<<<Bn / 4, 1024, 0, stream>>>(
        state, enc, target, emb, WaT, bWa, Va, bVa, W0ihT, W0hhT, bih0, bhh0,
        W1ihT, W1hhT, bih1, bhh1, fcWT, fcb, kproj, out, wsloss, wscorrect);
    finisher<<<1, 1, 0, stream>>>(wsloss, wscorrect, out);
  }
}

// Round 9
// 7640.238 us; speedup vs baseline: 5.4791x; 1.0221x over previous
//
#include <hip/hip_runtime.h>
#include <math.h>

#define Hn 512
#define En 256
#define Sn 32
#define Bn 1024
#define Tn 32
#define Vn 256
#define G3 1536
#define EHn 768

// fma4 as a FUNCTION, not a macro (R6 lesson: macro param `w` collides with `.w`).
__device__ __forceinline__ void fma4(float& acc, const float4 w, const float4 x) {
  acc = fmaf(w.x, x.x, acc);
  acc = fmaf(w.y, x.y, acc);
  acc = fmaf(w.z, x.z, acc);
  acc = fmaf(w.w, x.w, acc);
}

// ============ one-time weight transpose: W[gate][K] -> WT4[k4*G + g] ============
__global__ __launch_bounds__(256) void transpose_pack(const float* __restrict__ W,
                                                      float4* __restrict__ WT4,
                                                      int G, int K) {
  const int idx = blockIdx.x * blockDim.x + threadIdx.x;
  const int n = G * (K >> 2);
  if (idx >= n) return;
  const int k4 = idx / G, g = idx - k4 * G;
  WT4[idx] = *(const float4*)(W + (size_t)g * K + (k4 << 2));
}

// ============ kproj GEMM: C(M,N) = A(M,K) @ W(N,K)^T + bias ============
__global__ __launch_bounds__(256) void gemm_bias(const float* __restrict__ A,
                                                 const float* __restrict__ Wt,
                                                 const float* __restrict__ bias,
                                                 float* __restrict__ C,
                                                 int M, int N, int K) {
  __shared__ float As[16][68];
  __shared__ float Ws[16][68];
  const int bm = blockIdx.y * 64;
  const int bn = blockIdx.x * 64;
  const int tid = threadIdx.x;
  const int tx = tid & 15;
  const int ty = tid >> 4;
  const int kk = tid & 15;
  const int r0 = tid >> 4;
  float acc[4][4] = {};
  for (int k0 = 0; k0 < K; k0 += 16) {
#pragma unroll
    for (int i = 0; i < 4; ++i) {
      const int m = r0 + (i << 4);
      As[kk][m] = A[(size_t)(bm + m) * K + (k0 + kk)];
      Ws[kk][m] = Wt[(size_t)(bn + m) * K + (k0 + kk)];
    }
    __syncthreads();
#pragma unroll
    for (int k = 0; k < 16; ++k) {
      const float4 a4 = *(const float4*)&As[k][ty * 4];
      const float4 w4 = *(const float4*)&Ws[k][tx * 4];
      const float av[4] = {a4.x, a4.y, a4.z, a4.w};
      const float wv[4] = {w4.x, w4.y, w4.z, w4.w};
#pragma unroll
      for (int i = 0; i < 4; ++i)
#pragma unroll
        for (int j = 0; j < 4; ++j) acc[i][j] = fmaf(av[i], wv[j], acc[i][j]);
    }
    __syncthreads();
  }
#pragma unroll
  for (int i = 0; i < 4; ++i) {
    const size_t m = (size_t)bm + ty * 4 + i;
    float* crow = C + m * N + bn + tx * 4;
#pragma unroll
    for (int j = 0; j < 4; ++j) crow[j] = acc[i][j] + bias[bn + tx * 4 + j];
  }
}

// =================== Path G3: per-phase GEMM + reg double-buffer ===============
// R9: R8 hit 7.8ms; remaining gap is exposed chunk-staging latency (1 block/CU,
// 20 chunks x load->barrier->compute) + one extra launch/step. Fix: register
// prefetch of chunk c+1 under chunk c's compute (T14 async-STAGE), and fuse
// argmax/loss into attn_gin (reads logits of step t-1 directly).

// ---- K1: argmax(t-1) + attention + gin assembly (block-local 4 rows) ----
__global__ __launch_bounds__(1024) void attn_gin(
    const float* __restrict__ logits, const int* __restrict__ target,
    int t, int use_am,
    const float* __restrict__ qp, const float* __restrict__ kproj,
    const float* __restrict__ enc, const float* __restrict__ emb,
    const float* __restrict__ Va, const float* __restrict__ bVa,
    float* __restrict__ gin, int* __restrict__ mf,
    float* __restrict__ out, float* __restrict__ wsloss) {
  __shared__ __attribute__((aligned(16))) float qps[4 * Hn];
  __shared__ __attribute__((aligned(16))) float vas[Hn];
  __shared__ __attribute__((aligned(16))) float ep[1024];
  __shared__ float wrs[128];
  __shared__ float wred[16];
  __shared__ int wredi[16];
  __shared__ float mxv[4], lgt[4];
  __shared__ int tgv[4], tokb[4];
  const int tid = threadIdx.x;
  const int b0 = blockIdx.x * 4;
  const int v = tid & 255, rr = tid >> 8;

  for (int i = tid; i < 4 * Hn; i += 1024)
    qps[i] = qp[(size_t)(b0 + (i >> 9)) * Hn + (i & 511)];
  if (tid < 512) vas[tid] = Va[tid];
  float l = 0.f;
  if (use_am) {
    l = logits[(size_t)(b0 + rr) * Vn + v];
    if (tid < 4) tgv[tid] = target[(size_t)(b0 + tid) * Tn + (t - 1)];
  } else {
    if (tid < 4) tokb[tid] = 1;
  }
  __syncthreads();
  if (use_am) {
    if (v == tgv[rr]) lgt[rr] = l;
    {
      float m = l;
      int mi = v;
#pragma unroll
      for (int off = 32; off; off >>= 1) {
        const float om = __shfl_xor(m, off);
        const int oi = __shfl_xor(mi, off);
        if (om > m || (om == m && oi < mi)) { m = om; mi = oi; }
      }
      if ((tid & 63) == 0) {
        wred[tid >> 6] = m;
        wredi[tid >> 6] = mi;
      }
    }
    __syncthreads();
    if (tid < 4) {
      float bm = wred[4 * tid];
      int bi = wredi[4 * tid];
#pragma unroll
      for (int q = 1; q < 4; ++q) {
        const float o = wred[4 * tid + q];
        const int oi = wredi[4 * tid + q];
        if (o > bm || (o == bm && oi < bi)) { bm = o; bi = oi; }
      }
      mxv[tid] = bm;
      tokb[tid] = bi;
      if (bi != tgv[tid]) mf[b0 + tid] = 0;
      out[(size_t)(b0 + tid) * Tn + (t - 1)] = (float)bi;
    }
    __syncthreads();
    {
      float ex = expf(l - mxv[rr]);
#pragma unroll
      for (int off = 32; off; off >>= 1) ex += __shfl_xor(ex, off);
      if ((tid & 63) == 0) wred[tid >> 6] = ex;
    }
    __syncthreads();
    if (tid == 0) {
      float lp = 0.f;
#pragma unroll
      for (int r = 0; r < 4; ++r) {
        const float s =
            wred[4 * r] + wred[4 * r + 1] + wred[4 * r + 2] + wred[4 * r + 3];
        lp += -(lgt[r] - mxv[r] - logf(s)) * (1.f / 1024.f);
      }
      atomicAdd(wsloss, lp);
    }
  }
  __syncthreads();  // tokb ready for emb phase; qps/vas ready
  // e: 8 threads per (r,s) pair
  {
    const int p = tid >> 3, q = tid & 7;
    const int r = p >> 5, s = p & 31;
    const float4* kp4 = (const float4*)(kproj + ((size_t)s * Bn + (b0 + r)) * Hn);
    const float4* qp4 = (const float4*)(qps + r * Hn);
    const float4* va4 = (const float4*)vas;
    float partial = 0.f;
    for (int i = 0; i < 16; i += 2) {
#pragma unroll
      for (int u = 0; u < 2; ++u) {
        const int f = q + ((i + u) << 3);
        const float4 k4 = kp4[f], q4 = qp4[f], v4 = va4[f];
        partial += v4.x * tanhf(q4.x + k4.x);
        partial += v4.y * tanhf(q4.y + k4.y);
        partial += v4.z * tanhf(q4.z + k4.z);
        partial += v4.w * tanhf(q4.w + k4.w);
      }
    }
    ep[tid] = partial;
  }
  __syncthreads();
  if (tid < 128) {
    float e = ep[tid * 8] + ep[tid * 8 + 1] + ep[tid * 8 + 2] + ep[tid * 8 + 3] +
              ep[tid * 8 + 4] + ep[tid * 8 + 5] + ep[tid * 8 + 6] + ep[tid * 8 + 7] +
              bVa[0];
    float m = e;
#pragma unroll
    for (int off = 16; off; off >>= 1) m = fmaxf(m, __shfl_xor(m, off));
    const float ex = expf(e - m);
    float ss = ex;
#pragma unroll
    for (int off = 16; off; off >>= 1) ss += __shfl_xor(ss, off);
    const float w = ex / ss;
    const int r = tid >> 5, s = tid & 31;
    wrs[tid] = w;
    out[(size_t)(Bn * Tn) + (size_t)t * (Bn * Sn) + (size_t)(b0 + r) * Sn + s] = w;
  }
  __syncthreads();
  {
    const int h = tid & 511, rp = tid >> 9;
    float c0 = 0.f, c1 = 0.f;
    const float* w0 = wrs + (2 * rp) * 32;
    const float* w1 = wrs + (2 * rp + 1) * 32;
#pragma unroll 4
    for (int s = 0; s < Sn; ++s) {
      const size_t base = ((size_t)s * Bn + b0 + 2 * rp) * Hn + h;
      c0 = fmaf(w0[s], enc[base], c0);
      c1 = fmaf(w1[s], enc[base + Hn], c1);
    }
    gin[(size_t)(b0 + 2 * rp) * EHn + En + h] = c0;
    gin[(size_t)(b0 + 2 * rp + 1) * EHn + En + h] = c1;
  }
  {
    const int r = tid >> 8, j = tid & 255;
    gin[(size_t)(b0 + r) * EHn + j] = fmaxf(emb[(size_t)tokb[r] * En + j], 0.f);
  }
}

// ---- chunk compute for GRU GEMM (accumulator for wn selected by caller) ----
__device__ __forceinline__ void gru_chunk(
    const float4* __restrict__ xs4, const float4* __restrict__ ws4,
    int row0, int tx, float (&ar)[4], float (&az)[4], float (&aw)[4]) {
#pragma unroll 2
  for (int k4 = 0; k4 < 16; ++k4) {
    const float4 wr = ws4[(k4 * 3 + 0) * 32 + tx];
    const float4 wz = ws4[(k4 * 3 + 1) * 32 + tx];
    const float4 wn = ws4[(k4 * 3 + 2) * 32 + tx];
    float4 xr[4];
#pragma unroll
    for (int rr = 0; rr < 4; ++rr) xr[rr] = xs4[(row0 + rr) * 16 + k4];
#pragma unroll
    for (int rr = 0; rr < 4; ++rr) {
      fma4(ar[rr], wr, xr[rr]);
      fma4(az[rr], wz, xr[rr]);
      fma4(aw[rr], wn, xr[rr]);
    }
  }
}

// ---- K2/K3: GRU as LDS-staged GEMM with register double-buffer.
// BM=64 x BN=32(x3 gates). Grid (16 j, 16 m) = 256 blocks, 512 threads.
template <int KIH4>
__global__ __launch_bounds__(512) __attribute__((amdgpu_waves_per_eu(2)))
void gru_gemm3(
    const float* __restrict__ xsrc, int xsF4,
    const float* __restrict__ hsrc,
    const float4* __restrict__ WihT, const float4* __restrict__ WhhT,
    const float* __restrict__ bih, const float* __restrict__ bhh,
    float* __restrict__ hdst) {
  __shared__ float4 xs4[64 * 16];      // 16 KB
  __shared__ float4 ws4[16 * 3 * 32];  // 24 KB, layout [k4][g][col]
  const int tid = threadIdx.x;
  const int J0 = blockIdx.x * 32;
  const int R0 = blockIdx.y * 64;
  const int tx = tid & 31;
  const int ty = tid >> 5;  // 0..15
  const int row0 = ty * 4;
  constexpr int NCI = KIH4 / 16;
  // staging coords
  const int xr0 = tid >> 4, xf0 = tid & 15;
  const int xr1 = (tid + 512) >> 4, xf1 = (tid + 512) & 15;
  const int wk0 = tid / 96, wm0 = tid - wk0 * 96;
  const int wk1 = (tid + 512) / 96, wm1 = (tid + 512) - wk1 * 96;
  const int wk2 = (tid + 1024) / 96, wm2 = (tid + 1024) - wk2 * 96;
  const int wo0 = (wm0 >> 5) * 512 + J0 + (wm0 & 31);
  const int wo1 = (wm1 >> 5) * 512 + J0 + (wm1 & 31);
  const int wo2 = (wm2 >> 5) * 512 + J0 + (wm2 & 31);
  const float4* x4 = (const float4*)xsrc;
  const float4* h4 = (const float4*)hsrc;
  float ar[4] = {}, az[4] = {}, ai[4] = {}, an[4] = {};
  // prefetch ih chunk 0
  float4 px0 = x4[(size_t)(R0 + xr0) * xsF4 + xf0];
  float4 px1 = x4[(size_t)(R0 + xr1) * xsF4 + xf1];
  float4 pw0 = WihT[(size_t)wk0 * G3 + wo0];
  float4 pw1 = WihT[(size_t)wk1 * G3 + wo1];
  float4 pw2 = WihT[(size_t)wk2 * G3 + wo2];
  for (int c = 0; c < NCI + 8; ++c) {
    __syncthreads();  // previous chunk's compute done -> LDS reusable
    xs4[tid] = px0;
    xs4[tid + 512] = px1;
    ws4[tid] = pw0;
    ws4[tid + 512] = pw1;
    ws4[tid + 1024] = pw2;
    // issue next chunk's loads; they complete under this chunk's compute
    if (c + 1 < NCI) {
      const int cc = c + 1;
      px0 = x4[(size_t)(R0 + xr0) * xsF4 + cc * 16 + xf0];
      px1 = x4[(size_t)(R0 + xr1) * xsF4 + cc * 16 + xf1];
      pw0 = WihT[(size_t)(cc * 16 + wk0) * G3 + wo0];
      pw1 = WihT[(size_t)(cc * 16 + wk1) * G3 + wo1];
      pw2 = WihT[(size_t)(cc * 16 + wk2) * G3 + wo2];
    } else if (c + 1 < NCI + 8) {
      const int cc = c + 1 - NCI;
      px0 = h4[(size_t)(R0 + xr0) * (Hn / 4) + cc * 16 + xf0];
      px1 = h4[(size_t)(R0 + xr1) * (Hn / 4) + cc * 16 + xf1];
      pw0 = WhhT[(size_t)(cc * 16 + wk0) * G3 + wo0];
      pw1 = WhhT[(size_t)(cc * 16 + wk1) * G3 + wo1];
      pw2 = WhhT[(size_t)(cc * 16 + wk2) * G3 + wo2];
    }
    __syncthreads();  // LDS tiles ready
    if (c < NCI)
      gru_chunk(xs4, ws4, row0, tx, ar, az, ai);
    else
      gru_chunk(xs4, ws4, row0, tx, ar, az, an);
  }
  const int g0 = J0 + tx;
  const float bir = bih[g0], biz = bih[g0 + 512], bin = bih[g0 + 1024];
  const float bhr = bhh[g0], bhz = bhh[g0 + 512], bhn = bhh[g0 + 1024];
#pragma unroll
  for (int rr = 0; rr < 4; ++rr) {
    const int row = R0 + row0 + rr;
    const float rg = 1.f / (1.f + expf(-(ar[rr] + bir + bhr)));
    const float zg = 1.f / (1.f + expf(-(az[rr] + biz + bhz)));
    const float ng = tanhf(ai[rr] + bin + rg * (an[rr] + bhn));
    const float hold = hsrc[(size_t)row * Hn + g0];
    hdst[(size_t)row * Hn + g0] = (1.f - zg) * ng + zg * hold;
  }
}

// ---- K4: fc and qp as tiled GEMM (register double-buffered), one launch.
// Grid (24 j, 16 m): jt<8 -> fc tile; jt>=8 -> qp tile.
__global__ __launch_bounds__(512) __attribute__((amdgpu_waves_per_eu(2)))
void fcqp_gemm(
    const float* __restrict__ h1,
    const float4* __restrict__ fcWT, const float* __restrict__ fcb,
    const float4* __restrict__ WaT, const float* __restrict__ bWa,
    float* __restrict__ logits, float* __restrict__ qp) {
  __shared__ float4 xs4[64 * 16];  // 16 KB
  __shared__ float4 ws4[16 * 32];  // 8 KB
  const int tid = threadIdx.x;
  const int jt = blockIdx.x;
  const int R0 = blockIdx.y * 64;
  const bool isfc = jt < 8;
  const int J0 = isfc ? jt * 32 : (jt - 8) * 32;
  const float4* W = isfc ? fcWT : WaT;
  const int ldW = isfc ? Vn : Hn;
  const int tx = tid & 31;
  const int ty = tid >> 5;
  const int row0 = ty * 4;
  const int xr0 = tid >> 4, xf0 = tid & 15;
  const int xr1 = (tid + 512) >> 4, xf1 = (tid + 512) & 15;
  const int wk = tid >> 5, wc = tid & 31;
  float a[4] = {};
  const float4* h4 = (const float4*)h1;
  float4 px0 = h4[(size_t)(R0 + xr0) * (Hn / 4) + xf0];
  float4 px1 = h4[(size_t)(R0 + xr1) * (Hn / 4) + xf1];
  float4 pw = W[(size_t)wk * ldW + J0 + wc];
  for (int c = 0; c < 8; ++c) {
    __syncthreads();
    xs4[tid] = px0;
    xs4[tid + 512] = px1;
    ws4[tid] = pw;
    if (c + 1 < 8) {
      const int cc = c + 1;
      px0 = h4[(size_t)(R0 + xr0) * (Hn / 4) + cc * 16 + xf0];
      px1 = h4[(size_t)(R0 + xr1) * (Hn / 4) + cc * 16 + xf1];
      pw = W[(size_t)(cc * 16 + wk) * ldW + J0 + wc];
    }
    __syncthreads();
#pragma unroll 4
    for (int k4 = 0; k4 < 16; ++k4) {
      const float4 w = ws4[k4 * 32 + tx];
      float4 xr[4];
#pragma unroll
      for (int rr = 0; rr < 4; ++rr) xr[rr] = xs4[(row0 + rr) * 16 + k4];
#pragma unroll
      for (int rr = 0; rr < 4; ++rr) fma4(a[rr], w, xr[rr]);
    }
  }
  if (isfc) {
    const float bb = fcb[J0 + tx];
#pragma unroll
    for (int rr = 0; rr < 4; ++rr)
      logits[(size_t)(R0 + row0 + rr) * Vn + J0 + tx] = a[rr] + bb;
  } else {
    const float bb = bWa[J0 + tx];
#pragma unroll
    for (int rr = 0; rr < 4; ++rr)
      qp[(size_t)(R0 + row0 + rr) * Hn + J0 + tx] = a[rr] + bb;
  }
}

// ---- K5: final-step argmax + loss + token (reads logits only) ----
__global__ __launch_bounds__(1024) void argmax_loss(
    const float* __restrict__ logits, const int* __restrict__ target, int t,
    int* __restrict__ tok, int* __restrict__ mf,
    float* __restrict__ out, float* __restrict__ wsloss) {
  __shared__ float wred[16];
  __shared__ int wredi[16];
  __shared__ float mxv[4], lgt[4];
  __shared__ int tgv[4];
  const int tid = threadIdx.x;
  const int b0 = blockIdx.x * 4;
  const int v = tid & 255, rr = tid >> 8;
  const float l = logits[(size_t)(b0 + rr) * Vn + v];
  if (tid < 4) tgv[tid] = target[(size_t)(b0 + tid) * Tn + t];
  __syncthreads();
  if (v == tgv[rr]) lgt[rr] = l;
  {
    float m = l;
    int mi = v;
#pragma unroll
    for (int off = 32; off; off >>= 1) {
      const float om = __shfl_xor(m, off);
      const int oi = __shfl_xor(mi, off);
      if (om > m || (om == m && oi < mi)) { m = om; mi = oi; }
    }
    if ((tid & 63) == 0) {
      wred[tid >> 6] = m;
      wredi[tid >> 6] = mi;
    }
  }
  __syncthreads();
  int am_r = 0;
  if (tid < 4) {
    float bm = wred[4 * tid];
    int bi = wredi[4 * tid];
#pragma unroll
    for (int q = 1; q < 4; ++q) {
      const float o = wred[4 * tid + q];
      const int oi = wredi[4 * tid + q];
      if (o > bm || (o == bm && oi < bi)) { bm = o; bi = oi; }
    }
    mxv[tid] = bm;
    am_r = bi;
  }
  __syncthreads();
  {
    float ex = expf(l - mxv[rr]);
#pragma unroll
    for (int off = 32; off; off >>= 1) ex += __shfl_xor(ex, off);
    if ((tid & 63) == 0) wred[tid >> 6] = ex;
  }
  __syncthreads();
  if (tid < 4) {
    tok[b0 + tid] = am_r;
    if (am_r != tgv[tid]) mf[b0 + tid] = 0;
    out[(size_t)(b0 + tid) * Tn + t] = (float)am_r;
  }
  if (tid == 0) {
    float lp = 0.f;
#pragma unroll
    for (int r = 0; r < 4; ++r) {
      const float s = wred[4 * r] + wred[4 * r + 1] + wred[4 * r + 2] + wred[4 * r + 3];
      lp += -(lgt[r] - mxv[r] - logf(s)) * (1.f / 1024.f);
    }
    atomicAdd(wsloss, lp);
  }
}

// ---- qp for t=0 (from initial h1 = state layer 1) ----
__global__ __launch_bounds__(1024) void qp_only(
    const float* __restrict__ h1src, const float4* __restrict__ WaT,
    const float* __restrict__ bWa, float* __restrict__ qp) {
  __shared__ __attribute__((aligned(16))) float h1s[4 * Hn];
  const int tid = threadIdx.x;
  const int b0 = blockIdx.x * 4;
  for (int i = tid; i < 4 * Hn; i += 1024)
    h1s[i] = h1src[(size_t)(b0 + (i >> 9)) * Hn + (i & 511)];
  __syncthreads();
  const int jj = (tid & 31) | ((tid >> 6) << 5);
  const int grp = (tid >> 5) & 1;
  const int k0 = grp * 64;
  const float4* wp = WaT + jj + (size_t)k0 * Hn;
  float a0 = 0.f, a1 = 0.f, a2 = 0.f, a3 = 0.f;
  for (int k4 = 0; k4 < 64; k4 += 2) {
#pragma unroll
    for (int u = 0; u < 2; ++u) {
      const float4 w = wp[(size_t)(k4 + u) * Hn];
      const float4 x0 = ((const float4*)(h1s))[k0 + k4 + u];
      const float4 x1 = ((const float4*)(h1s + Hn))[k0 + k4 + u];
      const float4 x2 = ((const float4*)(h1s + 2 * Hn))[k0 + k4 + u];
      const float4 x3 = ((const float4*)(h1s + 3 * Hn))[k0 + k4 + u];
      fma4(a0, w, x0); fma4(a1, w, x1); fma4(a2, w, x2); fma4(a3, w, x3);
    }
  }
  a0 += __shfl_xor(a0, 32);
  a1 += __shfl_xor(a1, 32);
  a2 += __shfl_xor(a2, 32);
  a3 += __shfl_xor(a3, 32);
  const float bb = bWa[jj];
  if (!grp) {
    qp[(size_t)(b0 + 0) * Hn + jj] = a0 + bb;
    qp[(size_t)(b0 + 1) * Hn + jj] = a1 + bb;
  } else {
    qp[(size_t)(b0 + 2) * Hn + jj] = a2 + bb;
    qp[(size_t)(b0 + 3) * Hn + jj] = a3 + bb;
  }
}

__global__ void init_bufs(int* tok, int* mf, float* wsloss) {
  const int i = blockIdx.x * blockDim.x + threadIdx.x;
  if (i < Bn) { tok[i] = 1; mf[i] = 1; }
  if (i == 0) wsloss[0] = 0.f;
}

__global__ __launch_bounds__(1024) void finisher2(const float* __restrict__ wsloss,
                                                  const int* __restrict__ mf,
                                                  float* __restrict__ out) {
  __shared__ int s[1024];
  const int tid = threadIdx.x;
  s[tid] = mf[tid];
  __syncthreads();
  for (int off = 512; off; off >>= 1) {
    if (tid < off) s[tid] += s[tid + off];
    __syncthreads();
  }
  if (tid == 0) {
    const size_t base = (size_t)Bn * Tn + (size_t)Tn * Bn * Sn;
    out[base] = wsloss[0];
    out[base + 1] = (float)s[0];
  }
}

// ============ tier-2 fallback: R3-verified r4y decoder (9.95 ms) ===============
template <int KCI, int KCH>
__device__ __forceinline__ void gru_pair(
    int jj, int grp,
    const float4* __restrict__ WihT,
    const float4* __restrict__ WhhT,
    const float* __restrict__ x, int xstride,
    float* __restrict__ h,
    const float* __restrict__ bih, const float* __restrict__ bhh) {
  float ar[4] = {}, az[4] = {}, ain[4] = {}, ahn[4] = {};
  {
    const int k0 = grp * KCI;
    const float4* w0 = WihT + jj + (size_t)k0 * G3;
    const float4* w1 = WihT + jj + 512 + (size_t)k0 * G3;
    const float4* w2 = WihT + jj + 1024 + (size_t)k0 * G3;
    for (int k4 = 0; k4 < KCI; k4 += 2) {
#pragma unroll
      for (int u = 0; u < 2; ++u) {
        const float4 a = w0[(size_t)(k4 + u) * G3];
        const float4 b = w1[(size_t)(k4 + u) * G3];
        const float4 c = w2[(size_t)(k4 + u) * G3];
#pragma unroll
        for (int r = 0; r < 4; ++r) {
          const float4 xv = ((const float4*)(x + r * xstride))[k0 + k4 + u];
          fma4(ar[r], a, xv);
          fma4(az[r], b, xv);
          fma4(ain[r], c, xv);
        }
      }
    }
  }
  {
    const int k0 = grp * KCH;
    const float4* w0 = WhhT + jj + (size_t)k0 * G3;
    const float4* w1 = WhhT + jj + 512 + (size_t)k0 * G3;
    const float4* w2 = WhhT + jj + 1024 + (size_t)k0 * G3;
    for (int k4 = 0; k4 < KCH; k4 += 2) {
#pragma unroll
      for (int u = 0; u < 2; ++u) {
        const float4 a = w0[(size_t)(k4 + u) * G3];
        const float4 b = w1[(size_t)(k4 + u) * G3];
        const float4 c = w2[(size_t)(k4 + u) * G3];
#pragma unroll
        for (int r = 0; r < 4; ++r) {
          const float4 xv = ((const float4*)(h + r * Hn))[k0 + k4 + u];
          fma4(ar[r], a, xv);
          fma4(az[r], b, xv);
          fma4(ahn[r], c, xv);
        }
      }
    }
  }
#pragma unroll
  for (int r = 0; r < 4; ++r) {
    ar[r] += __shfl_xor(ar[r], 32);
    az[r] += __shfl_xor(az[r], 32);
    ain[r] += __shfl_xor(ain[r], 32);
    ahn[r] += __shfl_xor(ahn[r], 32);
  }
  const float bir = bih[jj], biz = bih[jj + 512], bin = bih[jj + 1024];
  const float bhr = bhh[jj], bhz = bhh[jj + 512], bhn = bhh[jj + 1024];
  const int r2 = grp * 2;
  const float s0r = (grp ? ar[2] : ar[0]) + bir + bhr;
  const float s0z = (grp ? az[2] : az[0]) + biz + bhz;
  const float s0i = (grp ? ain[2] : ain[0]) + bin;
  const float s0h = (grp ? ahn[2] : ahn[0]) + bhn;
  const float s1r = (grp ? ar[3] : ar[1]) + bir + bhr;
  const float s1z = (grp ? az[3] : az[1]) + biz + bhz;
  const float s1i = (grp ? ain[3] : ain[1]) + bin;
  const float s1h = (grp ? ahn[3] : ahn[1]) + bhn;
  const float rg0 = 1.f / (1.f + expf(-s0r));
  const float zg0 = 1.f / (1.f + expf(-s0z));
  const float ng0 = tanhf(s0i + rg0 * s0h);
  const float rg1 = 1.f / (1.f + expf(-s1r));
  const float zg1 = 1.f / (1.f + expf(-s1z));
  const float ng1 = tanhf(s1i + rg1 * s1h);
  const float h0old = h[(r2 + 0) * Hn + jj];
  const float h1old = h[(r2 + 1) * Hn + jj];
  const float hn0 = (1.f - zg0) * ng0 + zg0 * h0old;
  const float hn1 = (1.f - zg1) * ng1 + zg1 * h1old;
  __syncthreads();
  h[(r2 + 0) * Hn + jj] = hn0;
  h[(r2 + 1) * Hn + jj] = hn1;
  __syncthreads();
}

__global__ __launch_bounds__(1024) __attribute__((amdgpu_waves_per_eu(4, 4)))
void decoder_r4y(
    const float* __restrict__ state, const float* __restrict__ enc,
    const int* __restrict__ target, const float* __restrict__ emb,
    const float4* __restrict__ WaT, const float* __restrict__ bWa,
    const float* __restrict__ Va, const float* __restrict__ bVa,
    const float4* __restrict__ W0ihT, const float4* __restrict__ W0hhT,
    const float* __restrict__ bih0, const float* __restrict__ bhh0,
    const float4* __restrict__ W1ihT, const float4* __restrict__ W1hhT,
    const float* __restrict__ bih1, const float* __restrict__ bhh1,
    const float4* __restrict__ fcWT, const float* __restrict__ fcb,
    const float* __restrict__ kproj, float* __restrict__ out,
    float* __restrict__ wsloss, int* __restrict__ wscorrect) {
  __shared__ __attribute__((aligned(16))) float h0s[4 * Hn];
  __shared__ __attribute__((aligned(16))) float h1s[4 * Hn];
  __shared__ __attribute__((aligned(16))) float qps[4 * Hn];
  __shared__ __attribute__((aligned(16))) float gins[4 * EHn];
  __shared__ __attribute__((aligned(16))) float vas[Hn];
  __shared__ __attribute__((aligned(16))) float wrs[4 * Sn];
  __shared__ __attribute__((aligned(16))) float ep[1024];
  __shared__ float wred[16];
  __shared__ int wredi[16];
  __shared__ float mxv[4], lgt[4];
  __shared__ int tgv[4], tokb[4], mfs[4];

  const int tid = threadIdx.x;
  const int b0 = blockIdx.x * 4;
  const int jj = (tid & 31) | ((tid >> 6) << 5);
  const int grp = (tid >> 5) & 1;

  for (int i = tid; i < 4 * Hn; i += 1024) {
    const int r = i >> 9, j = i & 511;
    h0s[i] = state[(size_t)(b0 + r) * Hn + j];
    h1s[i] = state[(size_t)(Bn + b0 + r) * Hn + j];
  }
  if (tid < 512) vas[tid] = Va[tid];
  if (tid < 4) { tokb[tid] = 1; mfs[tid] = 1; }
  __syncthreads();

  float run_loss = 0.f;

  for (int t = 0; t < Tn; ++t) {
    {
      const int kc = (Hn >> 2) >> 1;
      const int k0 = grp * kc;
      const float4* wp = WaT + jj + (size_t)k0 * Hn;
      float a0 = 0.f, a1 = 0.f, a2 = 0.f, a3 = 0.f;
      for (int k4 = 0; k4 < 64; k4 += 2) {
#pragma unroll
        for (int u = 0; u < 2; ++u) {
          const float4 w = wp[(size_t)(k4 + u) * Hn];
          const float4 x0 = ((const float4*)(h1s))[k0 + k4 + u];
          const float4 x1 = ((const float4*)(h1s + Hn))[k0 + k4 + u];
          const float4 x2 = ((const float4*)(h1s + 2 * Hn))[k0 + k4 + u];
          const float4 x3 = ((const float4*)(h1s + 3 * Hn))[k0 + k4 + u];
          fma4(a0, w, x0); fma4(a1, w, x1); fma4(a2, w, x2); fma4(a3, w, x3);
        }
      }
      a0 += __shfl_xor(a0, 32);
      a1 += __shfl_xor(a1, 32);
      a2 += __shfl_xor(a2, 32);
      a3 += __shfl_xor(a3, 32);
      const float bb = bWa[jj];
      if (!grp) {
        qps[jj] = a0 + bb;
        qps[Hn + jj] = a1 + bb;
      } else {
        qps[2 * Hn + jj] = a2 + bb;
        qps[3 * Hn + jj] = a3 + bb;
      }
    }
    __syncthreads();
    {
      const int p = tid >> 3, q = tid & 7;
      const int r = p >> 5, s = p & 31;
      const float4* kp4 = (const float4*)(kproj + ((size_t)s * Bn + (b0 + r)) * Hn);
      const float4* qp4 = (const float4*)(qps + r * Hn);
      const float4* va4 = (const float4*)vas;
      float partial = 0.f;
      for (int i = 0; i < 16; i += 2) {
#pragma unroll
        for (int u = 0; u < 2; ++u) {
          const int f = q + ((i + u) << 3);
          const float4 k4 = kp4[f], q4 = qp4[f], v4 = va4[f];
          partial += v4.x * tanhf(q4.x + k4.x);
          partial += v4.y * tanhf(q4.y + k4.y);
          partial += v4.z * tanhf(q4.z + k4.z);
          partial += v4.w * tanhf(q4.w + k4.w);
        }
      }
      ep[tid] = partial;
    }
    __syncthreads();
    if (tid < 128) {
      float e = ep[tid * 8] + ep[tid * 8 + 1] + ep[tid * 8 + 2] + ep[tid * 8 + 3] +
                ep[tid * 8 + 4] + ep[tid * 8 + 5] + ep[tid * 8 + 6] + ep[tid * 8 + 7] +
                bVa[0];
      float m = e;
#pragma unroll
      for (int off = 16; off; off >>= 1) m = fmaxf(m, __shfl_xor(m, off));
      const float ex = expf(e - m);
      float ss = ex;
#pragma unroll
      for (int off = 16; off; off >>= 1) ss += __shfl_xor(ss, off);
      const float w = ex / ss;
      const int r = tid >> 5, s = tid & 31;
      wrs[tid] = w;
      out[(size_t)(Bn * Tn) + (size_t)t * (Bn * Sn) + (size_t)(b0 + r) * Sn + s] = w;
    }
    __syncthreads();
    {
      const int h = tid & 511, rp = tid >> 9;
      float c0 = 0.f, c1 = 0.f;
      const float* w0 = wrs + (2 * rp) * 32;
      const float* w1 = wrs + (2 * rp + 1) * 32;
#pragma unroll 4
      for (int s = 0; s < Sn; ++s) {
        const size_t base = ((size_t)s * Bn + b0 + 2 * rp) * Hn + h;
        c0 = fmaf(w0[s], enc[base], c0);
        c1 = fmaf(w1[s], enc[base + Hn], c1);
      }
      gins[(2 * rp) * EHn + En + h] = c0;
      gins[(2 * rp + 1) * EHn + En + h] = c1;
    }
    {
      const int r = tid >> 8, j = tid & 255;
      gins[r * EHn + j] = fmaxf(emb[(size_t)tokb[r] * En + j], 0.f);
    }
    if (tid < 4) tgv[tid] = target[(size_t)(b0 + tid) * Tn + t];
    __syncthreads();
    gru_pair<96, 64>(jj, grp, W0ihT, W0hhT, gins, EHn, h0s, bih0, bhh0);
    gru_pair<64, 64>(jj, grp, W1ihT, W1hhT, h0s, Hn, h1s, bih1, bhh1);
    const int v = tid & 255, rr = tid >> 8;
    float l;
    {
      const float4* wp = fcWT + v;
      const float4* xr = (const float4*)(h1s + rr * Hn);
      float acc = 0.f;
      for (int k4 = 0; k4 < (Hn >> 2); k4 += 4) {
#pragma unroll
        for (int u = 0; u < 4; ++u) {
          const float4 w = wp[(size_t)(k4 + u) * Vn];
          fma4(acc, w, xr[k4 + u]);
        }
      }
      l = acc + fcb[v];
    }
    if (v == tgv[rr]) lgt[rr] = l;
    {
      float m = l;
      int mi = v;
#pragma unroll
      for (int off = 32; off; off >>= 1) {
        const float om = __shfl_xor(m, off);
        const int oi = __shfl_xor(mi, off);
        if (om > m || (om == m && oi < mi)) { m = om; mi = oi; }
      }
      if ((tid & 63) == 0) {
        wred[tid >> 6] = m;
        wredi[tid >> 6] = mi;
      }
    }
    __syncthreads();
    int am_r = 0;
    if (tid < 4) {
      float bm = wred[4 * tid];
      int bi = wredi[4 * tid];
#pragma unroll
      for (int q = 1; q < 4; ++q) {
        const float o = wred[4 * tid + q];
        const int oi = wredi[4 * tid + q];
        if (o > bm || (o == bm && oi < bi)) { bm = o; bi = oi; }
      }
      mxv[tid] = bm;
      am_r = bi;
    }
    __syncthreads();
    {
      float ex = expf(l - mxv[rr]);
#pragma unroll
      for (int off = 32; off; off >>= 1) ex += __shfl_xor(ex, off);
      if ((tid & 63) == 0) wred[tid >> 6] = ex;
    }
    __syncthreads();
    if (tid < 4) {
      tokb[tid] = am_r;
      if (am_r != tgv[tid]) mfs[tid] = 0;
      out[(size_t)(b0 + tid) * Tn + t] = (float)am_r;
    }
    if (tid == 0) {
#pragma unroll
      for (int r = 0; r < 4; ++r) {
        const float s = wred[4 * r] + wred[4 * r + 1] + wred[4 * r + 2] + wred[4 * r + 3];
        run_loss += -(lgt[r] - mxv[r] - logf(s)) * (1.f / 1024.f);
      }
    }
  }

  __syncthreads();
  if (tid == 0) {
    atomicAdd(wsloss, run_loss);
    atomicAdd(wscorrect, mfs[0] + mfs[1] + mfs[2] + mfs[3]);
  }
}

__global__ void ws_init(float* wsloss, int* wscorrect) {
  wsloss[0] = 0.f;
  wscorrect[0] = 0;
}

__global__ void finisher(const float* __restrict__ wsloss,
                         const int* __restrict__ wscorrect, float* __restrict__ out) {
  const size_t base = (size_t)Bn * Tn + (size_t)Tn * Bn * Sn;
  out[base] = wsloss[0];
  out[base + 1] = (float)wscorrect[0];
}

extern "C" void kernel_launch(void* const* d_in, const int* in_sizes, int n_in,
                              void* d_out, int out_size, void* d_ws, size_t ws_size,
                              hipStream_t stream) {
  const float* state = (const float*)d_in[0];
  const float* enc = (const float*)d_in[1];
  const int* target = (const int*)d_in[2];
  const float* emb = (const float*)d_in[3];
  const float* Wa = (const float*)d_in[4];
  const float* bWa = (const float*)d_in[5];
  const float* Ua = (const float*)d_in[6];
  const float* bUa = (const float*)d_in[7];
  const float* Va = (const float*)d_in[8];
  const float* bVa = (const float*)d_in[9];
  const float* Wih0 = (const float*)d_in[10];
  const float* Whh0 = (const float*)d_in[11];
  const float* bih0 = (const float*)d_in[12];
  const float* bhh0 = (const float*)d_in[13];
  const float* Wih1 = (const float*)d_in[14];
  const float* Whh1 = (const float*)d_in[15];
  const float* bih1 = (const float*)d_in[16];
  const float* bhh1 = (const float*)d_in[17];
  const float* fcW = (const float*)d_in[18];
  const float* fcb = (const float*)d_in[19];
  float* out = (float*)d_out;

  const size_t KPROJ_FLOATS = (size_t)Sn * Bn * Hn;  // 64 MB

  const size_t N0IH = (size_t)G3 * (EHn / 4);
  const size_t NHH = (size_t)G3 * (Hn / 4);
  const size_t NWA = (size_t)Hn * (Hn / 4);
  const size_t NFC = (size_t)Vn * (Hn / 4);
  const size_t WT_TOTAL = N0IH + 3 * NHH + NWA + NFC;
  const size_t NEED_A2 = WT_TOTAL * 16 + KPROJ_FLOATS * 4 + 256;

  const size_t NGIN = (size_t)Bn * EHn;
  const size_t NH = (size_t)Bn * Hn;
  const size_t NLG = (size_t)Bn * Vn;
  const size_t EXTRA = NGIN + 5 * NH + NLG;  // gin + h0A/B + h1A/B + qp + logits
  const size_t NEED_NEW = NEED_A2 + EXTRA * 4 + 4 * 2048 + 256;

  if (ws_size >= NEED_NEW) {
    float4* W0ihT = (float4*)d_ws;
    float4* W0hhT = W0ihT + N0IH;
    float4* W1ihT = W0hhT + NHH;
    float4* W1hhT = W1ihT + NHH;
    float4* WaT = W1hhT + NHH;
    float4* fcWT = WaT + NWA;
    float* kproj = (float*)(fcWT + NFC);
    float* gin = kproj + KPROJ_FLOATS;
    float* h0A = gin + NGIN;
    float* h0B = h0A + NH;
    float* h1A = h0B + NH;
    float* h1B = h1A + NH;
    float* qpbuf = h1B + NH;
    float* logits = qpbuf + NH;
    int* tok = (int*)(logits + NLG);
    int* mf = tok + Bn;
    float* wsloss = (float*)(mf + Bn);

    init_bufs<<<2, 512, 0, stream>>>(tok, mf, wsloss);
    transpose_pack<<<(int)((N0IH + 255) / 256), 256, 0, stream>>>(Wih0, W0ihT, G3, EHn);
    transpose_pack<<<(int)((NHH + 255) / 256), 256, 0, stream>>>(Whh0, W0hhT, G3, Hn);
    transpose_pack<<<(int)((NHH + 255) / 256), 256, 0, stream>>>(Wih1, W1ihT, G3, Hn);
    transpose_pack<<<(int)((NHH + 255) / 256), 256, 0, stream>>>(Whh1, W1hhT, G3, Hn);
    transpose_pack<<<(int)((NWA + 255) / 256), 256, 0, stream>>>(Wa, WaT, Hn, Hn);
    transpose_pack<<<(int)((NFC + 255) / 256), 256, 0, stream>>>(fcW, fcWT, Vn, Hn);
    gemm_bias<<<dim3(Hn / 64, (Sn * Bn) / 64), 256, 0, stream>>>(
        enc, Ua, bUa, kproj, Sn * Bn, Hn, Hn);
    qp_only<<<Bn / 4, 1024, 0, stream>>>(state + (size_t)Bn * Hn, WaT, bWa, qpbuf);

    for (int t = 0; t < Tn; ++t) {
      const float* h0cur = (t == 0) ? state : ((t & 1) ? h0A : h0B);
      float* h0nxt = (t & 1) ? h0B : h0A;
      const float* h1cur =
          (t == 0) ? (state + (size_t)Bn * Hn) : ((t & 1) ? h1A : h1B);
      float* h1nxt = (t & 1) ? h1B : h1A;

      attn_gin<<<Bn / 4, 1024, 0, stream>>>(logits, target, t, (t > 0) ? 1 : 0,
                                            qpbuf, kproj, enc, emb, Va, bVa,
                                            gin, mf, out, wsloss);
      gru_gemm3<192><<<dim3(16, 16), 512, 0, stream>>>(
          gin, EHn / 4, h0cur, W0ihT, W0hhT, bih0, bhh0, h0nxt);
      gru_gemm3<128><<<dim3(16, 16), 512, 0, stream>>>(
          h0nxt, Hn / 4, h1cur, W1ihT, W1hhT, bih1, bhh1, h1nxt);
      fcqp_gemm<<<dim3(24, 16), 512, 0, stream>>>(h1nxt, fcWT, fcb, WaT, bWa,
                                                  logits, qpbuf);
    }
    argmax_loss<<<Bn / 4, 1024, 0, stream>>>(logits, target, Tn - 1, tok, mf, out,
                                             wsloss);
    finisher2<<<1, 1024, 0, stream>>>(wsloss, mf, out);
  } else if (ws_size >= NEED_A2) {
    float4* W0ihT = (float4*)d_ws;
    float4* W0hhT = W0ihT + N0IH;
    float4* W1ihT = W0hhT + NHH;
    float4* W1hhT = W1ihT + NHH;
    float4* WaT = W1hhT + NHH;
    float4* fcWT = WaT + NWA;
    float* kproj = (float*)(fcWT + NFC);
    float* wsloss = kproj + KPROJ_FLOATS;
    int* wscorrect = (int*)(wsloss + 1);

    ws_init<<<1, 1, 0, stream>>>(wsloss, wscorrect);
    transpose_pack<<<(int)((N0IH + 255) / 256), 256, 0, stream>>>(Wih0, W0ihT, G3, EHn);
    transpose_pack<<<(int)((NHH + 255) / 256), 256, 0, stream>>>(Whh0, W0hhT, G3, Hn);
    transpose_pack<<<(int)((NHH + 255) / 256), 256, 0, stream>>>(Wih1, W1ihT, G3, Hn);
    transpose_pack<<<(int)((NHH + 255) / 256), 256, 0, stream>>>(Whh1, W1hhT, G3, Hn);
    transpose_pack<<<(int)((NWA + 255) / 256), 256, 0, stream>>>(Wa, WaT, Hn, Hn);
    transpose_pack<<<(int)((NFC + 255) / 256), 256, 0, stream>>>(fcW, fcWT, Vn, Hn);
    gemm_bias<<<dim3(Hn / 64, (Sn * Bn) / 64), 256, 0, stream>>>(
        enc, Ua, bUa, kproj, Sn * Bn, Hn, Hn);
    decoder_r4y<<<Bn / 4, 1024, 0, stream>>>(
        state, enc, target, emb, WaT, bWa, Va, bVa, W0ihT, W0hhT, bih0, bhh0,
        W1ihT, W1hhT, bih1, bhh1, fcWT, fcb, kproj, out, wsloss, wscorrect);
    finisher<<<1, 1, 0, stream>>>(wsloss, wscorrect, out);
  }
}